// Round 1
// baseline (2092.489 us; speedup 1.0000x reference)
//
#include <hip/hip_runtime.h>
#include <hip/hip_bf16.h>
#include <cstdint>
#include <cstddef>

#define DEVI __device__ __forceinline__

#define BB 2
#define S_LEN 2048
#define HID_DIM 4096
#define NH 128
#define PD 64
#define NS 128
#define NG 8
#define INTER 8192
#define CONVD 10240
#define PROJ 18560
#define NC 16
#define BS 4096
#define GN 1024   // NG*NS

using short8 = __attribute__((ext_vector_type(8))) short;
using short4v = __attribute__((ext_vector_type(4))) short;
using f32x4  = __attribute__((ext_vector_type(4))) float;
using bf16x8 = __attribute__((ext_vector_type(8))) __bf16;

DEVI float bf2f(short u) {
  union { unsigned int i; float f; } v;
  v.i = ((unsigned int)(unsigned short)u) << 16;
  return v.f;
}
DEVI short f2bf(float f) {
  union { float ff; unsigned int i; } v; v.ff = f;
  unsigned int x = v.i;
  return (short)((x + 0x7fffu + ((x >> 16) & 1u)) >> 16);
}
DEVI f32x4 mfma16(short8 a, short8 b, f32x4 c) {
  return __builtin_amdgcn_mfma_f32_16x16x32_bf16(
      __builtin_bit_cast(bf16x8, a), __builtin_bit_cast(bf16x8, b), c, 0, 0, 0);
}
DEVI void gl_lds16(const short* g, short* l) {
  __builtin_amdgcn_global_load_lds(
      (const __attribute__((address_space(1))) void*)g,
      (__attribute__((address_space(3))) void*)l, 16, 0, 0);
}
DEVI float sigmoidf_(float x) { return 1.f / (1.f + __expf(-x)); }

// ---------------------------------------------------------------- converts
__global__ __launch_bounds__(256) void cvt_f32_bf16_k(const float* __restrict__ in,
                                                      short* __restrict__ out, size_t n) {
  size_t i = ((size_t)blockIdx.x * 256 + threadIdx.x) * 8;
  if (i + 8 > n) return;
  float4 a = *(const float4*)(in + i);
  float4 b = *(const float4*)(in + i + 4);
  short8 o;
  o[0] = f2bf(a.x); o[1] = f2bf(a.y); o[2] = f2bf(a.z); o[3] = f2bf(a.w);
  o[4] = f2bf(b.x); o[5] = f2bf(b.y); o[6] = f2bf(b.z); o[7] = f2bf(b.w);
  *(short8*)(out + i) = o;
}

// ---------------------------------------------------------------- GEMM (bt layout)
// C[M,N] = A[M,K](bf16,row) * Bt[N,K](bf16,row)^T ; 128x128 tile, BK=32, 4 waves.
__global__ __launch_bounds__(256) void gemm_bt_k(const short* __restrict__ A,
                                                 const short* __restrict__ Bt,
                                                 void* __restrict__ Cout,
                                                 int M, int N, int K, int cbf16) {
  __shared__ short As[128 * 32];
  __shared__ short Bs[128 * 32];
  const int tid = threadIdx.x;
  const int wid = tid >> 6;
  const int lane = tid & 63;
  const int m0 = blockIdx.y * 128;
  const int n0 = blockIdx.x * 128;
  const int wm = (wid >> 1) * 64;
  const int wn = (wid & 1) * 64;

  f32x4 acc[4][4] = {};

  const int rowA = tid >> 2;
  const int k8 = (tid & 3) * 8;
  const short* aS0 = A + (size_t)(m0 + rowA) * K + k8;
  const short* aS1 = A + (size_t)(m0 + rowA + 64) * K + k8;
  const short* bS0 = Bt + (size_t)(n0 + rowA) * K + k8;
  const short* bS1 = Bt + (size_t)(n0 + rowA + 64) * K + k8;

  const int fr = lane & 15;
  const int fk = (lane >> 4) * 8;

  for (int kt = 0; kt < K; kt += 32) {
    gl_lds16(aS0 + kt, As + wid * 512);
    gl_lds16(aS1 + kt, As + 2048 + wid * 512);
    gl_lds16(bS0 + kt, Bs + wid * 512);
    gl_lds16(bS1 + kt, Bs + 2048 + wid * 512);
    __syncthreads();
    short8 af[4], bf_[4];
#pragma unroll
    for (int mi = 0; mi < 4; ++mi)
      af[mi] = *(const short8*)(As + (wm + mi * 16 + fr) * 32 + fk);
#pragma unroll
    for (int ni = 0; ni < 4; ++ni)
      bf_[ni] = *(const short8*)(Bs + (wn + ni * 16 + fr) * 32 + fk);
#pragma unroll
    for (int mi = 0; mi < 4; ++mi)
#pragma unroll
      for (int ni = 0; ni < 4; ++ni)
        acc[mi][ni] = mfma16(af[mi], bf_[ni], acc[mi][ni]);
    __syncthreads();
  }

  const int er = (lane >> 4) * 4;
  const int ec = lane & 15;
  if (cbf16) {
    short* C = (short*)Cout;
#pragma unroll
    for (int mi = 0; mi < 4; ++mi)
#pragma unroll
      for (int j = 0; j < 4; ++j) {
        size_t base = (size_t)(m0 + wm + mi * 16 + er + j) * N + n0 + wn + ec;
#pragma unroll
        for (int ni = 0; ni < 4; ++ni) C[base + ni * 16] = f2bf(acc[mi][ni][j]);
      }
  } else {
    float* C = (float*)Cout;
#pragma unroll
    for (int mi = 0; mi < 4; ++mi)
#pragma unroll
      for (int j = 0; j < 4; ++j) {
        size_t base = (size_t)(m0 + wm + mi * 16 + er + j) * N + n0 + wn + ec;
#pragma unroll
        for (int ni = 0; ni < 4; ++ni) C[base + ni * 16] = acc[mi][ni][j];
      }
  }
}

// ---------------------------------------------------------------- conv + silu
__global__ __launch_bounds__(256) void conv_silu_k(const short* __restrict__ projb,
                                                   const float* __restrict__ convw,
                                                   const float* __restrict__ convb,
                                                   short* __restrict__ hbc) {
  const int c = blockIdx.x * 256 + threadIdx.x;
  const int s = blockIdx.y, b = blockIdx.z;
  const size_t rb = (size_t)b * S_LEN;
  const float* wp = convw + (size_t)c * 4;
  float w0 = wp[0], w1 = wp[1], w2 = wp[2], w3 = wp[3];
  float acc = convb[c];
  if (s >= 3) acc += bf2f(projb[(rb + s - 3) * PROJ + INTER + c]) * w0;
  if (s >= 2) acc += bf2f(projb[(rb + s - 2) * PROJ + INTER + c]) * w1;
  if (s >= 1) acc += bf2f(projb[(rb + s - 1) * PROJ + INTER + c]) * w2;
  acc += bf2f(projb[(rb + s) * PROJ + INTER + c]) * w3;
  float o = acc * sigmoidf_(acc);
  hbc[(rb + s) * CONVD + c] = f2bf(o);
}

// ---------------------------------------------------------------- dt (softplus, transposed store)
__global__ __launch_bounds__(128) void dt_k(const short* __restrict__ projb,
                                            const float* __restrict__ dt_bias,
                                            float* __restrict__ dtT) {
  const int h = threadIdx.x;
  const int r = blockIdx.x;  // 0..BS-1
  float x = bf2f(projb[(size_t)r * PROJ + INTER + CONVD + h]) + dt_bias[h];
  float sp = (x > 20.f) ? x : log1pf(__expf(x));
  sp = fminf(fmaxf(sp, 0.f), 100.f);
  const int b = r / S_LEN, s = r - b * S_LEN;
  dtT[((size_t)(b * NH + h)) * S_LEN + s] = sp;
}

// ---------------------------------------------------------------- per-chunk cumsum of dt*A
__global__ __launch_bounds__(128) void acum_k(const float* __restrict__ dtT,
                                              const float* __restrict__ A_log,
                                              float* __restrict__ acum) {
  const int l = threadIdx.x;
  const int z = blockIdx.x, h = blockIdx.y, b = blockIdx.z;
  const float A = -__expf(A_log[h]);
  __shared__ float sv[128];
  const size_t base = ((size_t)(b * NH + h)) * S_LEN + z * 128;
  sv[l] = dtT[base + l] * A;
  __syncthreads();
  for (int off = 1; off < 128; off <<= 1) {
    float t = (l >= off) ? sv[l - off] : 0.f;
    __syncthreads();
    sv[l] += t;
    __syncthreads();
  }
  acum[base + l] = sv[l];
}

// ---------------------------------------------------------------- SSD per-(b,z,h): Y_diag + states
__global__ __launch_bounds__(256) void ssm_chunk_k(const short* __restrict__ hbc,
                                                   const float* __restrict__ dtT,
                                                   const float* __restrict__ acum,
                                                   float* __restrict__ Y,
                                                   float* __restrict__ states) {
  __shared__ short sCP[128 * 128];  // C, then P
  __shared__ short sB[128 * 128];
  __shared__ short sxT[64 * 128];   // [p][s] of hs*dt
  const int tid = threadIdx.x, wid = tid >> 6, lane = tid & 63;
  const int h = blockIdx.x, z = blockIdx.y, b = blockIdx.z;
  const int g = h >> 4;
  const size_t srow0 = (size_t)(b * S_LEN + z * 128);
  const short* hrow = hbc + srow0 * CONVD;
  const float* ac = acum + ((size_t)(b * NH + h)) * S_LEN + z * 128;
  const float* dts = dtT + ((size_t)(b * NH + h)) * S_LEN + z * 128;

  {
    const int n0 = (tid & 15) * 8;
    const int sr = tid >> 4;
#pragma unroll
    for (int it = 0; it < 8; ++it) {
      int s = it * 16 + sr;
      gl_lds16(hrow + (size_t)s * CONVD + INTER + GN + g * NS + n0, sCP + it * 2048 + wid * 512);
      gl_lds16(hrow + (size_t)s * CONVD + INTER + g * NS + n0, sB + it * 2048 + wid * 512);
    }
  }
#pragma unroll
  for (int it = 0; it < 4; ++it) {
    int e = it * 256 + tid;
    int s = e >> 3;
    int p0 = (e & 7) * 8;
    short8 hv = *(const short8*)(hrow + (size_t)s * CONVD + (size_t)h * PD + p0);
    float dv = dts[s];
#pragma unroll
    for (int j = 0; j < 8; ++j) sxT[(p0 + j) * 128 + s] = f2bf(bf2f(hv[j]) * dv);
  }
  __syncthreads();

  const int fr = lane & 15, fk8 = (lane >> 4) * 8;
  const int er = (lane >> 4) * 4, ec = lane & 15;

  // scores = C * B^T over n
  f32x4 sc[2][8] = {};
#pragma unroll
  for (int kk = 0; kk < 4; ++kk) {
    short8 a0 = *(const short8*)(sCP + (wid * 32 + fr) * 128 + kk * 32 + fk8);
    short8 a1 = *(const short8*)(sCP + (wid * 32 + 16 + fr) * 128 + kk * 32 + fk8);
#pragma unroll
    for (int ni = 0; ni < 8; ++ni) {
      short8 bv = *(const short8*)(sB + (ni * 16 + fr) * 128 + kk * 32 + fk8);
      sc[0][ni] = mfma16(a0, bv, sc[0][ni]);
      sc[1][ni] = mfma16(a1, bv, sc[1][ni]);
    }
  }
  // mask with L and write P into sCP band (each wave only touches its own rows)
  {
    float acS[8];
#pragma unroll
    for (int ni = 0; ni < 8; ++ni) acS[ni] = ac[ni * 16 + ec];
#pragma unroll
    for (int mi = 0; mi < 2; ++mi)
#pragma unroll
      for (int j = 0; j < 4; ++j) {
        int l = wid * 32 + mi * 16 + er + j;
        float acl = ac[l];
#pragma unroll
        for (int ni = 0; ni < 8; ++ni) {
          int s = ni * 16 + ec;
          float v = (s <= l) ? sc[mi][ni][j] * __expf(acl - acS[ni]) : 0.f;
          sCP[l * 128 + s] = f2bf(v);
        }
      }
  }
  __syncthreads();

  // Y_diag = P @ xdt
  {
    f32x4 yd[2][4] = {};
#pragma unroll
    for (int kk = 0; kk < 4; ++kk) {
      short8 a0 = *(const short8*)(sCP + (wid * 32 + fr) * 128 + kk * 32 + fk8);
      short8 a1 = *(const short8*)(sCP + (wid * 32 + 16 + fr) * 128 + kk * 32 + fk8);
#pragma unroll
      for (int ni = 0; ni < 4; ++ni) {
        short8 bv = *(const short8*)(sxT + (ni * 16 + fr) * 128 + kk * 32 + fk8);
        yd[0][ni] = mfma16(a0, bv, yd[0][ni]);
        yd[1][ni] = mfma16(a1, bv, yd[1][ni]);
      }
    }
#pragma unroll
    for (int mi = 0; mi < 2; ++mi)
#pragma unroll
      for (int ni = 0; ni < 4; ++ni)
#pragma unroll
        for (int j = 0; j < 4; ++j) {
          int l = wid * 32 + mi * 16 + er + j;
          int p = ni * 16 + ec;
          Y[(srow0 + l) * (size_t)INTER + (size_t)h * PD + p] = yd[mi][ni][j];
        }
  }

  // states[n][p] = sum_l B[l][n]*decay[l]*xdt[l][p]
  {
    const float acLast = ac[127];
    f32x4 st[2][4] = {};
#pragma unroll
    for (int kk = 0; kk < 4; ++kk) {
      short8 a0, a1;
      const int na = wid * 32 + fr;
#pragma unroll
      for (int j = 0; j < 8; ++j) {
        int l = kk * 32 + fk8 + j;
        float dec = __expf(acLast - ac[l]);
        a0[j] = f2bf(bf2f(sB[l * 128 + na]) * dec);
        a1[j] = f2bf(bf2f(sB[l * 128 + na + 16]) * dec);
      }
#pragma unroll
      for (int ni = 0; ni < 4; ++ni) {
        short8 bv = *(const short8*)(sxT + (ni * 16 + fr) * 128 + kk * 32 + fk8);
        st[0][ni] = mfma16(a0, bv, st[0][ni]);
        st[1][ni] = mfma16(a1, bv, st[1][ni]);
      }
    }
    float* stp = states + (((size_t)(b * NC + z)) * NH + h) * (size_t)(NS * PD);
#pragma unroll
    for (int mi = 0; mi < 2; ++mi)
#pragma unroll
      for (int ni = 0; ni < 4; ++ni)
#pragma unroll
        for (int j = 0; j < 4; ++j) {
          int n = wid * 32 + mi * 16 + er + j;
          int p = ni * 16 + ec;
          stp[n * PD + p] = st[mi][ni][j];
        }
  }
}

// ---------------------------------------------------------------- inter-chunk scan (in-place, transposes to [p][n])
__global__ __launch_bounds__(256) void scan_k(float* __restrict__ states,
                                              const float* __restrict__ acum) {
  const int h = blockIdx.x, b = blockIdx.y;
  const int tid = threadIdx.x;
  float* stp = states + ((size_t)(b * NC * NH) + h) * (size_t)(NS * PD);
  const size_t cst = (size_t)NH * NS * PD;
  const float* ac = acum + ((size_t)(b * NH + h)) * S_LEN;
  float E[32];
#pragma unroll
  for (int i = 0; i < 32; ++i) E[i] = 0.f;
  for (int zz = 0; zz < NC; ++zz) {
    float* sz = stp + (size_t)zz * cst;
    float tmp[32];
#pragma unroll
    for (int i = 0; i < 32; ++i) tmp[i] = sz[i * 256 + tid];
    __syncthreads();
    float dec = __expf(ac[zz * 128 + 127]);
#pragma unroll
    for (int i = 0; i < 32; ++i) {
      int e = i * 256 + tid;
      int n = e >> 6, p = e & 63;
      sz[p * NS + n] = E[i];          // prev state entering chunk zz, [p][n]
      E[i] = dec * E[i] + tmp[i];
    }
    __syncthreads();
  }
}

// ---------------------------------------------------------------- combine: Y += exp(Acum)*C@prev^T + hs*D
__global__ __launch_bounds__(256) void combine_k(const short* __restrict__ hbc,
                                                 const float* __restrict__ acum,
                                                 const float* __restrict__ states,
                                                 const float* __restrict__ Dv,
                                                 float* __restrict__ Y) {
  __shared__ short sC[128 * 128];
  __shared__ short sPrev[64 * 128];  // [p][n]
  const int tid = threadIdx.x, wid = tid >> 6, lane = tid & 63;
  const int h = blockIdx.x, z = blockIdx.y, b = blockIdx.z;
  const int g = h >> 4;
  const size_t srow0 = (size_t)(b * S_LEN + z * 128);
  const short* hrow = hbc + srow0 * CONVD;
  const float* ac = acum + ((size_t)(b * NH + h)) * S_LEN + z * 128;
  const float* pv = states + (((size_t)(b * NC + z)) * NH + h) * (size_t)(NS * PD);

  {
    const int n0 = (tid & 15) * 8;
    const int sr = tid >> 4;
#pragma unroll
    for (int it = 0; it < 8; ++it) {
      int s = it * 16 + sr;
      gl_lds16(hrow + (size_t)s * CONVD + INTER + GN + g * NS + n0, sC + it * 2048 + wid * 512);
    }
  }
#pragma unroll
  for (int it = 0; it < 8; ++it) {
    int e = (it * 256 + tid) * 4;
    float4 v = *(const float4*)(pv + e);
    short4v o;
    o[0] = f2bf(v.x); o[1] = f2bf(v.y); o[2] = f2bf(v.z); o[3] = f2bf(v.w);
    *(short4v*)(sPrev + e) = o;
  }
  __syncthreads();

  const int fr = lane & 15, fk8 = (lane >> 4) * 8;
  const int er = (lane >> 4) * 4, ec = lane & 15;
  f32x4 off[2][4] = {};
#pragma unroll
  for (int kk = 0; kk < 4; ++kk) {
    short8 a0 = *(const short8*)(sC + (wid * 32 + fr) * 128 + kk * 32 + fk8);
    short8 a1 = *(const short8*)(sC + (wid * 32 + 16 + fr) * 128 + kk * 32 + fk8);
#pragma unroll
    for (int ni = 0; ni < 4; ++ni) {
      short8 bv = *(const short8*)(sPrev + (ni * 16 + fr) * 128 + kk * 32 + fk8);
      off[0][ni] = mfma16(a0, bv, off[0][ni]);
      off[1][ni] = mfma16(a1, bv, off[1][ni]);
    }
  }
  const float Dh = Dv[h];
#pragma unroll
  for (int mi = 0; mi < 2; ++mi)
#pragma unroll
    for (int j = 0; j < 4; ++j) {
      int l = wid * 32 + mi * 16 + er + j;
      float e_ac = __expf(ac[l]);
#pragma unroll
      for (int ni = 0; ni < 4; ++ni) {
        int p = ni * 16 + ec;
        size_t yi = (srow0 + l) * (size_t)INTER + (size_t)h * PD + p;
        float hs = bf2f(hrow[(size_t)l * CONVD + (size_t)h * PD + p]);
        Y[yi] = Y[yi] + off[mi][ni][j] * e_ac + hs * Dh;
      }
    }
}

// ---------------------------------------------------------------- gated group RMS norm -> bf16
__global__ __launch_bounds__(256) void norm_k(const float* __restrict__ Y,
                                              const short* __restrict__ projb,
                                              const float* __restrict__ norm_w,
                                              short* __restrict__ outn) {
  const int r = blockIdx.x;
  const int tid = threadIdx.x;
  const int gi = tid >> 5, li = tid & 31;
  const float* yrow = Y + (size_t)r * INTER;
  const short* grow = projb + (size_t)r * PROJ;
  const int e0 = gi * 1024 + li * 32;
  float gv[32];
  float ss = 0.f;
#pragma unroll
  for (int j4 = 0; j4 < 32; j4 += 4) {
    float4 yv = *(const float4*)(yrow + e0 + j4);
    short4v gt = *(const short4v*)(grow + e0 + j4);
    float ys[4] = {yv.x, yv.y, yv.z, yv.w};
#pragma unroll
    for (int q = 0; q < 4; ++q) {
      float gate = bf2f(gt[q]);
      float gg = ys[q] * gate * sigmoidf_(gate);
      gv[j4 + q] = gg;
      ss += gg * gg;
    }
  }
#pragma unroll
  for (int m = 16; m >= 1; m >>= 1) ss += __shfl_xor(ss, m, 64);
  const float scale = rsqrtf(ss * (1.f / 1024.f) + 1e-5f);
#pragma unroll
  for (int j4 = 0; j4 < 32; j4 += 4) {
    short4v o;
#pragma unroll
    for (int q = 0; q < 4; ++q) o[q] = f2bf(gv[j4 + q] * scale * norm_w[e0 + j4 + q]);
    *(short4v*)(outn + (size_t)r * INTER + e0 + j4) = o;
  }
}

// ----------------------------------------------------------------
extern "C" void kernel_launch(void* const* d_in, const int* in_sizes, int n_in,
                              void* d_out, int out_size, void* d_ws, size_t ws_size,
                              hipStream_t stream) {
  const float* x     = (const float*)d_in[0];
  const float* w1    = (const float*)d_in[1];
  const float* convw = (const float*)d_in[2];
  const float* convb = (const float*)d_in[3];
  const float* dtb   = (const float*)d_in[4];
  const float* alog  = (const float*)d_in[5];
  const float* Dv    = (const float*)d_in[6];
  const float* nw    = (const float*)d_in[7];
  const float* w2    = (const float*)d_in[8];
  float* out = (float*)d_out;

  char* ws = (char*)d_ws;
  size_t off = 0;
  float* dtT = (float*)(ws + off);  off += (size_t)BB * NH * S_LEN * 4;
  float* acum = (float*)(ws + off); off += (size_t)BB * NH * S_LEN * 4;
  short* xb = (short*)(ws + off);   off += (size_t)BS * HID_DIM * 2;
  char* w1region = ws + off;        off += (size_t)PROJ * HID_DIM * 2;
  short* w1b = (short*)w1region;
  short* normed = (short*)w1region;                              // reuse after gemm1
  short* w2b = (short*)(w1region + (size_t)BS * INTER * 2);      // reuse after gemm1
  short* projb = (short*)(ws + off); off += (size_t)BS * PROJ * 2;
  short* hbc = (short*)(ws + off);   off += (size_t)BS * CONVD * 2;
  float* Y = (float*)(ws + off);     off += (size_t)BS * INTER * 4;
  float* states = (float*)(ws + off); off += (size_t)BB * NC * NH * NS * PD * 4;

  const size_t nx = (size_t)BS * HID_DIM;
  const size_t nw1 = (size_t)PROJ * HID_DIM;
  const size_t nw2 = (size_t)HID_DIM * INTER;

  cvt_f32_bf16_k<<<dim3(nx / 2048), 256, 0, stream>>>(x, xb, nx);
  cvt_f32_bf16_k<<<dim3(nw1 / 2048), 256, 0, stream>>>(w1, w1b, nw1);

  gemm_bt_k<<<dim3(PROJ / 128, BS / 128), 256, 0, stream>>>(xb, w1b, projb, BS, PROJ, HID_DIM, 1);

  // w1b dead now; stage w2 into its region
  cvt_f32_bf16_k<<<dim3(nw2 / 2048), 256, 0, stream>>>(w2, w2b, nw2);

  conv_silu_k<<<dim3(CONVD / 256, S_LEN, BB), 256, 0, stream>>>(projb, convw, convb, hbc);
  dt_k<<<dim3(BS), 128, 0, stream>>>(projb, dtb, dtT);
  acum_k<<<dim3(NC, NH, BB), 128, 0, stream>>>(dtT, alog, acum);

  ssm_chunk_k<<<dim3(NH, NC, BB), 256, 0, stream>>>(hbc, dtT, acum, Y, states);
  scan_k<<<dim3(NH, BB), 256, 0, stream>>>(states, acum);
  combine_k<<<dim3(NH, NC, BB), 256, 0, stream>>>(hbc, acum, states, Dv, Y);

  norm_k<<<dim3(BS), 256, 0, stream>>>(Y, projb, nw, normed);

  gemm_bt_k<<<dim3(HID_DIM / 128, BS / 128), 256, 0, stream>>>(normed, w2b, out, BS, HID_DIM, INTER, 0);
}

// Round 2
// 2053.605 us; speedup vs baseline: 1.0189x; 1.0189x over previous
//
#include <hip/hip_runtime.h>
#include <hip/hip_bf16.h>
#include <cstdint>
#include <cstddef>

#define DEVI __device__ __forceinline__

#define BB 2
#define S_LEN 2048
#define HID_DIM 4096
#define NH 128
#define PD 64
#define NS 128
#define NG 8
#define INTER 8192
#define CONVD 10240
#define PROJ 18560
#define NC 16
#define BS 4096
#define GN 1024   // NG*NS

using short8 = __attribute__((ext_vector_type(8))) short;
using short4v = __attribute__((ext_vector_type(4))) short;
using f32x4  = __attribute__((ext_vector_type(4))) float;
using bf16x8 = __attribute__((ext_vector_type(8))) __bf16;

DEVI float bf2f(short u) {
  union { unsigned int i; float f; } v;
  v.i = ((unsigned int)(unsigned short)u) << 16;
  return v.f;
}
DEVI short f2bf(float f) {
  union { float ff; unsigned int i; } v; v.ff = f;
  unsigned int x = v.i;
  return (short)((x + 0x7fffu + ((x >> 16) & 1u)) >> 16);
}
DEVI f32x4 mfma16(short8 a, short8 b, f32x4 c) {
  return __builtin_amdgcn_mfma_f32_16x16x32_bf16(
      __builtin_bit_cast(bf16x8, a), __builtin_bit_cast(bf16x8, b), c, 0, 0, 0);
}
DEVI void gl_lds16(const short* g, short* l) {
  __builtin_amdgcn_global_load_lds(
      (const __attribute__((address_space(1))) void*)g,
      (__attribute__((address_space(3))) void*)l, 16, 0, 0);
}
DEVI float sigmoidf_(float x) { return 1.f / (1.f + __expf(-x)); }

// ---------------------------------------------------------------- converts
__global__ __launch_bounds__(256) void cvt_f32_bf16_k(const float* __restrict__ in,
                                                      short* __restrict__ out, size_t n) {
  size_t i = ((size_t)blockIdx.x * 256 + threadIdx.x) * 8;
  if (i + 8 > n) return;
  float4 a = *(const float4*)(in + i);
  float4 b = *(const float4*)(in + i + 4);
  short8 o;
  o[0] = f2bf(a.x); o[1] = f2bf(a.y); o[2] = f2bf(a.z); o[3] = f2bf(a.w);
  o[4] = f2bf(b.x); o[5] = f2bf(b.y); o[6] = f2bf(b.z); o[7] = f2bf(b.w);
  *(short8*)(out + i) = o;
}

// ---------------------------------------------------------------- GEMM (bt layout)
// C[M,N] = A[M,K](bf16,row) * Bt[N,K](bf16,row)^T ; 128x128 tile, BK=32, 4 waves.
// 1D grid; XCD-bijective chunking (nwg%8==0) + GM=8 supertile decode for L2/L3 reuse.
__global__ __launch_bounds__(256) void gemm_bt_k(const short* __restrict__ A,
                                                 const short* __restrict__ Bt,
                                                 void* __restrict__ Cout,
                                                 int M, int N, int K, int cbf16, int ntn) {
  __shared__ short As[128 * 32];
  __shared__ short Bs[128 * 32];
  const int tid = threadIdx.x;
  const int wid = tid >> 6;
  const int lane = tid & 63;

  // --- block remap: XCD chunk then GM=8 m-grouped supertile ---
  const int nwg = gridDim.x;                 // divisible by 8
  const int orig = blockIdx.x;
  const int swz = (orig & 7) * (nwg >> 3) + (orig >> 3);
  const int per_group = ntn << 3;            // GM=8 m-tiles per group
  const int group = swz / per_group;
  const int rem = swz - group * per_group;
  const int mt = (group << 3) + (rem & 7);
  const int nt = rem >> 3;
  const int m0 = mt * 128;
  const int n0 = nt * 128;

  const int wm = (wid >> 1) * 64;
  const int wn = (wid & 1) * 64;

  f32x4 acc[4][4] = {};

  const int rowA = tid >> 2;
  const int k8 = (tid & 3) * 8;
  const short* aS0 = A + (size_t)(m0 + rowA) * K + k8;
  const short* aS1 = A + (size_t)(m0 + rowA + 64) * K + k8;
  const short* bS0 = Bt + (size_t)(n0 + rowA) * K + k8;
  const short* bS1 = Bt + (size_t)(n0 + rowA + 64) * K + k8;

  const int fr = lane & 15;
  const int fk = (lane >> 4) * 8;

  for (int kt = 0; kt < K; kt += 32) {
    gl_lds16(aS0 + kt, As + wid * 512);
    gl_lds16(aS1 + kt, As + 2048 + wid * 512);
    gl_lds16(bS0 + kt, Bs + wid * 512);
    gl_lds16(bS1 + kt, Bs + 2048 + wid * 512);
    __syncthreads();
    short8 af[4], bf_[4];
#pragma unroll
    for (int mi = 0; mi < 4; ++mi)
      af[mi] = *(const short8*)(As + (wm + mi * 16 + fr) * 32 + fk);
#pragma unroll
    for (int ni = 0; ni < 4; ++ni)
      bf_[ni] = *(const short8*)(Bs + (wn + ni * 16 + fr) * 32 + fk);
#pragma unroll
    for (int mi = 0; mi < 4; ++mi)
#pragma unroll
      for (int ni = 0; ni < 4; ++ni)
        acc[mi][ni] = mfma16(af[mi], bf_[ni], acc[mi][ni]);
    __syncthreads();
  }

  const int er = (lane >> 4) * 4;
  const int ec = lane & 15;
  if (cbf16) {
    short* C = (short*)Cout;
#pragma unroll
    for (int mi = 0; mi < 4; ++mi)
#pragma unroll
      for (int j = 0; j < 4; ++j) {
        size_t base = (size_t)(m0 + wm + mi * 16 + er + j) * N + n0 + wn + ec;
#pragma unroll
        for (int ni = 0; ni < 4; ++ni) C[base + ni * 16] = f2bf(acc[mi][ni][j]);
      }
  } else {
    float* C = (float*)Cout;
#pragma unroll
    for (int mi = 0; mi < 4; ++mi)
#pragma unroll
      for (int j = 0; j < 4; ++j) {
        size_t base = (size_t)(m0 + wm + mi * 16 + er + j) * N + n0 + wn + ec;
#pragma unroll
        for (int ni = 0; ni < 4; ++ni) C[base + ni * 16] = acc[mi][ni][j];
      }
  }
}

// ---------------------------------------------------------------- conv + silu
__global__ __launch_bounds__(256) void conv_silu_k(const short* __restrict__ projb,
                                                   const float* __restrict__ convw,
                                                   const float* __restrict__ convb,
                                                   short* __restrict__ hbc) {
  const int c = blockIdx.x * 256 + threadIdx.x;
  const int s = blockIdx.y, b = blockIdx.z;
  const size_t rb = (size_t)b * S_LEN;
  const float* wp = convw + (size_t)c * 4;
  float w0 = wp[0], w1 = wp[1], w2 = wp[2], w3 = wp[3];
  float acc = convb[c];
  if (s >= 3) acc += bf2f(projb[(rb + s - 3) * PROJ + INTER + c]) * w0;
  if (s >= 2) acc += bf2f(projb[(rb + s - 2) * PROJ + INTER + c]) * w1;
  if (s >= 1) acc += bf2f(projb[(rb + s - 1) * PROJ + INTER + c]) * w2;
  acc += bf2f(projb[(rb + s) * PROJ + INTER + c]) * w3;
  float o = acc * sigmoidf_(acc);
  hbc[(rb + s) * CONVD + c] = f2bf(o);
}

// ---------------------------------------------------------------- dt (softplus, transposed store)
__global__ __launch_bounds__(128) void dt_k(const short* __restrict__ projb,
                                            const float* __restrict__ dt_bias,
                                            float* __restrict__ dtT) {
  const int h = threadIdx.x;
  const int r = blockIdx.x;  // 0..BS-1
  float x = bf2f(projb[(size_t)r * PROJ + INTER + CONVD + h]) + dt_bias[h];
  float sp = (x > 20.f) ? x : log1pf(__expf(x));
  sp = fminf(fmaxf(sp, 0.f), 100.f);
  const int b = r / S_LEN, s = r - b * S_LEN;
  dtT[((size_t)(b * NH + h)) * S_LEN + s] = sp;
}

// ---------------------------------------------------------------- per-chunk cumsum of dt*A
__global__ __launch_bounds__(128) void acum_k(const float* __restrict__ dtT,
                                              const float* __restrict__ A_log,
                                              float* __restrict__ acum) {
  const int l = threadIdx.x;
  const int z = blockIdx.x, h = blockIdx.y, b = blockIdx.z;
  const float A = -__expf(A_log[h]);
  __shared__ float sv[128];
  const size_t base = ((size_t)(b * NH + h)) * S_LEN + z * 128;
  sv[l] = dtT[base + l] * A;
  __syncthreads();
  for (int off = 1; off < 128; off <<= 1) {
    float t = (l >= off) ? sv[l - off] : 0.f;
    __syncthreads();
    sv[l] += t;
    __syncthreads();
  }
  acum[base + l] = sv[l];
}

// ---------------------------------------------------------------- SSD per-(b,z,h): Y_diag + states
__global__ __launch_bounds__(256) void ssm_chunk_k(const short* __restrict__ hbc,
                                                   const float* __restrict__ dtT,
                                                   const float* __restrict__ acum,
                                                   float* __restrict__ Y,
                                                   float* __restrict__ states) {
  __shared__ short sCP[128 * 128];  // C, then P
  __shared__ short sB[128 * 128];
  __shared__ short sxT[64 * 128];   // [p][s] of hs*dt
  const int tid = threadIdx.x, wid = tid >> 6, lane = tid & 63;
  const int h = blockIdx.x, z = blockIdx.y, b = blockIdx.z;
  const int g = h >> 4;
  const size_t srow0 = (size_t)(b * S_LEN + z * 128);
  const short* hrow = hbc + srow0 * CONVD;
  const float* ac = acum + ((size_t)(b * NH + h)) * S_LEN + z * 128;
  const float* dts = dtT + ((size_t)(b * NH + h)) * S_LEN + z * 128;

  {
    const int n0 = (tid & 15) * 8;
    const int sr = tid >> 4;
#pragma unroll
    for (int it = 0; it < 8; ++it) {
      int s = it * 16 + sr;
      gl_lds16(hrow + (size_t)s * CONVD + INTER + GN + g * NS + n0, sCP + it * 2048 + wid * 512);
      gl_lds16(hrow + (size_t)s * CONVD + INTER + g * NS + n0, sB + it * 2048 + wid * 512);
    }
  }
#pragma unroll
  for (int it = 0; it < 4; ++it) {
    int e = it * 256 + tid;
    int s = e >> 3;
    int p0 = (e & 7) * 8;
    short8 hv = *(const short8*)(hrow + (size_t)s * CONVD + (size_t)h * PD + p0);
    float dv = dts[s];
#pragma unroll
    for (int j = 0; j < 8; ++j) sxT[(p0 + j) * 128 + s] = f2bf(bf2f(hv[j]) * dv);
  }
  __syncthreads();

  const int fr = lane & 15, fk8 = (lane >> 4) * 8;
  const int er = (lane >> 4) * 4, ec = lane & 15;

  // scores = C * B^T over n
  f32x4 sc[2][8] = {};
#pragma unroll
  for (int kk = 0; kk < 4; ++kk) {
    short8 a0 = *(const short8*)(sCP + (wid * 32 + fr) * 128 + kk * 32 + fk8);
    short8 a1 = *(const short8*)(sCP + (wid * 32 + 16 + fr) * 128 + kk * 32 + fk8);
#pragma unroll
    for (int ni = 0; ni < 8; ++ni) {
      short8 bv = *(const short8*)(sB + (ni * 16 + fr) * 128 + kk * 32 + fk8);
      sc[0][ni] = mfma16(a0, bv, sc[0][ni]);
      sc[1][ni] = mfma16(a1, bv, sc[1][ni]);
    }
  }
  // mask with L and write P into sCP band (each wave only touches its own rows)
  {
    float acS[8];
#pragma unroll
    for (int ni = 0; ni < 8; ++ni) acS[ni] = ac[ni * 16 + ec];
#pragma unroll
    for (int mi = 0; mi < 2; ++mi)
#pragma unroll
      for (int j = 0; j < 4; ++j) {
        int l = wid * 32 + mi * 16 + er + j;
        float acl = ac[l];
#pragma unroll
        for (int ni = 0; ni < 8; ++ni) {
          int s = ni * 16 + ec;
          float v = (s <= l) ? sc[mi][ni][j] * __expf(acl - acS[ni]) : 0.f;
          sCP[l * 128 + s] = f2bf(v);
        }
      }
  }
  __syncthreads();

  // Y_diag = P @ xdt
  {
    f32x4 yd[2][4] = {};
#pragma unroll
    for (int kk = 0; kk < 4; ++kk) {
      short8 a0 = *(const short8*)(sCP + (wid * 32 + fr) * 128 + kk * 32 + fk8);
      short8 a1 = *(const short8*)(sCP + (wid * 32 + 16 + fr) * 128 + kk * 32 + fk8);
#pragma unroll
      for (int ni = 0; ni < 4; ++ni) {
        short8 bv = *(const short8*)(sxT + (ni * 16 + fr) * 128 + kk * 32 + fk8);
        yd[0][ni] = mfma16(a0, bv, yd[0][ni]);
        yd[1][ni] = mfma16(a1, bv, yd[1][ni]);
      }
    }
#pragma unroll
    for (int mi = 0; mi < 2; ++mi)
#pragma unroll
      for (int ni = 0; ni < 4; ++ni)
#pragma unroll
        for (int j = 0; j < 4; ++j) {
          int l = wid * 32 + mi * 16 + er + j;
          int p = ni * 16 + ec;
          Y[(srow0 + l) * (size_t)INTER + (size_t)h * PD + p] = yd[mi][ni][j];
        }
  }

  // states[n][p] = sum_l B[l][n]*decay[l]*xdt[l][p]
  {
    const float acLast = ac[127];
    f32x4 st[2][4] = {};
#pragma unroll
    for (int kk = 0; kk < 4; ++kk) {
      short8 a0, a1;
      const int na = wid * 32 + fr;
#pragma unroll
      for (int j = 0; j < 8; ++j) {
        int l = kk * 32 + fk8 + j;
        float dec = __expf(acLast - ac[l]);
        a0[j] = f2bf(bf2f(sB[l * 128 + na]) * dec);
        a1[j] = f2bf(bf2f(sB[l * 128 + na + 16]) * dec);
      }
#pragma unroll
      for (int ni = 0; ni < 4; ++ni) {
        short8 bv = *(const short8*)(sxT + (ni * 16 + fr) * 128 + kk * 32 + fk8);
        st[0][ni] = mfma16(a0, bv, st[0][ni]);
        st[1][ni] = mfma16(a1, bv, st[1][ni]);
      }
    }
    float* stp = states + (((size_t)(b * NC + z)) * NH + h) * (size_t)(NS * PD);
#pragma unroll
    for (int mi = 0; mi < 2; ++mi)
#pragma unroll
      for (int ni = 0; ni < 4; ++ni)
#pragma unroll
        for (int j = 0; j < 4; ++j) {
          int n = wid * 32 + mi * 16 + er + j;
          int p = ni * 16 + ec;
          stp[n * PD + p] = st[mi][ni][j];
        }
  }
}

// ---------------------------------------------------------------- inter-chunk scan (in-place, transposes to [p][n])
__global__ __launch_bounds__(256) void scan_k(float* __restrict__ states,
                                              const float* __restrict__ acum) {
  const int h = blockIdx.x, b = blockIdx.y;
  const int tid = threadIdx.x;
  float* stp = states + ((size_t)(b * NC * NH) + h) * (size_t)(NS * PD);
  const size_t cst = (size_t)NH * NS * PD;
  const float* ac = acum + ((size_t)(b * NH + h)) * S_LEN;
  float E[32];
#pragma unroll
  for (int i = 0; i < 32; ++i) E[i] = 0.f;
  for (int zz = 0; zz < NC; ++zz) {
    float* sz = stp + (size_t)zz * cst;
    float tmp[32];
#pragma unroll
    for (int i = 0; i < 32; ++i) tmp[i] = sz[i * 256 + tid];
    __syncthreads();
    float dec = __expf(ac[zz * 128 + 127]);
#pragma unroll
    for (int i = 0; i < 32; ++i) {
      int e = i * 256 + tid;
      int n = e >> 6, p = e & 63;
      sz[p * NS + n] = E[i];          // prev state entering chunk zz, [p][n]
      E[i] = dec * E[i] + tmp[i];
    }
    __syncthreads();
  }
}

// ---------------------------------------------------------------- combine: Y += exp(Acum)*C@prev^T + hs*D
__global__ __launch_bounds__(256) void combine_k(const short* __restrict__ hbc,
                                                 const float* __restrict__ acum,
                                                 const float* __restrict__ states,
                                                 const float* __restrict__ Dv,
                                                 float* __restrict__ Y) {
  __shared__ short sC[128 * 128];
  __shared__ short sPrev[64 * 128];  // [p][n]
  const int tid = threadIdx.x, wid = tid >> 6, lane = tid & 63;
  const int h = blockIdx.x, z = blockIdx.y, b = blockIdx.z;
  const int g = h >> 4;
  const size_t srow0 = (size_t)(b * S_LEN + z * 128);
  const short* hrow = hbc + srow0 * CONVD;
  const float* ac = acum + ((size_t)(b * NH + h)) * S_LEN + z * 128;
  const float* pv = states + (((size_t)(b * NC + z)) * NH + h) * (size_t)(NS * PD);

  {
    const int n0 = (tid & 15) * 8;
    const int sr = tid >> 4;
#pragma unroll
    for (int it = 0; it < 8; ++it) {
      int s = it * 16 + sr;
      gl_lds16(hrow + (size_t)s * CONVD + INTER + GN + g * NS + n0, sC + it * 2048 + wid * 512);
    }
  }
#pragma unroll
  for (int it = 0; it < 8; ++it) {
    int e = (it * 256 + tid) * 4;
    float4 v = *(const float4*)(pv + e);
    short4v o;
    o[0] = f2bf(v.x); o[1] = f2bf(v.y); o[2] = f2bf(v.z); o[3] = f2bf(v.w);
    *(short4v*)(sPrev + e) = o;
  }
  __syncthreads();

  const int fr = lane & 15, fk8 = (lane >> 4) * 8;
  const int er = (lane >> 4) * 4, ec = lane & 15;
  f32x4 off[2][4] = {};
#pragma unroll
  for (int kk = 0; kk < 4; ++kk) {
    short8 a0 = *(const short8*)(sC + (wid * 32 + fr) * 128 + kk * 32 + fk8);
    short8 a1 = *(const short8*)(sC + (wid * 32 + 16 + fr) * 128 + kk * 32 + fk8);
#pragma unroll
    for (int ni = 0; ni < 4; ++ni) {
      short8 bv = *(const short8*)(sPrev + (ni * 16 + fr) * 128 + kk * 32 + fk8);
      off[0][ni] = mfma16(a0, bv, off[0][ni]);
      off[1][ni] = mfma16(a1, bv, off[1][ni]);
    }
  }
  const float Dh = Dv[h];
#pragma unroll
  for (int mi = 0; mi < 2; ++mi)
#pragma unroll
    for (int j = 0; j < 4; ++j) {
      int l = wid * 32 + mi * 16 + er + j;
      float e_ac = __expf(ac[l]);
#pragma unroll
      for (int ni = 0; ni < 4; ++ni) {
        int p = ni * 16 + ec;
        size_t yi = (srow0 + l) * (size_t)INTER + (size_t)h * PD + p;
        float hs = bf2f(hrow[(size_t)l * CONVD + (size_t)h * PD + p]);
        Y[yi] = Y[yi] + off[mi][ni][j] * e_ac + hs * Dh;
      }
    }
}

// ---------------------------------------------------------------- gated group RMS norm -> bf16
__global__ __launch_bounds__(256) void norm_k(const float* __restrict__ Y,
                                              const short* __restrict__ projb,
                                              const float* __restrict__ norm_w,
                                              short* __restrict__ outn) {
  const int r = blockIdx.x;
  const int tid = threadIdx.x;
  const int gi = tid >> 5, li = tid & 31;
  const float* yrow = Y + (size_t)r * INTER;
  const short* grow = projb + (size_t)r * PROJ;
  const int e0 = gi * 1024 + li * 32;
  float gv[32];
  float ss = 0.f;
#pragma unroll
  for (int j4 = 0; j4 < 32; j4 += 4) {
    float4 yv = *(const float4*)(yrow + e0 + j4);
    short4v gt = *(const short4v*)(grow + e0 + j4);
    float ys[4] = {yv.x, yv.y, yv.z, yv.w};
#pragma unroll
    for (int q = 0; q < 4; ++q) {
      float gate = bf2f(gt[q]);
      float gg = ys[q] * gate * sigmoidf_(gate);
      gv[j4 + q] = gg;
      ss += gg * gg;
    }
  }
#pragma unroll
  for (int m = 16; m >= 1; m >>= 1) ss += __shfl_xor(ss, m, 64);
  const float scale = rsqrtf(ss * (1.f / 1024.f) + 1e-5f);
#pragma unroll
  for (int j4 = 0; j4 < 32; j4 += 4) {
    short4v o;
#pragma unroll
    for (int q = 0; q < 4; ++q) o[q] = f2bf(gv[j4 + q] * scale * norm_w[e0 + j4 + q]);
    *(short4v*)(outn + (size_t)r * INTER + e0 + j4) = o;
  }
}

// ----------------------------------------------------------------
extern "C" void kernel_launch(void* const* d_in, const int* in_sizes, int n_in,
                              void* d_out, int out_size, void* d_ws, size_t ws_size,
                              hipStream_t stream) {
  const float* x     = (const float*)d_in[0];
  const float* w1    = (const float*)d_in[1];
  const float* convw = (const float*)d_in[2];
  const float* convb = (const float*)d_in[3];
  const float* dtb   = (const float*)d_in[4];
  const float* alog  = (const float*)d_in[5];
  const float* Dv    = (const float*)d_in[6];
  const float* nw    = (const float*)d_in[7];
  const float* w2    = (const float*)d_in[8];
  float* out = (float*)d_out;

  char* ws = (char*)d_ws;
  size_t off = 0;
  float* dtT = (float*)(ws + off);  off += (size_t)BB * NH * S_LEN * 4;
  float* acum = (float*)(ws + off); off += (size_t)BB * NH * S_LEN * 4;
  short* xb = (short*)(ws + off);   off += (size_t)BS * HID_DIM * 2;
  char* w1region = ws + off;        off += (size_t)PROJ * HID_DIM * 2;
  short* w1b = (short*)w1region;
  short* normed = (short*)w1region;                              // reuse after gemm1
  short* w2b = (short*)(w1region + (size_t)BS * INTER * 2);      // reuse after gemm1
  short* projb = (short*)(ws + off); off += (size_t)BS * PROJ * 2;
  short* hbc = (short*)(ws + off);   off += (size_t)BS * CONVD * 2;
  float* Y = (float*)(ws + off);     off += (size_t)BS * INTER * 4;
  float* states = (float*)(ws + off); off += (size_t)BB * NC * NH * NS * PD * 4;

  const size_t nx = (size_t)BS * HID_DIM;
  const size_t nw1 = (size_t)PROJ * HID_DIM;
  const size_t nw2 = (size_t)HID_DIM * INTER;

  cvt_f32_bf16_k<<<dim3(nx / 2048), 256, 0, stream>>>(x, xb, nx);
  cvt_f32_bf16_k<<<dim3(nw1 / 2048), 256, 0, stream>>>(w1, w1b, nw1);

  gemm_bt_k<<<dim3((PROJ / 128) * (BS / 128)), 256, 0, stream>>>(xb, w1b, projb, BS, PROJ, HID_DIM, 1, PROJ / 128);

  // w1b dead now; stage w2 into its region
  cvt_f32_bf16_k<<<dim3(nw2 / 2048), 256, 0, stream>>>(w2, w2b, nw2);

  conv_silu_k<<<dim3(CONVD / 256, S_LEN, BB), 256, 0, stream>>>(projb, convw, convb, hbc);
  dt_k<<<dim3(BS), 128, 0, stream>>>(projb, dtb, dtT);
  acum_k<<<dim3(NC, NH, BB), 128, 0, stream>>>(dtT, alog, acum);

  ssm_chunk_k<<<dim3(NH, NC, BB), 256, 0, stream>>>(hbc, dtT, acum, Y, states);
  scan_k<<<dim3(NH, BB), 256, 0, stream>>>(states, acum);
  combine_k<<<dim3(NH, NC, BB), 256, 0, stream>>>(hbc, acum, states, Dv, Y);

  norm_k<<<dim3(BS), 256, 0, stream>>>(Y, projb, nw, normed);

  gemm_bt_k<<<dim3((HID_DIM / 128) * (BS / 128)), 256, 0, stream>>>(normed, w2b, out, BS, HID_DIM, INTER, 0, HID_DIM / 128);
}

// Round 4
// 1515.952 us; speedup vs baseline: 1.3803x; 1.3547x over previous
//
#include <hip/hip_runtime.h>
#include <hip/hip_bf16.h>
#include <cstdint>
#include <cstddef>

#define DEVI __device__ __forceinline__

#define BB 2
#define S_LEN 2048
#define HID_DIM 4096
#define NH 128
#define PD 64
#define NS 128
#define NG 8
#define INTER 8192
#define CONVD 10240
#define PROJ 18560
#define PROJP 18688   // padded to 73*256 for 256-wide GEMM tiles
#define NC 16
#define BS 4096
#define GN 1024   // NG*NS

using short8 = __attribute__((ext_vector_type(8))) short;
using short4v = __attribute__((ext_vector_type(4))) short;
using f32x4  = __attribute__((ext_vector_type(4))) float;
using bf16x8 = __attribute__((ext_vector_type(8))) __bf16;

DEVI float bf2f(short u) {
  union { unsigned int i; float f; } v;
  v.i = ((unsigned int)(unsigned short)u) << 16;
  return v.f;
}
DEVI short f2bf(float f) {
  union { float ff; unsigned int i; } v; v.ff = f;
  unsigned int x = v.i;
  return (short)((x + 0x7fffu + ((x >> 16) & 1u)) >> 16);
}
DEVI f32x4 mfma16(short8 a, short8 b, f32x4 c) {
  return __builtin_amdgcn_mfma_f32_16x16x32_bf16(
      __builtin_bit_cast(bf16x8, a), __builtin_bit_cast(bf16x8, b), c, 0, 0, 0);
}
DEVI void gl_lds16(const short* g, short* l) {
  __builtin_amdgcn_global_load_lds(
      (const __attribute__((address_space(1))) void*)g,
      (__attribute__((address_space(3))) void*)l, 16, 0, 0);
}
DEVI float sigmoidf_(float x) { return 1.f / (1.f + __expf(-x)); }

// ---------------------------------------------------------------- converts
__global__ __launch_bounds__(256) void cvt_f32_bf16_k(const float* __restrict__ in,
                                                      short* __restrict__ out, size_t n) {
  size_t i = ((size_t)blockIdx.x * 256 + threadIdx.x) * 8;
  if (i + 8 > n) return;
  float4 a = *(const float4*)(in + i);
  float4 b = *(const float4*)(in + i + 4);
  short8 o;
  o[0] = f2bf(a.x); o[1] = f2bf(a.y); o[2] = f2bf(a.z); o[3] = f2bf(a.w);
  o[4] = f2bf(b.x); o[5] = f2bf(b.y); o[6] = f2bf(b.z); o[7] = f2bf(b.w);
  *(short8*)(out + i) = o;
}

// ---------------------------------------------------------------- 256x256 8-phase GEMM
// C[M,N] = A[M,K](bf16,row) * Bt[N,K](bf16,row)^T
// 512 thr = 8 waves (2M x 4N); BK=64 split in two K-halves; LDS = 8 regions of
// 16KB (A/B x dbuf x khalf), total 128KB. Regions swizzled: 16B slot ^= (row>>1)&3
// (2-way bank aliasing = free). Staged via global_load_lds with pre-swizzled
// global source (linear LDS dest, wave-uniform base). vmcnt(6) at phases 4/8 only.
//
// Region liveness (iter computes tiles t[buf0], t+1[buf1]; stages t+2,t+3):
//  ph1 R:A00,B00  S:A11<-t+1 | ph2 R:A00 S:B00<-t+2 | ph3 R:A01,B01 S:A00<-t+2
//  ph4 R:A01 S:B01<-t+2 VM6  | ph5 R:A10,B10 S:A01<-t+2 | ph6 R:A10 S:B10<-t+3
//  ph7 R:A11,B11 S:A10<-t+3  | ph8 R:A11 S:B11<-t+3 VM6
// Epilogue MUST still stage A11<-NT-1 at its ph1 (steady-state stages it in the
// NEXT iteration's ph1) — missing this was round-3's stale-tile bug.

#define STG(ISB, BUF, KH, TILE) do { \
  const short* _src = (ISB) ? Bt : A; \
  const int _r0 = (ISB) ? n0 : m0; \
  short* _lb = lds_ + ((ISB) ? 32768 : 0) + ((BUF)*2+(KH))*8192; \
  const int _kt = (TILE)*64 + (KH)*32; \
  { int _row = (wid*2)*16 + srow; int _sl = sps ^ ((_row>>1)&3); \
    gl_lds16(_src + (size_t)(_r0+_row)*K + _kt + _sl*8, _lb + (wid*2)*512); } \
  { int _row = (wid*2+1)*16 + srow; int _sl = sps ^ ((_row>>1)&3); \
    gl_lds16(_src + (size_t)(_r0+_row)*K + _kt + _sl*8, _lb + (wid*2+1)*512); } \
} while(0)

#define NOPS ((void)0)
#define VM6 asm volatile("s_waitcnt vmcnt(6)" ::: "memory")
#define VM0 asm volatile("s_waitcnt vmcnt(0)" ::: "memory")

#define PH(BUF, KH, MIH, DOB, STGS, VMW) do { \
  _Pragma("unroll") \
  for (int _m = 0; _m < 4; ++_m) { \
    int _row = wr*128 + ((MIH)*4+_m)*16 + fr; \
    af[_m] = *(const short8*)(lds_ + ((BUF)*2+(KH))*8192 + _row*32 + ((slot ^ ((_row>>1)&3))<<3)); \
  } \
  if (DOB) { \
    _Pragma("unroll") \
    for (int _n = 0; _n < 4; ++_n) { \
      int _row = wc*64 + _n*16 + fr; \
      bf_[_n] = *(const short8*)(lds_ + 32768 + ((BUF)*2+(KH))*8192 + _row*32 + ((slot ^ ((_row>>1)&3))<<3)); \
    } \
  } \
  STGS; VMW; \
  __builtin_amdgcn_s_barrier(); \
  asm volatile("s_waitcnt lgkmcnt(0)" ::: "memory"); \
  __builtin_amdgcn_sched_barrier(0); \
  __builtin_amdgcn_s_setprio(1); \
  _Pragma("unroll") \
  for (int _m = 0; _m < 4; ++_m) \
    _Pragma("unroll") \
    for (int _n = 0; _n < 4; ++_n) \
      acc[(MIH)*4+_m][_n] = mfma16(af[_m], bf_[_n], acc[(MIH)*4+_m][_n]); \
  __builtin_amdgcn_s_setprio(0); \
  __builtin_amdgcn_s_barrier(); \
} while(0)

template<int CB16>
__global__ __launch_bounds__(512, 2) void gemm256_k(const short* __restrict__ A,
                                                    const short* __restrict__ Bt,
                                                    void* __restrict__ Cout,
                                                    int Nstride, int K, int ntn) {
  __shared__ short lds_[65536];  // 128 KiB
  const int tid = threadIdx.x, wid = tid >> 6, lane = tid & 63;
  // XCD-bijective chunk + GM=8 m-supertile decode
  const int nwg = gridDim.x, orig = blockIdx.x;
  const int swz = (orig & 7) * (nwg >> 3) + (orig >> 3);
  const int per_group = ntn << 3;
  const int group = swz / per_group;
  const int rem = swz - group * per_group;
  const int m0 = (group * 8 + (rem & 7)) * 256;
  const int n0 = (rem >> 3) * 256;
  const int wr = wid >> 2, wc = wid & 3;
  const int fr = lane & 15, slot = lane >> 4;
  const int srow = lane >> 2, sps = lane & 3;

  f32x4 acc[8][4] = {};
  short8 af[4], bf_[4];
  const int NT = K >> 6;

  // prologue: tile 0 (4 halves) + tile 1 (3 halves); A buf1 kh1 of tile 1 staged at ph1
  STG(1, 0, 0, 0); STG(0, 0, 0, 0); STG(1, 0, 1, 0); STG(0, 0, 1, 0);
  asm volatile("s_waitcnt vmcnt(4)" ::: "memory");
  STG(1, 1, 0, 1); STG(0, 1, 0, 1); STG(1, 1, 1, 1);
  asm volatile("s_waitcnt vmcnt(6)" ::: "memory");
  __builtin_amdgcn_s_barrier();

  for (int i = 0; i < (NT >> 1) - 1; ++i) {
    const int t = 2 * i;
    PH(0, 0, 0, 1, STG(0, 1, 1, t + 1), NOPS);
    PH(0, 0, 1, 0, STG(1, 0, 0, t + 2), NOPS);
    PH(0, 1, 0, 1, STG(0, 0, 0, t + 2), NOPS);
    PH(0, 1, 1, 0, STG(1, 0, 1, t + 2), VM6);
    PH(1, 0, 0, 1, STG(0, 0, 1, t + 2), NOPS);
    PH(1, 0, 1, 0, STG(1, 1, 0, t + 3), NOPS);
    PH(1, 1, 0, 1, STG(0, 1, 0, t + 3), NOPS);
    PH(1, 1, 1, 0, STG(1, 1, 1, t + 3), VM6);
  }
  // epilogue: stage the missing A buf1 kh1 <- NT-1 at ph1; drain all at ph4.
  PH(0, 0, 0, 1, STG(0, 1, 1, NT - 1), NOPS);
  PH(0, 0, 1, 0, NOPS, NOPS);
  PH(0, 1, 0, 1, NOPS, NOPS);
  PH(0, 1, 1, 0, NOPS, VM0);
  PH(1, 0, 0, 1, NOPS, NOPS);
  PH(1, 0, 1, 0, NOPS, NOPS);
  PH(1, 1, 0, 1, NOPS, NOPS);
  PH(1, 1, 1, 0, NOPS, NOPS);

  const int er = (lane >> 4) * 4, ec = lane & 15;
  if (CB16) {
    short* C = (short*)Cout;
#pragma unroll
    for (int mi = 0; mi < 8; ++mi)
#pragma unroll
      for (int j = 0; j < 4; ++j) {
        size_t base = (size_t)(m0 + wr * 128 + mi * 16 + er + j) * Nstride + n0 + wc * 64 + ec;
#pragma unroll
        for (int ni = 0; ni < 4; ++ni) C[base + ni * 16] = f2bf(acc[mi][ni][j]);
      }
  } else {
    float* C = (float*)Cout;
#pragma unroll
    for (int mi = 0; mi < 8; ++mi)
#pragma unroll
      for (int j = 0; j < 4; ++j) {
        size_t base = (size_t)(m0 + wr * 128 + mi * 16 + er + j) * Nstride + n0 + wc * 64 + ec;
#pragma unroll
        for (int ni = 0; ni < 4; ++ni) C[base + ni * 16] = acc[mi][ni][j];
      }
  }
}

// ---------------------------------------------------------------- conv + silu
__global__ __launch_bounds__(256) void conv_silu_k(const short* __restrict__ projb,
                                                   const float* __restrict__ convw,
                                                   const float* __restrict__ convb,
                                                   short* __restrict__ hbc) {
  const int c = blockIdx.x * 256 + threadIdx.x;
  const int s = blockIdx.y, b = blockIdx.z;
  const size_t rb = (size_t)b * S_LEN;
  const float* wp = convw + (size_t)c * 4;
  float w0 = wp[0], w1 = wp[1], w2 = wp[2], w3 = wp[3];
  float acc = convb[c];
  if (s >= 3) acc += bf2f(projb[(rb + s - 3) * PROJP + INTER + c]) * w0;
  if (s >= 2) acc += bf2f(projb[(rb + s - 2) * PROJP + INTER + c]) * w1;
  if (s >= 1) acc += bf2f(projb[(rb + s - 1) * PROJP + INTER + c]) * w2;
  acc += bf2f(projb[(rb + s) * PROJP + INTER + c]) * w3;
  float o = acc * sigmoidf_(acc);
  hbc[(rb + s) * CONVD + c] = f2bf(o);
}

// ---------------------------------------------------------------- dt (softplus, transposed store)
__global__ __launch_bounds__(128) void dt_k(const short* __restrict__ projb,
                                            const float* __restrict__ dt_bias,
                                            float* __restrict__ dtT) {
  const int h = threadIdx.x;
  const int r = blockIdx.x;  // 0..BS-1
  float x = bf2f(projb[(size_t)r * PROJP + INTER + CONVD + h]) + dt_bias[h];
  float sp = (x > 20.f) ? x : log1pf(__expf(x));
  sp = fminf(fmaxf(sp, 0.f), 100.f);
  const int b = r / S_LEN, s = r - b * S_LEN;
  dtT[((size_t)(b * NH + h)) * S_LEN + s] = sp;
}

// ---------------------------------------------------------------- per-chunk cumsum of dt*A
__global__ __launch_bounds__(128) void acum_k(const float* __restrict__ dtT,
                                              const float* __restrict__ A_log,
                                              float* __restrict__ acum) {
  const int l = threadIdx.x;
  const int z = blockIdx.x, h = blockIdx.y, b = blockIdx.z;
  const float A = -__expf(A_log[h]);
  __shared__ float sv[128];
  const size_t base = ((size_t)(b * NH + h)) * S_LEN + z * 128;
  sv[l] = dtT[base + l] * A;
  __syncthreads();
  for (int off = 1; off < 128; off <<= 1) {
    float t = (l >= off) ? sv[l - off] : 0.f;
    __syncthreads();
    sv[l] += t;
    __syncthreads();
  }
  acum[base + l] = sv[l];
}

// ---------------------------------------------------------------- SSD per-(b,z,h): Y_diag + states
__global__ __launch_bounds__(256) void ssm_chunk_k(const short* __restrict__ hbc,
                                                   const float* __restrict__ dtT,
                                                   const float* __restrict__ acum,
                                                   float* __restrict__ Y,
                                                   float* __restrict__ states) {
  __shared__ short sCP[128 * 128];  // C, then P
  __shared__ short sB[128 * 128];
  __shared__ short sxT[64 * 128];   // [p][s] of hs*dt
  const int tid = threadIdx.x, wid = tid >> 6, lane = tid & 63;
  const int h = blockIdx.x, z = blockIdx.y, b = blockIdx.z;
  const int g = h >> 4;
  const size_t srow0 = (size_t)(b * S_LEN + z * 128);
  const short* hrow = hbc + srow0 * CONVD;
  const float* ac = acum + ((size_t)(b * NH + h)) * S_LEN + z * 128;
  const float* dts = dtT + ((size_t)(b * NH + h)) * S_LEN + z * 128;

  {
    const int n0 = (tid & 15) * 8;
    const int sr = tid >> 4;
#pragma unroll
    for (int it = 0; it < 8; ++it) {
      int s = it * 16 + sr;
      gl_lds16(hrow + (size_t)s * CONVD + INTER + GN + g * NS + n0, sCP + it * 2048 + wid * 512);
      gl_lds16(hrow + (size_t)s * CONVD + INTER + g * NS + n0, sB + it * 2048 + wid * 512);
    }
  }
#pragma unroll
  for (int it = 0; it < 4; ++it) {
    int e = it * 256 + tid;
    int s = e >> 3;
    int p0 = (e & 7) * 8;
    short8 hv = *(const short8*)(hrow + (size_t)s * CONVD + (size_t)h * PD + p0);
    float dv = dts[s];
#pragma unroll
    for (int j = 0; j < 8; ++j) sxT[(p0 + j) * 128 + s] = f2bf(bf2f(hv[j]) * dv);
  }
  __syncthreads();

  const int fr = lane & 15, fk8 = (lane >> 4) * 8;
  const int er = (lane >> 4) * 4, ec = lane & 15;

  // scores = C * B^T over n
  f32x4 sc[2][8] = {};
#pragma unroll
  for (int kk = 0; kk < 4; ++kk) {
    short8 a0 = *(const short8*)(sCP + (wid * 32 + fr) * 128 + kk * 32 + fk8);
    short8 a1 = *(const short8*)(sCP + (wid * 32 + 16 + fr) * 128 + kk * 32 + fk8);
#pragma unroll
    for (int ni = 0; ni < 8; ++ni) {
      short8 bv = *(const short8*)(sB + (ni * 16 + fr) * 128 + kk * 32 + fk8);
      sc[0][ni] = mfma16(a0, bv, sc[0][ni]);
      sc[1][ni] = mfma16(a1, bv, sc[1][ni]);
    }
  }
  // mask with L and write P into sCP band (each wave only touches its own rows)
  {
    float acS[8];
#pragma unroll
    for (int ni = 0; ni < 8; ++ni) acS[ni] = ac[ni * 16 + ec];
#pragma unroll
    for (int mi = 0; mi < 2; ++mi)
#pragma unroll
      for (int j = 0; j < 4; ++j) {
        int l = wid * 32 + mi * 16 + er + j;
        float acl = ac[l];
#pragma unroll
        for (int ni = 0; ni < 8; ++ni) {
          int s = ni * 16 + ec;
          float v = (s <= l) ? sc[mi][ni][j] * __expf(acl - acS[ni]) : 0.f;
          sCP[l * 128 + s] = f2bf(v);
        }
      }
  }
  __syncthreads();

  // Y_diag = P @ xdt
  {
    f32x4 yd[2][4] = {};
#pragma unroll
    for (int kk = 0; kk < 4; ++kk) {
      short8 a0 = *(const short8*)(sCP + (wid * 32 + fr) * 128 + kk * 32 + fk8);
      short8 a1 = *(const short8*)(sCP + (wid * 32 + 16 + fr) * 128 + kk * 32 + fk8);
#pragma unroll
      for (int ni = 0; ni < 4; ++ni) {
        short8 bv = *(const short8*)(sxT + (ni * 16 + fr) * 128 + kk * 32 + fk8);
        yd[0][ni] = mfma16(a0, bv, yd[0][ni]);
        yd[1][ni] = mfma16(a1, bv, yd[1][ni]);
      }
    }
#pragma unroll
    for (int mi = 0; mi < 2; ++mi)
#pragma unroll
      for (int ni = 0; ni < 4; ++ni)
#pragma unroll
        for (int j = 0; j < 4; ++j) {
          int l = wid * 32 + mi * 16 + er + j;
          int p = ni * 16 + ec;
          Y[(srow0 + l) * (size_t)INTER + (size_t)h * PD + p] = yd[mi][ni][j];
        }
  }

  // states[n][p] = sum_l B[l][n]*decay[l]*xdt[l][p]
  {
    const float acLast = ac[127];
    f32x4 st[2][4] = {};
#pragma unroll
    for (int kk = 0; kk < 4; ++kk) {
      short8 a0, a1;
      const int na = wid * 32 + fr;
#pragma unroll
      for (int j = 0; j < 8; ++j) {
        int l = kk * 32 + fk8 + j;
        float dec = __expf(acLast - ac[l]);
        a0[j] = f2bf(bf2f(sB[l * 128 + na]) * dec);
        a1[j] = f2bf(bf2f(sB[l * 128 + na + 16]) * dec);
      }
#pragma unroll
      for (int ni = 0; ni < 4; ++ni) {
        short8 bv = *(const short8*)(sxT + (ni * 16 + fr) * 128 + kk * 32 + fk8);
        st[0][ni] = mfma16(a0, bv, st[0][ni]);
        st[1][ni] = mfma16(a1, bv, st[1][ni]);
      }
    }
    float* stp = states + (((size_t)(b * NC + z)) * NH + h) * (size_t)(NS * PD);
#pragma unroll
    for (int mi = 0; mi < 2; ++mi)
#pragma unroll
      for (int ni = 0; ni < 4; ++ni)
#pragma unroll
        for (int j = 0; j < 4; ++j) {
          int n = wid * 32 + mi * 16 + er + j;
          int p = ni * 16 + ec;
          stp[n * PD + p] = st[mi][ni][j];
        }
  }
}

// ---------------------------------------------------------------- inter-chunk scan (in-place, transposes to [p][n])
__global__ __launch_bounds__(256) void scan_k(float* __restrict__ states,
                                              const float* __restrict__ acum) {
  const int h = blockIdx.x, b = blockIdx.y;
  const int tid = threadIdx.x;
  float* stp = states + ((size_t)(b * NC * NH) + h) * (size_t)(NS * PD);
  const size_t cst = (size_t)NH * NS * PD;
  const float* ac = acum + ((size_t)(b * NH + h)) * S_LEN;
  float E[32];
#pragma unroll
  for (int i = 0; i < 32; ++i) E[i] = 0.f;
  for (int zz = 0; zz < NC; ++zz) {
    float* sz = stp + (size_t)zz * cst;
    float tmp[32];
#pragma unroll
    for (int i = 0; i < 32; ++i) tmp[i] = sz[i * 256 + tid];
    __syncthreads();
    float dec = __expf(ac[zz * 128 + 127]);
#pragma unroll
    for (int i = 0; i < 32; ++i) {
      int e = i * 256 + tid;
      int n = e >> 6, p = e & 63;
      sz[p * NS + n] = E[i];          // prev state entering chunk zz, [p][n]
      E[i] = dec * E[i] + tmp[i];
    }
    __syncthreads();
  }
}

// ---------------------------------------------------------------- combine: Y += exp(Acum)*C@prev^T + hs*D
__global__ __launch_bounds__(256) void combine_k(const short* __restrict__ hbc,
                                                 const float* __restrict__ acum,
                                                 const float* __restrict__ states,
                                                 const float* __restrict__ Dv,
                                                 float* __restrict__ Y) {
  __shared__ short sC[128 * 128];
  __shared__ short sPrev[64 * 128];  // [p][n]
  const int tid = threadIdx.x, wid = tid >> 6, lane = tid & 63;
  const int h = blockIdx.x, z = blockIdx.y, b = blockIdx.z;
  const int g = h >> 4;
  const size_t srow0 = (size_t)(b * S_LEN + z * 128);
  const short* hrow = hbc + srow0 * CONVD;
  const float* ac = acum + ((size_t)(b * NH + h)) * S_LEN + z * 128;
  const float* pv = states + (((size_t)(b * NC + z)) * NH + h) * (size_t)(NS * PD);

  {
    const int n0 = (tid & 15) * 8;
    const int sr = tid >> 4;
#pragma unroll
    for (int it = 0; it < 8; ++it) {
      int s = it * 16 + sr;
      gl_lds16(hrow + (size_t)s * CONVD + INTER + GN + g * NS + n0, sC + it * 2048 + wid * 512);
    }
  }
#pragma unroll
  for (int it = 0; it < 8; ++it) {
    int e = (it * 256 + tid) * 4;
    float4 v = *(const float4*)(pv + e);
    short4v o;
    o[0] = f2bf(v.x); o[1] = f2bf(v.y); o[2] = f2bf(v.z); o[3] = f2bf(v.w);
    *(short4v*)(sPrev + e) = o;
  }
  __syncthreads();

  const int fr = lane & 15, fk8 = (lane >> 4) * 8;
  const int er = (lane >> 4) * 4, ec = lane & 15;
  f32x4 off[2][4] = {};
#pragma unroll
  for (int kk = 0; kk < 4; ++kk) {
    short8 a0 = *(const short8*)(sC + (wid * 32 + fr) * 128 + kk * 32 + fk8);
    short8 a1 = *(const short8*)(sC + (wid * 32 + 16 + fr) * 128 + kk * 32 + fk8);
#pragma unroll
    for (int ni = 0; ni < 4; ++ni) {
      short8 bv = *(const short8*)(sPrev + (ni * 16 + fr) * 128 + kk * 32 + fk8);
      off[0][ni] = mfma16(a0, bv, off[0][ni]);
      off[1][ni] = mfma16(a1, bv, off[1][ni]);
    }
  }
  const float Dh = Dv[h];
#pragma unroll
  for (int mi = 0; mi < 2; ++mi)
#pragma unroll
    for (int j = 0; j < 4; ++j) {
      int l = wid * 32 + mi * 16 + er + j;
      float e_ac = __expf(ac[l]);
#pragma unroll
      for (int ni = 0; ni < 4; ++ni) {
        int p = ni * 16 + ec;
        size_t yi = (srow0 + l) * (size_t)INTER + (size_t)h * PD + p;
        float hs = bf2f(hrow[(size_t)l * CONVD + (size_t)h * PD + p]);
        Y[yi] = Y[yi] + off[mi][ni][j] * e_ac + hs * Dh;
      }
    }
}

// ---------------------------------------------------------------- gated group RMS norm -> bf16
__global__ __launch_bounds__(256) void norm_k(const float* __restrict__ Y,
                                              const short* __restrict__ projb,
                                              const float* __restrict__ norm_w,
                                              short* __restrict__ outn) {
  const int r = blockIdx.x;
  const int tid = threadIdx.x;
  const int gi = tid >> 5, li = tid & 31;
  const float* yrow = Y + (size_t)r * INTER;
  const short* grow = projb + (size_t)r * PROJP;
  const int e0 = gi * 1024 + li * 32;
  float gv[32];
  float ss = 0.f;
#pragma unroll
  for (int j4 = 0; j4 < 32; j4 += 4) {
    float4 yv = *(const float4*)(yrow + e0 + j4);
    short4v gt = *(const short4v*)(grow + e0 + j4);
    float ys[4] = {yv.x, yv.y, yv.z, yv.w};
#pragma unroll
    for (int q = 0; q < 4; ++q) {
      float gate = bf2f(gt[q]);
      float gg = ys[q] * gate * sigmoidf_(gate);
      gv[j4 + q] = gg;
      ss += gg * gg;
    }
  }
#pragma unroll
  for (int m = 16; m >= 1; m >>= 1) ss += __shfl_xor(ss, m, 64);
  const float scale = rsqrtf(ss * (1.f / 1024.f) + 1e-5f);
#pragma unroll
  for (int j4 = 0; j4 < 32; j4 += 4) {
    short4v o;
#pragma unroll
    for (int q = 0; q < 4; ++q) o[q] = f2bf(gv[j4 + q] * scale * norm_w[e0 + j4 + q]);
    *(short4v*)(outn + (size_t)r * INTER + e0 + j4) = o;
  }
}

// ----------------------------------------------------------------
extern "C" void kernel_launch(void* const* d_in, const int* in_sizes, int n_in,
                              void* d_out, int out_size, void* d_ws, size_t ws_size,
                              hipStream_t stream) {
  const float* x     = (const float*)d_in[0];
  const float* w1    = (const float*)d_in[1];
  const float* convw = (const float*)d_in[2];
  const float* convb = (const float*)d_in[3];
  const float* dtb   = (const float*)d_in[4];
  const float* alog  = (const float*)d_in[5];
  const float* Dv    = (const float*)d_in[6];
  const float* nw    = (const float*)d_in[7];
  const float* w2    = (const float*)d_in[8];
  float* out = (float*)d_out;

  char* ws = (char*)d_ws;
  size_t off = 0;
  float* dtT = (float*)(ws + off);  off += (size_t)BB * NH * S_LEN * 4;
  float* acum = (float*)(ws + off); off += (size_t)BB * NH * S_LEN * 4;
  short* xb = (short*)(ws + off);   off += (size_t)BS * HID_DIM * 2;
  char* w1region = ws + off;        off += (size_t)PROJP * HID_DIM * 2;
  short* w1b = (short*)w1region;    // 18688 rows x 4096 (rows >= 18560 stay garbage; pad C-cols never read)
  short* normed = (short*)w1region;                              // reuse after gemm1
  short* w2b = (short*)(w1region + (size_t)BS * INTER * 2);      // reuse after gemm1
  short* projb = (short*)(ws + off); off += (size_t)BS * PROJP * 2;
  short* hbc = (short*)(ws + off);   off += (size_t)BS * CONVD * 2;
  float* Y = (float*)(ws + off);     off += (size_t)BS * INTER * 4;
  float* states = (float*)(ws + off); off += (size_t)BB * NC * NH * NS * PD * 4;

  const size_t nx = (size_t)BS * HID_DIM;
  const size_t nw1 = (size_t)PROJ * HID_DIM;
  const size_t nw2 = (size_t)HID_DIM * INTER;

  cvt_f32_bf16_k<<<dim3(nx / 2048), 256, 0, stream>>>(x, xb, nx);
  cvt_f32_bf16_k<<<dim3(nw1 / 2048), 256, 0, stream>>>(w1, w1b, nw1);

  // gemm1: [4096 x 18560(pad 18688)] = xb[4096x4096] * w1b^T ; 16 x 73 tiles
  gemm256_k<1><<<dim3(16 * 73), 512, 0, stream>>>(xb, w1b, projb, PROJP, HID_DIM, 73);

  // w1b dead now; stage w2 into its region
  cvt_f32_bf16_k<<<dim3(nw2 / 2048), 256, 0, stream>>>(w2, w2b, nw2);

  conv_silu_k<<<dim3(CONVD / 256, S_LEN, BB), 256, 0, stream>>>(projb, convw, convb, hbc);
  dt_k<<<dim3(BS), 128, 0, stream>>>(projb, dtb, dtT);
  acum_k<<<dim3(NC, NH, BB), 128, 0, stream>>>(dtT, alog, acum);

  ssm_chunk_k<<<dim3(NH, NC, BB), 256, 0, stream>>>(hbc, dtT, acum, Y, states);
  scan_k<<<dim3(NH, BB), 256, 0, stream>>>(states, acum);
  combine_k<<<dim3(NH, NC, BB), 256, 0, stream>>>(hbc, acum, states, Dv, Y);

  norm_k<<<dim3(BS), 256, 0, stream>>>(Y, projb, nw, normed);

  // gemm2: [4096 x 4096] = normed[4096x8192] * w2b^T ; 16 x 16 tiles
  gemm256_k<0><<<dim3(16 * 16), 512, 0, stream>>>(normed, w2b, out, HID_DIM, INTER, 16);
}

// Round 5
// 1476.962 us; speedup vs baseline: 1.4168x; 1.0264x over previous
//
#include <hip/hip_runtime.h>
#include <hip/hip_bf16.h>
#include <cstdint>
#include <cstddef>

#define DEVI __device__ __forceinline__

#define BB 2
#define S_LEN 2048
#define HID_DIM 4096
#define NH 128
#define PD 64
#define NS 128
#define NG 8
#define INTER 8192
#define CONVD 10240
#define PROJ 18560
#define PROJP 18688   // padded to 73*256 for 256-wide GEMM tiles
#define NC 16
#define BS 4096
#define GN 1024   // NG*NS

using short8 = __attribute__((ext_vector_type(8))) short;
using short4v = __attribute__((ext_vector_type(4))) short;
using f32x4  = __attribute__((ext_vector_type(4))) float;
using bf16x8 = __attribute__((ext_vector_type(8))) __bf16;

DEVI float bf2f(short u) {
  union { unsigned int i; float f; } v;
  v.i = ((unsigned int)(unsigned short)u) << 16;
  return v.f;
}
DEVI short f2bf(float f) {
  union { float ff; unsigned int i; } v; v.ff = f;
  unsigned int x = v.i;
  return (short)((x + 0x7fffu + ((x >> 16) & 1u)) >> 16);
}
DEVI f32x4 mfma16(short8 a, short8 b, f32x4 c) {
  return __builtin_amdgcn_mfma_f32_16x16x32_bf16(
      __builtin_bit_cast(bf16x8, a), __builtin_bit_cast(bf16x8, b), c, 0, 0, 0);
}
DEVI void gl_lds16(const short* g, short* l) {
  __builtin_amdgcn_global_load_lds(
      (const __attribute__((address_space(1))) void*)g,
      (__attribute__((address_space(3))) void*)l, 16, 0, 0);
}
DEVI float sigmoidf_(float x) { return 1.f / (1.f + __expf(-x)); }

// ---------------------------------------------------------------- converts
__global__ __launch_bounds__(256) void cvt_f32_bf16_k(const float* __restrict__ in,
                                                      short* __restrict__ out, size_t n) {
  size_t i = ((size_t)blockIdx.x * 256 + threadIdx.x) * 8;
  if (i + 8 > n) return;
  float4 a = *(const float4*)(in + i);
  float4 b = *(const float4*)(in + i + 4);
  short8 o;
  o[0] = f2bf(a.x); o[1] = f2bf(a.y); o[2] = f2bf(a.z); o[3] = f2bf(a.w);
  o[4] = f2bf(b.x); o[5] = f2bf(b.y); o[6] = f2bf(b.z); o[7] = f2bf(b.w);
  *(short8*)(out + i) = o;
}

// ---------------------------------------------------------------- 256x256 8-phase GEMM
// (unchanged from round 4 — see liveness ledger in comments)

#define STG(ISB, BUF, KH, TILE) do { \
  const short* _src = (ISB) ? Bt : A; \
  const int _r0 = (ISB) ? n0 : m0; \
  short* _lb = lds_ + ((ISB) ? 32768 : 0) + ((BUF)*2+(KH))*8192; \
  const int _kt = (TILE)*64 + (KH)*32; \
  { int _row = (wid*2)*16 + srow; int _sl = sps ^ ((_row>>1)&3); \
    gl_lds16(_src + (size_t)(_r0+_row)*K + _kt + _sl*8, _lb + (wid*2)*512); } \
  { int _row = (wid*2+1)*16 + srow; int _sl = sps ^ ((_row>>1)&3); \
    gl_lds16(_src + (size_t)(_r0+_row)*K + _kt + _sl*8, _lb + (wid*2+1)*512); } \
} while(0)

#define NOPS ((void)0)
#define VM6 asm volatile("s_waitcnt vmcnt(6)" ::: "memory")
#define VM0 asm volatile("s_waitcnt vmcnt(0)" ::: "memory")

#define PH(BUF, KH, MIH, DOB, STGS, VMW) do { \
  _Pragma("unroll") \
  for (int _m = 0; _m < 4; ++_m) { \
    int _row = wr*128 + ((MIH)*4+_m)*16 + fr; \
    af[_m] = *(const short8*)(lds_ + ((BUF)*2+(KH))*8192 + _row*32 + ((slot ^ ((_row>>1)&3))<<3)); \
  } \
  if (DOB) { \
    _Pragma("unroll") \
    for (int _n = 0; _n < 4; ++_n) { \
      int _row = wc*64 + _n*16 + fr; \
      bf_[_n] = *(const short8*)(lds_ + 32768 + ((BUF)*2+(KH))*8192 + _row*32 + ((slot ^ ((_row>>1)&3))<<3)); \
    } \
  } \
  STGS; VMW; \
  __builtin_amdgcn_s_barrier(); \
  asm volatile("s_waitcnt lgkmcnt(0)" ::: "memory"); \
  __builtin_amdgcn_sched_barrier(0); \
  __builtin_amdgcn_s_setprio(1); \
  _Pragma("unroll") \
  for (int _m = 0; _m < 4; ++_m) \
    _Pragma("unroll") \
    for (int _n = 0; _n < 4; ++_n) \
      acc[(MIH)*4+_m][_n] = mfma16(af[_m], bf_[_n], acc[(MIH)*4+_m][_n]); \
  __builtin_amdgcn_s_setprio(0); \
  __builtin_amdgcn_s_barrier(); \
} while(0)

template<int CB16>
__global__ __launch_bounds__(512, 2) void gemm256_k(const short* __restrict__ A,
                                                    const short* __restrict__ Bt,
                                                    void* __restrict__ Cout,
                                                    int Nstride, int K, int ntn) {
  __shared__ short lds_[65536];  // 128 KiB
  const int tid = threadIdx.x, wid = tid >> 6, lane = tid & 63;
  const int nwg = gridDim.x, orig = blockIdx.x;
  const int swz = (orig & 7) * (nwg >> 3) + (orig >> 3);
  const int per_group = ntn << 3;
  const int group = swz / per_group;
  const int rem = swz - group * per_group;
  const int m0 = (group * 8 + (rem & 7)) * 256;
  const int n0 = (rem >> 3) * 256;
  const int wr = wid >> 2, wc = wid & 3;
  const int fr = lane & 15, slot = lane >> 4;
  const int srow = lane >> 2, sps = lane & 3;

  f32x4 acc[8][4] = {};
  short8 af[4], bf_[4];
  const int NT = K >> 6;

  STG(1, 0, 0, 0); STG(0, 0, 0, 0); STG(1, 0, 1, 0); STG(0, 0, 1, 0);
  asm volatile("s_waitcnt vmcnt(4)" ::: "memory");
  STG(1, 1, 0, 1); STG(0, 1, 0, 1); STG(1, 1, 1, 1);
  asm volatile("s_waitcnt vmcnt(6)" ::: "memory");
  __builtin_amdgcn_s_barrier();

  for (int i = 0; i < (NT >> 1) - 1; ++i) {
    const int t = 2 * i;
    PH(0, 0, 0, 1, STG(0, 1, 1, t + 1), NOPS);
    PH(0, 0, 1, 0, STG(1, 0, 0, t + 2), NOPS);
    PH(0, 1, 0, 1, STG(0, 0, 0, t + 2), NOPS);
    PH(0, 1, 1, 0, STG(1, 0, 1, t + 2), VM6);
    PH(1, 0, 0, 1, STG(0, 0, 1, t + 2), NOPS);
    PH(1, 0, 1, 0, STG(1, 1, 0, t + 3), NOPS);
    PH(1, 1, 0, 1, STG(0, 1, 0, t + 3), NOPS);
    PH(1, 1, 1, 0, STG(1, 1, 1, t + 3), VM6);
  }
  PH(0, 0, 0, 1, STG(0, 1, 1, NT - 1), NOPS);
  PH(0, 0, 1, 0, NOPS, NOPS);
  PH(0, 1, 0, 1, NOPS, NOPS);
  PH(0, 1, 1, 0, NOPS, VM0);
  PH(1, 0, 0, 1, NOPS, NOPS);
  PH(1, 0, 1, 0, NOPS, NOPS);
  PH(1, 1, 0, 1, NOPS, NOPS);
  PH(1, 1, 1, 0, NOPS, NOPS);

  const int er = (lane >> 4) * 4, ec = lane & 15;
  if (CB16) {
    short* C = (short*)Cout;
#pragma unroll
    for (int mi = 0; mi < 8; ++mi)
#pragma unroll
      for (int j = 0; j < 4; ++j) {
        size_t base = (size_t)(m0 + wr * 128 + mi * 16 + er + j) * Nstride + n0 + wc * 64 + ec;
#pragma unroll
        for (int ni = 0; ni < 4; ++ni) C[base + ni * 16] = f2bf(acc[mi][ni][j]);
      }
  } else {
    float* C = (float*)Cout;
#pragma unroll
    for (int mi = 0; mi < 8; ++mi)
#pragma unroll
      for (int j = 0; j < 4; ++j) {
        size_t base = (size_t)(m0 + wr * 128 + mi * 16 + er + j) * Nstride + n0 + wc * 64 + ec;
#pragma unroll
        for (int ni = 0; ni < 4; ++ni) C[base + ni * 16] = acc[mi][ni][j];
      }
  }
}

// ---------------------------------------------------------------- conv + silu
__global__ __launch_bounds__(256) void conv_silu_k(const short* __restrict__ projb,
                                                   const float* __restrict__ convw,
                                                   const float* __restrict__ convb,
                                                   short* __restrict__ hbc) {
  const int c = blockIdx.x * 256 + threadIdx.x;
  const int s = blockIdx.y, b = blockIdx.z;
  const size_t rb = (size_t)b * S_LEN;
  const float* wp = convw + (size_t)c * 4;
  float w0 = wp[0], w1 = wp[1], w2 = wp[2], w3 = wp[3];
  float acc = convb[c];
  if (s >= 3) acc += bf2f(projb[(rb + s - 3) * PROJP + INTER + c]) * w0;
  if (s >= 2) acc += bf2f(projb[(rb + s - 2) * PROJP + INTER + c]) * w1;
  if (s >= 1) acc += bf2f(projb[(rb + s - 1) * PROJP + INTER + c]) * w2;
  acc += bf2f(projb[(rb + s) * PROJP + INTER + c]) * w3;
  float o = acc * sigmoidf_(acc);
  hbc[(rb + s) * CONVD + c] = f2bf(o);
}

// ---------------------------------------------------------------- dt (softplus, transposed store)
__global__ __launch_bounds__(128) void dt_k(const short* __restrict__ projb,
                                            const float* __restrict__ dt_bias,
                                            float* __restrict__ dtT) {
  const int h = threadIdx.x;
  const int r = blockIdx.x;  // 0..BS-1
  float x = bf2f(projb[(size_t)r * PROJP + INTER + CONVD + h]) + dt_bias[h];
  float sp = (x > 20.f) ? x : log1pf(__expf(x));
  sp = fminf(fmaxf(sp, 0.f), 100.f);
  const int b = r / S_LEN, s = r - b * S_LEN;
  dtT[((size_t)(b * NH + h)) * S_LEN + s] = sp;
}

// ---------------------------------------------------------------- per-chunk cumsum of dt*A
__global__ __launch_bounds__(128) void acum_k(const float* __restrict__ dtT,
                                              const float* __restrict__ A_log,
                                              float* __restrict__ acum) {
  const int l = threadIdx.x;
  const int z = blockIdx.x, h = blockIdx.y, b = blockIdx.z;
  const float A = -__expf(A_log[h]);
  __shared__ float sv[128];
  const size_t base = ((size_t)(b * NH + h)) * S_LEN + z * 128;
  sv[l] = dtT[base + l] * A;
  __syncthreads();
  for (int off = 1; off < 128; off <<= 1) {
    float t = (l >= off) ? sv[l - off] : 0.f;
    __syncthreads();
    sv[l] += t;
    __syncthreads();
  }
  acum[base + l] = sv[l];
}

// ---------------------------------------------------------------- states per (b,z,g): B staged once, 16 heads
// states_h[n][p] = sum_l B[l][n]*exp(acLast-ac[l])*xdt_h[l][p]
__global__ __launch_bounds__(512) void states_k(const short* __restrict__ hbc,
                                                const float* __restrict__ dtT,
                                                const float* __restrict__ acum,
                                                float* __restrict__ states) {
  __shared__ short sB[128 * 128];   // [s][n]
  __shared__ short sxdt[64 * 128];  // [p][s]
  __shared__ float sac[128];
  const int tid = threadIdx.x, wid = tid >> 6, lane = tid & 63;
  const int g = blockIdx.x, z = blockIdx.y, b = blockIdx.z;
  const size_t srow0 = (size_t)(b * S_LEN + z * 128);
  const short* hrow = hbc + srow0 * CONVD;

  {
    const int n0_ = (lane & 15) * 8;
#pragma unroll
    for (int it = 0; it < 4; ++it) {
      int s = it * 32 + wid * 4 + (lane >> 4);
      gl_lds16(hrow + (size_t)s * CONVD + INTER + g * NS + n0_, sB + (it * 32 + wid * 4) * 128);
    }
  }

  const int fr = lane & 15, fk8 = (lane >> 4) * 8;
  const int er = (lane >> 4) * 4, ec = lane & 15;
  const int nbase = wid * 16;

  for (int hh = 0; hh < 16; ++hh) {
    const int h = g * 16 + hh;
    const float* ac = acum + ((size_t)(b * NH + h)) * S_LEN + z * 128;
    const float* dts = dtT + ((size_t)(b * NH + h)) * S_LEN + z * 128;
    __syncthreads();  // prior head's reads done (and B-stage vmcnt drained at hh=0)
    if (tid < 128) sac[tid] = ac[tid];
    {
      int s = tid >> 2, p0 = (tid & 3) * 16;
      float dv = dts[s];
      short8 hv0 = *(const short8*)(hrow + (size_t)s * CONVD + (size_t)h * PD + p0);
      short8 hv1 = *(const short8*)(hrow + (size_t)s * CONVD + (size_t)h * PD + p0 + 8);
#pragma unroll
      for (int j = 0; j < 8; ++j) {
        sxdt[(p0 + j) * 128 + s] = f2bf(bf2f(hv0[j]) * dv);
        sxdt[(p0 + 8 + j) * 128 + s] = f2bf(bf2f(hv1[j]) * dv);
      }
    }
    __syncthreads();
    const float acLast = sac[127];
    f32x4 st[4] = {};
#pragma unroll
    for (int kk = 0; kk < 4; ++kk) {
      short8 a;
#pragma unroll
      for (int j = 0; j < 8; ++j) {
        int l = kk * 32 + fk8 + j;
        float dec = __expf(acLast - sac[l]);
        a[j] = f2bf(bf2f(sB[l * 128 + nbase + fr]) * dec);
      }
#pragma unroll
      for (int ni = 0; ni < 4; ++ni) {
        short8 bv = *(const short8*)(sxdt + (ni * 16 + fr) * 128 + kk * 32 + fk8);
        st[ni] = mfma16(a, bv, st[ni]);
      }
    }
    float* stp = states + (((size_t)(b * NC + z)) * NH + h) * (size_t)(NS * PD);
#pragma unroll
    for (int ni = 0; ni < 4; ++ni)
#pragma unroll
      for (int j = 0; j < 4; ++j)
        stp[(nbase + er + j) * PD + ni * 16 + ec] = st[ni][j];
  }
}

// ---------------------------------------------------------------- inter-chunk scan (in-place, transposes to [p][n])
__global__ __launch_bounds__(256) void scan_k(float* __restrict__ states,
                                              const float* __restrict__ acum) {
  const int h = blockIdx.x, b = blockIdx.y;
  const int tid = threadIdx.x;
  float* stp = states + ((size_t)(b * NC * NH) + h) * (size_t)(NS * PD);
  const size_t cst = (size_t)NH * NS * PD;
  const float* ac = acum + ((size_t)(b * NH + h)) * S_LEN;
  float E[32];
#pragma unroll
  for (int i = 0; i < 32; ++i) E[i] = 0.f;
  for (int zz = 0; zz < NC; ++zz) {
    float* sz = stp + (size_t)zz * cst;
    float tmp[32];
#pragma unroll
    for (int i = 0; i < 32; ++i) tmp[i] = sz[i * 256 + tid];
    __syncthreads();
    float dec = __expf(ac[zz * 128 + 127]);
#pragma unroll
    for (int i = 0; i < 32; ++i) {
      int e = i * 256 + tid;
      int n = e >> 6, p = e & 63;
      sz[p * NS + n] = E[i];          // prev state entering chunk zz, [p][n]
      E[i] = dec * E[i] + tmp[i];
    }
    __syncthreads();
  }
}

// ---------------------------------------------------------------- fused Y per (b,z,g):
// raw scores C·B^T computed ONCE per group (fp32 in regs), then per head:
// P = mask(raw)·L_h ; Y = P@xdt_h + exp(ac)·(C@prev_h^T) + hs·D_h  (single write)
__global__ __launch_bounds__(512) void yfull_k(const short* __restrict__ hbc,
                                               const float* __restrict__ dtT,
                                               const float* __restrict__ acum,
                                               const float* __restrict__ states,
                                               const float* __restrict__ Dv,
                                               float* __restrict__ Y) {
  __shared__ short lds[49152];  // 96KB: sC 32K | sB 32K (overlaid by sxdt16K+sprev16K) | sP 32K
  __shared__ float sac[128];
  short* sC = lds;
  short* sB = lds + 16384;
  short* sxdt = lds + 16384;
  short* sprev = lds + 16384 + 8192;
  const int tid = threadIdx.x, wid = tid >> 6, lane = tid & 63;
  short* sPw = lds + 32768 + wid * 2048;  // per-wave private 16x128 P band
  const int g = blockIdx.x, z = blockIdx.y, b = blockIdx.z;
  const size_t srow0 = (size_t)(b * S_LEN + z * 128);
  const short* hrow = hbc + srow0 * CONVD;

  {
    const int n0_ = (lane & 15) * 8;
#pragma unroll
    for (int it = 0; it < 4; ++it) {
      int s = it * 32 + wid * 4 + (lane >> 4);
      gl_lds16(hrow + (size_t)s * CONVD + INTER + GN + g * NS + n0_, sC + (it * 32 + wid * 4) * 128);
      gl_lds16(hrow + (size_t)s * CONVD + INTER + g * NS + n0_, sB + (it * 32 + wid * 4) * 128);
    }
  }
  __syncthreads();  // drains gl_lds vmcnt

  const int fr = lane & 15, fk8 = (lane >> 4) * 8;
  const int er = (lane >> 4) * 4, ec = lane & 15;
  const int lrow = wid * 16;  // this wave's output-row band

  // raw scores: rows lrow..lrow+15, all 128 s-cols; kept in registers
  f32x4 sc[8] = {};
#pragma unroll
  for (int kk = 0; kk < 4; ++kk) {
    short8 a = *(const short8*)(sC + (lrow + fr) * 128 + kk * 32 + fk8);
#pragma unroll
    for (int si = 0; si < 8; ++si) {
      short8 bv = *(const short8*)(sB + (si * 16 + fr) * 128 + kk * 32 + fk8);
      sc[si] = mfma16(a, bv, sc[si]);
    }
  }

  for (int hh = 0; hh < 16; ++hh) {
    const int h = g * 16 + hh;
    const float* ac = acum + ((size_t)(b * NH + h)) * S_LEN + z * 128;
    const float* dts = dtT + ((size_t)(b * NH + h)) * S_LEN + z * 128;
    const float* pv = states + (((size_t)(b * NC + z)) * NH + h) * (size_t)(NS * PD);
    __syncthreads();  // prior head's sxdt/sprev reads done; hh=0: all waves done reading sB
    if (tid < 128) sac[tid] = ac[tid];
    {
      int s = tid >> 2, p0 = (tid & 3) * 16;
      float dv = dts[s];
      short8 hv0 = *(const short8*)(hrow + (size_t)s * CONVD + (size_t)h * PD + p0);
      short8 hv1 = *(const short8*)(hrow + (size_t)s * CONVD + (size_t)h * PD + p0 + 8);
#pragma unroll
      for (int j = 0; j < 8; ++j) {
        sxdt[(p0 + j) * 128 + s] = f2bf(bf2f(hv0[j]) * dv);
        sxdt[(p0 + 8 + j) * 128 + s] = f2bf(bf2f(hv1[j]) * dv);
      }
    }
#pragma unroll
    for (int it = 0; it < 4; ++it) {
      int e = (it * 512 + tid) * 4;
      float4 v = *(const float4*)(pv + e);
      short4v o;
      o[0] = f2bf(v.x); o[1] = f2bf(v.y); o[2] = f2bf(v.z); o[3] = f2bf(v.w);
      *(short4v*)(sprev + e) = o;
    }
    __syncthreads();

    // mask raw scores -> P (bf16) into this wave's private band
    {
      float acS[8];
#pragma unroll
      for (int si = 0; si < 8; ++si) acS[si] = sac[si * 16 + ec];
#pragma unroll
      for (int j = 0; j < 4; ++j) {
        int lloc = er + j;
        float acl = sac[lrow + lloc];
#pragma unroll
        for (int si = 0; si < 8; ++si) {
          int s = si * 16 + ec;
          float v = (s <= lrow + lloc) ? sc[si][j] * __expf(acl - acS[si]) : 0.f;
          sPw[lloc * 128 + s] = f2bf(v);
        }
      }
    }
    // PV (P@xdt) and C@prev^T
    f32x4 yd[4] = {}, yo[4] = {};
#pragma unroll
    for (int kk = 0; kk < 4; ++kk) {
      short8 ap = *(const short8*)(sPw + fr * 128 + kk * 32 + fk8);
      short8 acf = *(const short8*)(sC + (lrow + fr) * 128 + kk * 32 + fk8);
#pragma unroll
      for (int ni = 0; ni < 4; ++ni) {
        short8 bv = *(const short8*)(sxdt + (ni * 16 + fr) * 128 + kk * 32 + fk8);
        yd[ni] = mfma16(ap, bv, yd[ni]);
        short8 bp = *(const short8*)(sprev + (ni * 16 + fr) * 128 + kk * 32 + fk8);
        yo[ni] = mfma16(acf, bp, yo[ni]);
      }
    }
    const float Dh = Dv[h];
#pragma unroll
    for (int j = 0; j < 4; ++j) {
      int l = lrow + er + j;
      float e_ac = __expf(sac[l]);
#pragma unroll
      for (int ni = 0; ni < 4; ++ni) {
        int p = ni * 16 + ec;
        float hs = bf2f(hrow[(size_t)l * CONVD + (size_t)h * PD + p]);
        Y[(srow0 + l) * (size_t)INTER + (size_t)h * PD + p] = yd[ni][j] + yo[ni][j] * e_ac + hs * Dh;
      }
    }
  }
}

// ---------------------------------------------------------------- gated group RMS norm -> bf16
__global__ __launch_bounds__(256) void norm_k(const float* __restrict__ Y,
                                              const short* __restrict__ projb,
                                              const float* __restrict__ norm_w,
                                              short* __restrict__ outn) {
  const int r = blockIdx.x;
  const int tid = threadIdx.x;
  const int gi = tid >> 5, li = tid & 31;
  const float* yrow = Y + (size_t)r * INTER;
  const short* grow = projb + (size_t)r * PROJP;
  const int e0 = gi * 1024 + li * 32;
  float gv[32];
  float ss = 0.f;
#pragma unroll
  for (int j4 = 0; j4 < 32; j4 += 4) {
    float4 yv = *(const float4*)(yrow + e0 + j4);
    short4v gt = *(const short4v*)(grow + e0 + j4);
    float ys[4] = {yv.x, yv.y, yv.z, yv.w};
#pragma unroll
    for (int q = 0; q < 4; ++q) {
      float gate = bf2f(gt[q]);
      float gg = ys[q] * gate * sigmoidf_(gate);
      gv[j4 + q] = gg;
      ss += gg * gg;
    }
  }
#pragma unroll
  for (int m = 16; m >= 1; m >>= 1) ss += __shfl_xor(ss, m, 64);
  const float scale = rsqrtf(ss * (1.f / 1024.f) + 1e-5f);
#pragma unroll
  for (int j4 = 0; j4 < 32; j4 += 4) {
    short4v o;
#pragma unroll
    for (int q = 0; q < 4; ++q) o[q] = f2bf(gv[j4 + q] * scale * norm_w[e0 + j4 + q]);
    *(short4v*)(outn + (size_t)r * INTER + e0 + j4) = o;
  }
}

// ----------------------------------------------------------------
extern "C" void kernel_launch(void* const* d_in, const int* in_sizes, int n_in,
                              void* d_out, int out_size, void* d_ws, size_t ws_size,
                              hipStream_t stream) {
  const float* x     = (const float*)d_in[0];
  const float* w1    = (const float*)d_in[1];
  const float* convw = (const float*)d_in[2];
  const float* convb = (const float*)d_in[3];
  const float* dtb   = (const float*)d_in[4];
  const float* alog  = (const float*)d_in[5];
  const float* Dv    = (const float*)d_in[6];
  const float* nw    = (const float*)d_in[7];
  const float* w2    = (const float*)d_in[8];
  float* out = (float*)d_out;

  char* ws = (char*)d_ws;
  size_t off = 0;
  float* dtT = (float*)(ws + off);  off += (size_t)BB * NH * S_LEN * 4;
  float* acum = (float*)(ws + off); off += (size_t)BB * NH * S_LEN * 4;
  short* xb = (short*)(ws + off);   off += (size_t)BS * HID_DIM * 2;
  char* w1region = ws + off;        off += (size_t)PROJP * HID_DIM * 2;
  short* w1b = (short*)w1region;    // 18688 rows x 4096 (rows >= 18560 stay garbage; pad C-cols never read)
  short* normed = (short*)w1region;                              // reuse after gemm1
  short* w2b = (short*)(w1region + (size_t)BS * INTER * 2);      // reuse after gemm1
  short* projb = (short*)(ws + off); off += (size_t)BS * PROJP * 2;
  short* hbc = (short*)(ws + off);   off += (size_t)BS * CONVD * 2;
  float* Y = (float*)(ws + off);     off += (size_t)BS * INTER * 4;
  float* states = (float*)(ws + off); off += (size_t)BB * NC * NH * NS * PD * 4;

  const size_t nx = (size_t)BS * HID_DIM;
  const size_t nw1 = (size_t)PROJ * HID_DIM;
  const size_t nw2 = (size_t)HID_DIM * INTER;

  cvt_f32_bf16_k<<<dim3(nx / 2048), 256, 0, stream>>>(x, xb, nx);
  cvt_f32_bf16_k<<<dim3(nw1 / 2048), 256, 0, stream>>>(w1, w1b, nw1);

  // gemm1: [4096 x 18560(pad 18688)] = xb[4096x4096] * w1b^T ; 16 x 73 tiles
  gemm256_k<1><<<dim3(16 * 73), 512, 0, stream>>>(xb, w1b, projb, PROJP, HID_DIM, 73);

  // w1b dead now; stage w2 into its region
  cvt_f32_bf16_k<<<dim3(nw2 / 2048), 256, 0, stream>>>(w2, w2b, nw2);

  conv_silu_k<<<dim3(CONVD / 256, S_LEN, BB), 256, 0, stream>>>(projb, convw, convb, hbc);
  dt_k<<<dim3(BS), 128, 0, stream>>>(projb, dtb, dtT);
  acum_k<<<dim3(NC, NH, BB), 128, 0, stream>>>(dtT, alog, acum);

  states_k<<<dim3(NG, NC, BB), 512, 0, stream>>>(hbc, dtT, acum, states);
  scan_k<<<dim3(NH, BB), 256, 0, stream>>>(states, acum);
  yfull_k<<<dim3(NG, NC, BB), 512, 0, stream>>>(hbc, dtT, acum, states, Dv, Y);

  norm_k<<<dim3(BS), 256, 0, stream>>>(Y, projb, nw, normed);

  // gemm2: [4096 x 4096] = normed[4096x8192] * w2b^T ; 16 x 16 tiles
  gemm256_k<0><<<dim3(16 * 16), 512, 0, stream>>>(normed, w2b, out, HID_DIM, INTER, 16);
}

// Round 6
// 1391.830 us; speedup vs baseline: 1.5034x; 1.0612x over previous
//
#include <hip/hip_runtime.h>
#include <hip/hip_bf16.h>
#include <cstdint>
#include <cstddef>

#define DEVI __device__ __forceinline__

#define BB 2
#define S_LEN 2048
#define HID_DIM 4096
#define NH 128
#define PD 64
#define NS 128
#define NG 8
#define INTER 8192
#define CONVD 10240
#define PROJ 18560
#define PROJP 18688   // padded to 73*256 for 256-wide GEMM tiles
#define NC 16
#define BS 4096
#define GN 1024   // NG*NS

using short8 = __attribute__((ext_vector_type(8))) short;
using short4v = __attribute__((ext_vector_type(4))) short;
using f32x4  = __attribute__((ext_vector_type(4))) float;
using bf16x8 = __attribute__((ext_vector_type(8))) __bf16;

DEVI float bf2f(short u) {
  union { unsigned int i; float f; } v;
  v.i = ((unsigned int)(unsigned short)u) << 16;
  return v.f;
}
DEVI short f2bf(float f) {
  union { float ff; unsigned int i; } v; v.ff = f;
  unsigned int x = v.i;
  return (short)((x + 0x7fffu + ((x >> 16) & 1u)) >> 16);
}
DEVI f32x4 mfma16(short8 a, short8 b, f32x4 c) {
  return __builtin_amdgcn_mfma_f32_16x16x32_bf16(
      __builtin_bit_cast(bf16x8, a), __builtin_bit_cast(bf16x8, b), c, 0, 0, 0);
}
DEVI void gl_lds16(const short* g, short* l) {
  __builtin_amdgcn_global_load_lds(
      (const __attribute__((address_space(1))) void*)g,
      (__attribute__((address_space(3))) void*)l, 16, 0, 0);
}
DEVI float sigmoidf_(float x) { return 1.f / (1.f + __expf(-x)); }

// ---------------------------------------------------------------- converts
__global__ __launch_bounds__(256) void cvt_f32_bf16_k(const float* __restrict__ in,
                                                      short* __restrict__ out, size_t n) {
  size_t i = ((size_t)blockIdx.x * 256 + threadIdx.x) * 8;
  if (i + 8 > n) return;
  float4 a = *(const float4*)(in + i);
  float4 b = *(const float4*)(in + i + 4);
  short8 o;
  o[0] = f2bf(a.x); o[1] = f2bf(a.y); o[2] = f2bf(a.z); o[3] = f2bf(a.w);
  o[4] = f2bf(b.x); o[5] = f2bf(b.y); o[6] = f2bf(b.z); o[7] = f2bf(b.w);
  *(short8*)(out + i) = o;
}

// ---------------------------------------------------------------- 256x256 8-phase GEMM
// (unchanged from round 4 — see liveness ledger in comments)

#define STG(ISB, BUF, KH, TILE) do { \
  const short* _src = (ISB) ? Bt : A; \
  const int _r0 = (ISB) ? n0 : m0; \
  short* _lb = lds_ + ((ISB) ? 32768 : 0) + ((BUF)*2+(KH))*8192; \
  const int _kt = (TILE)*64 + (KH)*32; \
  { int _row = (wid*2)*16 + srow; int _sl = sps ^ ((_row>>1)&3); \
    gl_lds16(_src + (size_t)(_r0+_row)*K + _kt + _sl*8, _lb + (wid*2)*512); } \
  { int _row = (wid*2+1)*16 + srow; int _sl = sps ^ ((_row>>1)&3); \
    gl_lds16(_src + (size_t)(_r0+_row)*K + _kt + _sl*8, _lb + (wid*2+1)*512); } \
} while(0)

#define NOPS ((void)0)
#define VM6 asm volatile("s_waitcnt vmcnt(6)" ::: "memory")
#define VM0 asm volatile("s_waitcnt vmcnt(0)" ::: "memory")

#define PH(BUF, KH, MIH, DOB, STGS, VMW) do { \
  _Pragma("unroll") \
  for (int _m = 0; _m < 4; ++_m) { \
    int _row = wr*128 + ((MIH)*4+_m)*16 + fr; \
    af[_m] = *(const short8*)(lds_ + ((BUF)*2+(KH))*8192 + _row*32 + ((slot ^ ((_row>>1)&3))<<3)); \
  } \
  if (DOB) { \
    _Pragma("unroll") \
    for (int _n = 0; _n < 4; ++_n) { \
      int _row = wc*64 + _n*16 + fr; \
      bf_[_n] = *(const short8*)(lds_ + 32768 + ((BUF)*2+(KH))*8192 + _row*32 + ((slot ^ ((_row>>1)&3))<<3)); \
    } \
  } \
  STGS; VMW; \
  __builtin_amdgcn_s_barrier(); \
  asm volatile("s_waitcnt lgkmcnt(0)" ::: "memory"); \
  __builtin_amdgcn_sched_barrier(0); \
  __builtin_amdgcn_s_setprio(1); \
  _Pragma("unroll") \
  for (int _m = 0; _m < 4; ++_m) \
    _Pragma("unroll") \
    for (int _n = 0; _n < 4; ++_n) \
      acc[(MIH)*4+_m][_n] = mfma16(af[_m], bf_[_n], acc[(MIH)*4+_m][_n]); \
  __builtin_amdgcn_s_setprio(0); \
  __builtin_amdgcn_s_barrier(); \
} while(0)

template<int CB16>
__global__ __launch_bounds__(512, 2) void gemm256_k(const short* __restrict__ A,
                                                    const short* __restrict__ Bt,
                                                    void* __restrict__ Cout,
                                                    int Nstride, int K, int ntn) {
  __shared__ short lds_[65536];  // 128 KiB
  const int tid = threadIdx.x, wid = tid >> 6, lane = tid & 63;
  const int nwg = gridDim.x, orig = blockIdx.x;
  const int swz = (orig & 7) * (nwg >> 3) + (orig >> 3);
  const int per_group = ntn << 3;
  const int group = swz / per_group;
  const int rem = swz - group * per_group;
  const int m0 = (group * 8 + (rem & 7)) * 256;
  const int n0 = (rem >> 3) * 256;
  const int wr = wid >> 2, wc = wid & 3;
  const int fr = lane & 15, slot = lane >> 4;
  const int srow = lane >> 2, sps = lane & 3;

  f32x4 acc[8][4] = {};
  short8 af[4], bf_[4];
  const int NT = K >> 6;

  STG(1, 0, 0, 0); STG(0, 0, 0, 0); STG(1, 0, 1, 0); STG(0, 0, 1, 0);
  asm volatile("s_waitcnt vmcnt(4)" ::: "memory");
  STG(1, 1, 0, 1); STG(0, 1, 0, 1); STG(1, 1, 1, 1);
  asm volatile("s_waitcnt vmcnt(6)" ::: "memory");
  __builtin_amdgcn_s_barrier();

  for (int i = 0; i < (NT >> 1) - 1; ++i) {
    const int t = 2 * i;
    PH(0, 0, 0, 1, STG(0, 1, 1, t + 1), NOPS);
    PH(0, 0, 1, 0, STG(1, 0, 0, t + 2), NOPS);
    PH(0, 1, 0, 1, STG(0, 0, 0, t + 2), NOPS);
    PH(0, 1, 1, 0, STG(1, 0, 1, t + 2), VM6);
    PH(1, 0, 0, 1, STG(0, 0, 1, t + 2), NOPS);
    PH(1, 0, 1, 0, STG(1, 1, 0, t + 3), NOPS);
    PH(1, 1, 0, 1, STG(0, 1, 0, t + 3), NOPS);
    PH(1, 1, 1, 0, STG(1, 1, 1, t + 3), VM6);
  }
  PH(0, 0, 0, 1, STG(0, 1, 1, NT - 1), NOPS);
  PH(0, 0, 1, 0, NOPS, NOPS);
  PH(0, 1, 0, 1, NOPS, NOPS);
  PH(0, 1, 1, 0, NOPS, VM0);
  PH(1, 0, 0, 1, NOPS, NOPS);
  PH(1, 0, 1, 0, NOPS, NOPS);
  PH(1, 1, 0, 1, NOPS, NOPS);
  PH(1, 1, 1, 0, NOPS, NOPS);

  const int er = (lane >> 4) * 4, ec = lane & 15;
  if (CB16) {
    short* C = (short*)Cout;
#pragma unroll
    for (int mi = 0; mi < 8; ++mi)
#pragma unroll
      for (int j = 0; j < 4; ++j) {
        size_t base = (size_t)(m0 + wr * 128 + mi * 16 + er + j) * Nstride + n0 + wc * 64 + ec;
#pragma unroll
        for (int ni = 0; ni < 4; ++ni) C[base + ni * 16] = f2bf(acc[mi][ni][j]);
      }
  } else {
    float* C = (float*)Cout;
#pragma unroll
    for (int mi = 0; mi < 8; ++mi)
#pragma unroll
      for (int j = 0; j < 4; ++j) {
        size_t base = (size_t)(m0 + wr * 128 + mi * 16 + er + j) * Nstride + n0 + wc * 64 + ec;
#pragma unroll
        for (int ni = 0; ni < 4; ++ni) C[base + ni * 16] = acc[mi][ni][j];
      }
  }
}

// ---------------------------------------------------------------- conv + silu (sliding window, read-once)
__global__ __launch_bounds__(256) void conv_silu_k(const short* __restrict__ projb,
                                                   const float* __restrict__ convw,
                                                   const float* __restrict__ convb,
                                                   short* __restrict__ hbc) {
  const int c = blockIdx.x * 256 + threadIdx.x;
  const int s0 = blockIdx.y * 256;
  const int b = blockIdx.z;
  const size_t rb = (size_t)b * S_LEN;
  const float* wp = convw + (size_t)c * 4;
  const float w0 = wp[0], w1 = wp[1], w2 = wp[2], w3 = wp[3];
  const float bias = convb[c];
  const short* pcol = projb + INTER + c;
  float x1 = 0.f, x2 = 0.f, x3 = 0.f;  // s-1, s-2, s-3
  if (s0 > 0) {
    x3 = bf2f(pcol[(rb + s0 - 3) * PROJP]);
    x2 = bf2f(pcol[(rb + s0 - 2) * PROJP]);
    x1 = bf2f(pcol[(rb + s0 - 1) * PROJP]);
  }
  for (int s = s0; s < s0 + 256; ++s) {
    float v = bf2f(pcol[(rb + s) * PROJP]);
    float acc = bias + w0 * x3 + w1 * x2 + w2 * x1 + w3 * v;
    float o = acc * sigmoidf_(acc);
    hbc[(rb + s) * CONVD + c] = f2bf(o);
    x3 = x2; x2 = x1; x1 = v;
  }
}

// ---------------------------------------------------------------- dt softplus + per-chunk cumsum (fused)
__global__ __launch_bounds__(128) void acum_k(const short* __restrict__ projb,
                                              const float* __restrict__ dt_bias,
                                              const float* __restrict__ A_log,
                                              float* __restrict__ dtT,
                                              float* __restrict__ acum) {
  const int l = threadIdx.x;
  const int z = blockIdx.x, h = blockIdx.y, b = blockIdx.z;
  const float A = -__expf(A_log[h]);
  __shared__ float sv[128];
  const int r = b * S_LEN + z * 128 + l;
  float xv = bf2f(projb[(size_t)r * PROJP + INTER + CONVD + h]) + dt_bias[h];
  float sp = (xv > 20.f) ? xv : log1pf(__expf(xv));
  sp = fminf(fmaxf(sp, 0.f), 100.f);
  const size_t base = ((size_t)(b * NH + h)) * S_LEN + z * 128;
  dtT[base + l] = sp;
  sv[l] = sp * A;
  __syncthreads();
  for (int off = 1; off < 128; off <<= 1) {
    float t = (l >= off) ? sv[l - off] : 0.f;
    __syncthreads();
    sv[l] += t;
    __syncthreads();
  }
  acum[base + l] = sv[l];
}

// ---------------------------------------------------------------- states per (b,z,g): B staged once, 16 heads
__global__ __launch_bounds__(512) void states_k(const short* __restrict__ hbc,
                                                const float* __restrict__ dtT,
                                                const float* __restrict__ acum,
                                                float* __restrict__ states) {
  __shared__ short sB[128 * 128];   // [s][n]
  __shared__ short sxdt[64 * 128];  // [p][s]
  __shared__ float sac[128];
  const int tid = threadIdx.x, wid = tid >> 6, lane = tid & 63;
  const int g = blockIdx.x, z = blockIdx.y, b = blockIdx.z;
  const size_t srow0 = (size_t)(b * S_LEN + z * 128);
  const short* hrow = hbc + srow0 * CONVD;

  {
    const int n0_ = (lane & 15) * 8;
#pragma unroll
    for (int it = 0; it < 4; ++it) {
      int s = it * 32 + wid * 4 + (lane >> 4);
      gl_lds16(hrow + (size_t)s * CONVD + INTER + g * NS + n0_, sB + (it * 32 + wid * 4) * 128);
    }
  }

  const int fr = lane & 15, fk8 = (lane >> 4) * 8;
  const int er = (lane >> 4) * 4, ec = lane & 15;
  const int nbase = wid * 16;

  for (int hh = 0; hh < 16; ++hh) {
    const int h = g * 16 + hh;
    const float* ac = acum + ((size_t)(b * NH + h)) * S_LEN + z * 128;
    const float* dts = dtT + ((size_t)(b * NH + h)) * S_LEN + z * 128;
    __syncthreads();
    if (tid < 128) sac[tid] = ac[tid];
    {
      int s = tid >> 2, p0 = (tid & 3) * 16;
      float dv = dts[s];
      short8 hv0 = *(const short8*)(hrow + (size_t)s * CONVD + (size_t)h * PD + p0);
      short8 hv1 = *(const short8*)(hrow + (size_t)s * CONVD + (size_t)h * PD + p0 + 8);
#pragma unroll
      for (int j = 0; j < 8; ++j) {
        sxdt[(p0 + j) * 128 + s] = f2bf(bf2f(hv0[j]) * dv);
        sxdt[(p0 + 8 + j) * 128 + s] = f2bf(bf2f(hv1[j]) * dv);
      }
    }
    __syncthreads();
    const float acLast = sac[127];
    f32x4 st[4] = {};
#pragma unroll
    for (int kk = 0; kk < 4; ++kk) {
      short8 a;
#pragma unroll
      for (int j = 0; j < 8; ++j) {
        int l = kk * 32 + fk8 + j;
        float dec = __expf(acLast - sac[l]);
        a[j] = f2bf(bf2f(sB[l * 128 + nbase + fr]) * dec);
      }
#pragma unroll
      for (int ni = 0; ni < 4; ++ni) {
        short8 bv = *(const short8*)(sxdt + (ni * 16 + fr) * 128 + kk * 32 + fk8);
        st[ni] = mfma16(a, bv, st[ni]);
      }
    }
    float* stp = states + (((size_t)(b * NC + z)) * NH + h) * (size_t)(NS * PD);
#pragma unroll
    for (int ni = 0; ni < 4; ++ni)
#pragma unroll
      for (int j = 0; j < 4; ++j)
        stp[(nbase + er + j) * PD + ni * 16 + ec] = st[ni][j];
  }
}

// ---------------------------------------------------------------- inter-chunk scan (in-place, transposes to [p][n])
__global__ __launch_bounds__(256) void scan_k(float* __restrict__ states,
                                              const float* __restrict__ acum) {
  const int h = blockIdx.x, b = blockIdx.y;
  const int tid = threadIdx.x;
  float* stp = states + ((size_t)(b * NC * NH) + h) * (size_t)(NS * PD);
  const size_t cst = (size_t)NH * NS * PD;
  const float* ac = acum + ((size_t)(b * NH + h)) * S_LEN;
  float E[32];
#pragma unroll
  for (int i = 0; i < 32; ++i) E[i] = 0.f;
  for (int zz = 0; zz < NC; ++zz) {
    float* sz = stp + (size_t)zz * cst;
    float tmp[32];
#pragma unroll
    for (int i = 0; i < 32; ++i) tmp[i] = sz[i * 256 + tid];
    __syncthreads();
    float dec = __expf(ac[zz * 128 + 127]);
#pragma unroll
    for (int i = 0; i < 32; ++i) {
      int e = i * 256 + tid;
      int n = e >> 6, p = e & 63;
      sz[p * NS + n] = E[i];
      E[i] = dec * E[i] + tmp[i];
    }
    __syncthreads();
  }
}

// ---------------------------------------------------------------- fused Y + gate + group-RMS-norm per (b,z,g)
// raw scores C·B^T once (fp32 regs); per head: P=mask·L, gg = (P@xdt + e^ac·C@prev^T + hs·D)·silu(gate)
// stored fp32 to Yg; per-row ssq accumulated in regs; epilogue: scale = rsqrt(mean+eps),
// re-read block's gg slab (L2-hot) and write bf16 normed. Replaces norm_k.
__global__ __launch_bounds__(512) void yfull_k(const short* __restrict__ hbc,
                                               const short* __restrict__ projb,
                                               const float* __restrict__ dtT,
                                               const float* __restrict__ acum,
                                               const float* __restrict__ states,
                                               const float* __restrict__ Dv,
                                               const float* __restrict__ norm_w,
                                               float* __restrict__ Yg,
                                               short* __restrict__ normed) {
  __shared__ short lds[49152];  // 96KB: sC 32K | sB 32K (overlaid sxdt16K+sprev16K) | sP 32K
  __shared__ float sac[128];
  __shared__ float sScale[128];
  __shared__ float sNW[1024];
  short* sC = lds;
  short* sB = lds + 16384;
  short* sxdt = lds + 16384;
  short* sprev = lds + 16384 + 8192;
  const int tid = threadIdx.x, wid = tid >> 6, lane = tid & 63;
  short* sPw = lds + 32768 + wid * 2048;  // per-wave private 16x128 P band
  const int g = blockIdx.x, z = blockIdx.y, b = blockIdx.z;
  const size_t srow0 = (size_t)(b * S_LEN + z * 128);
  const short* hrow = hbc + srow0 * CONVD;

  {
    const int n0_ = (lane & 15) * 8;
#pragma unroll
    for (int it = 0; it < 4; ++it) {
      int s = it * 32 + wid * 4 + (lane >> 4);
      gl_lds16(hrow + (size_t)s * CONVD + INTER + GN + g * NS + n0_, sC + (it * 32 + wid * 4) * 128);
      gl_lds16(hrow + (size_t)s * CONVD + INTER + g * NS + n0_, sB + (it * 32 + wid * 4) * 128);
    }
  }
  // norm_w slice for this group
  for (int i = tid; i < 1024; i += 512) sNW[i] = norm_w[g * 1024 + i];
  __syncthreads();  // drains gl_lds vmcnt; sNW visible

  const int fr = lane & 15, fk8 = (lane >> 4) * 8;
  const int er = (lane >> 4) * 4, ec = lane & 15;
  const int lrow = wid * 16;

  f32x4 sc[8] = {};
#pragma unroll
  for (int kk = 0; kk < 4; ++kk) {
    short8 a = *(const short8*)(sC + (lrow + fr) * 128 + kk * 32 + fk8);
#pragma unroll
    for (int si = 0; si < 8; ++si) {
      short8 bv = *(const short8*)(sB + (si * 16 + fr) * 128 + kk * 32 + fk8);
      sc[si] = mfma16(a, bv, sc[si]);
    }
  }

  float rssq[4] = {0.f, 0.f, 0.f, 0.f};

  for (int hh = 0; hh < 16; ++hh) {
    const int h = g * 16 + hh;
    const float* ac = acum + ((size_t)(b * NH + h)) * S_LEN + z * 128;
    const float* dts = dtT + ((size_t)(b * NH + h)) * S_LEN + z * 128;
    const float* pv = states + (((size_t)(b * NC + z)) * NH + h) * (size_t)(NS * PD);
    __syncthreads();
    if (tid < 128) sac[tid] = ac[tid];
    {
      int s = tid >> 2, p0 = (tid & 3) * 16;
      float dv = dts[s];
      short8 hv0 = *(const short8*)(hrow + (size_t)s * CONVD + (size_t)h * PD + p0);
      short8 hv1 = *(const short8*)(hrow + (size_t)s * CONVD + (size_t)h * PD + p0 + 8);
#pragma unroll
      for (int j = 0; j < 8; ++j) {
        sxdt[(p0 + j) * 128 + s] = f2bf(bf2f(hv0[j]) * dv);
        sxdt[(p0 + 8 + j) * 128 + s] = f2bf(bf2f(hv1[j]) * dv);
      }
    }
#pragma unroll
    for (int it = 0; it < 4; ++it) {
      int e = (it * 512 + tid) * 4;
      float4 v = *(const float4*)(pv + e);
      short4v o;
      o[0] = f2bf(v.x); o[1] = f2bf(v.y); o[2] = f2bf(v.z); o[3] = f2bf(v.w);
      *(short4v*)(sprev + e) = o;
    }
    __syncthreads();

    {
      float acS[8];
#pragma unroll
      for (int si = 0; si < 8; ++si) acS[si] = sac[si * 16 + ec];
#pragma unroll
      for (int j = 0; j < 4; ++j) {
        int lloc = er + j;
        float acl = sac[lrow + lloc];
#pragma unroll
        for (int si = 0; si < 8; ++si) {
          int s = si * 16 + ec;
          float v = (s <= lrow + lloc) ? sc[si][j] * __expf(acl - acS[si]) : 0.f;
          sPw[lloc * 128 + s] = f2bf(v);
        }
      }
    }
    f32x4 yd[4] = {}, yo[4] = {};
#pragma unroll
    for (int kk = 0; kk < 4; ++kk) {
      short8 ap = *(const short8*)(sPw + fr * 128 + kk * 32 + fk8);
      short8 acf = *(const short8*)(sC + (lrow + fr) * 128 + kk * 32 + fk8);
#pragma unroll
      for (int ni = 0; ni < 4; ++ni) {
        short8 bv = *(const short8*)(sxdt + (ni * 16 + fr) * 128 + kk * 32 + fk8);
        yd[ni] = mfma16(ap, bv, yd[ni]);
        short8 bp = *(const short8*)(sprev + (ni * 16 + fr) * 128 + kk * 32 + fk8);
        yo[ni] = mfma16(acf, bp, yo[ni]);
      }
    }
    const float Dh = Dv[h];
#pragma unroll
    for (int j = 0; j < 4; ++j) {
      int l = lrow + er + j;
      float e_ac = __expf(sac[l]);
#pragma unroll
      for (int ni = 0; ni < 4; ++ni) {
        int p = ni * 16 + ec;
        float hs = bf2f(hrow[(size_t)l * CONVD + (size_t)h * PD + p]);
        float y = yd[ni][j] + yo[ni][j] * e_ac + hs * Dh;
        float gate = bf2f(projb[(srow0 + l) * (size_t)PROJP + (size_t)h * PD + p]);
        float gg = y * gate * sigmoidf_(gate);
        Yg[(srow0 + l) * (size_t)INTER + (size_t)h * PD + p] = gg;
        rssq[j] += gg * gg;
      }
    }
  }

  // per-row scale: reduce rssq across the 16 ec lanes of each er-group
#pragma unroll
  for (int j = 0; j < 4; ++j) {
#pragma unroll
    for (int m = 1; m <= 8; m <<= 1) rssq[j] += __shfl_xor(rssq[j], m, 64);
  }
  if (ec == 0) {
#pragma unroll
    for (int j = 0; j < 4; ++j) sScale[lrow + er + j] = rsqrtf(rssq[j] * (1.f / 1024.f) + 1e-5f);
  }
  __syncthreads();  // also makes all Yg writes visible (vmcnt drained)

  // normed write: 128 rows x 1024 ch slab, coalesced
  for (int e = tid * 8; e < 128 * 1024; e += 4096) {
    int row = e >> 10, ch = e & 1023;
    const float* gp = Yg + (srow0 + row) * (size_t)INTER + g * 1024 + ch;
    float4 g0 = *(const float4*)(gp);
    float4 g1 = *(const float4*)(gp + 4);
    float scl = sScale[row];
    short8 o;
    o[0] = f2bf(g0.x * scl * sNW[ch + 0]); o[1] = f2bf(g0.y * scl * sNW[ch + 1]);
    o[2] = f2bf(g0.z * scl * sNW[ch + 2]); o[3] = f2bf(g0.w * scl * sNW[ch + 3]);
    o[4] = f2bf(g1.x * scl * sNW[ch + 4]); o[5] = f2bf(g1.y * scl * sNW[ch + 5]);
    o[6] = f2bf(g1.z * scl * sNW[ch + 6]); o[7] = f2bf(g1.w * scl * sNW[ch + 7]);
    *(short8*)(normed + (srow0 + row) * (size_t)INTER + g * 1024 + ch) = o;
  }
}

// ----------------------------------------------------------------
extern "C" void kernel_launch(void* const* d_in, const int* in_sizes, int n_in,
                              void* d_out, int out_size, void* d_ws, size_t ws_size,
                              hipStream_t stream) {
  const float* x     = (const float*)d_in[0];
  const float* w1    = (const float*)d_in[1];
  const float* convw = (const float*)d_in[2];
  const float* convb = (const float*)d_in[3];
  const float* dtb   = (const float*)d_in[4];
  const float* alog  = (const float*)d_in[5];
  const float* Dv    = (const float*)d_in[6];
  const float* nw    = (const float*)d_in[7];
  const float* w2    = (const float*)d_in[8];
  float* out = (float*)d_out;

  char* ws = (char*)d_ws;
  size_t off = 0;
  float* dtT = (float*)(ws + off);  off += (size_t)BB * NH * S_LEN * 4;
  float* acum = (float*)(ws + off); off += (size_t)BB * NH * S_LEN * 4;
  short* xb = (short*)(ws + off);   off += (size_t)BS * HID_DIM * 2;
  char* w1region = ws + off;        off += (size_t)PROJP * HID_DIM * 2;
  short* w1b = (short*)w1region;
  short* normed = (short*)w1region;                              // reuse after gemm1
  short* w2b = (short*)(w1region + (size_t)BS * INTER * 2);      // reuse after gemm1
  short* projb = (short*)(ws + off); off += (size_t)BS * PROJP * 2;
  short* hbc = (short*)(ws + off);   off += (size_t)BS * CONVD * 2;
  float* Y = (float*)(ws + off);     off += (size_t)BS * INTER * 4;
  float* states = (float*)(ws + off); off += (size_t)BB * NC * NH * NS * PD * 4;

  const size_t nx = (size_t)BS * HID_DIM;
  const size_t nw1 = (size_t)PROJ * HID_DIM;
  const size_t nw2 = (size_t)HID_DIM * INTER;

  cvt_f32_bf16_k<<<dim3(nx / 2048), 256, 0, stream>>>(x, xb, nx);
  cvt_f32_bf16_k<<<dim3(nw1 / 2048), 256, 0, stream>>>(w1, w1b, nw1);

  // gemm1: [4096 x 18560(pad 18688)] = xb[4096x4096] * w1b^T ; 16 x 73 tiles
  gemm256_k<1><<<dim3(16 * 73), 512, 0, stream>>>(xb, w1b, projb, PROJP, HID_DIM, 73);

  // w1b dead now; stage w2 into its region
  cvt_f32_bf16_k<<<dim3(nw2 / 2048), 256, 0, stream>>>(w2, w2b, nw2);

  conv_silu_k<<<dim3(CONVD / 256, S_LEN / 256, BB), 256, 0, stream>>>(projb, convw, convb, hbc);
  acum_k<<<dim3(NC, NH, BB), 128, 0, stream>>>(projb, dtb, alog, dtT, acum);

  states_k<<<dim3(NG, NC, BB), 512, 0, stream>>>(hbc, dtT, acum, states);
  scan_k<<<dim3(NH, BB), 256, 0, stream>>>(states, acum);
  yfull_k<<<dim3(NG, NC, BB), 512, 0, stream>>>(hbc, projb, dtT, acum, states, Dv, nw, Y, normed);

  // gemm2: [4096 x 4096] = normed[4096x8192] * w2b^T ; 16 x 16 tiles
  gemm256_k<0><<<dim3(16 * 16), 512, 0, stream>>>(normed, w2b, out, HID_DIM, INTER, 16);
}

// Round 7
// 1285.956 us; speedup vs baseline: 1.6272x; 1.0823x over previous
//
#include <hip/hip_runtime.h>
#include <hip/hip_bf16.h>
#include <cstdint>
#include <cstddef>

#define DEVI __device__ __forceinline__

#define BB 2
#define S_LEN 2048
#define HID_DIM 4096
#define NH 128
#define PD 64
#define NS 128
#define NG 8
#define INTER 8192
#define CONVD 10240
#define PROJ 18560
#define PROJP 18688   // padded to 73*256 for 256-wide GEMM tiles
#define NC 16
#define BS 4096
#define GN 1024   // NG*NS

using short8 = __attribute__((ext_vector_type(8))) short;
using short4v = __attribute__((ext_vector_type(4))) short;
using f32x4  = __attribute__((ext_vector_type(4))) float;
using bf16x8 = __attribute__((ext_vector_type(8))) __bf16;

DEVI float bf2f(short u) {
  union { unsigned int i; float f; } v;
  v.i = ((unsigned int)(unsigned short)u) << 16;
  return v.f;
}
DEVI short f2bf(float f) {
  union { float ff; unsigned int i; } v; v.ff = f;
  unsigned int x = v.i;
  return (short)((x + 0x7fffu + ((x >> 16) & 1u)) >> 16);
}
DEVI f32x4 mfma16(short8 a, short8 b, f32x4 c) {
  return __builtin_amdgcn_mfma_f32_16x16x32_bf16(
      __builtin_bit_cast(bf16x8, a), __builtin_bit_cast(bf16x8, b), c, 0, 0, 0);
}
DEVI void gl_lds16(const short* g, short* l) {
  __builtin_amdgcn_global_load_lds(
      (const __attribute__((address_space(1))) void*)g,
      (__attribute__((address_space(3))) void*)l, 16, 0, 0);
}
DEVI float sigmoidf_(float x) { return 1.f / (1.f + __expf(-x)); }

// ---------------------------------------------------------------- converts
__global__ __launch_bounds__(256) void cvt_f32_bf16_k(const float* __restrict__ in,
                                                      short* __restrict__ out, size_t n) {
  size_t i = ((size_t)blockIdx.x * 256 + threadIdx.x) * 8;
  if (i + 8 > n) return;
  float4 a = *(const float4*)(in + i);
  float4 b = *(const float4*)(in + i + 4);
  short8 o;
  o[0] = f2bf(a.x); o[1] = f2bf(a.y); o[2] = f2bf(a.z); o[3] = f2bf(a.w);
  o[4] = f2bf(b.x); o[5] = f2bf(b.y); o[6] = f2bf(b.z); o[7] = f2bf(b.w);
  *(short8*)(out + i) = o;
}

// ---------------------------------------------------------------- 256x256 8-phase GEMM
// (liveness ledger: see round-4 comments). GM=16 supertile: all 16 m-tiles share
// one n-sweep so B is HBM-fetched ~once (XCD-concurrent blocks share B panels in L2).

#define STG(ISB, BUF, KH, TILE) do { \
  const short* _src = (ISB) ? Bt : A; \
  const int _r0 = (ISB) ? n0 : m0; \
  short* _lb = lds_ + ((ISB) ? 32768 : 0) + ((BUF)*2+(KH))*8192; \
  const int _kt = (TILE)*64 + (KH)*32; \
  { int _row = (wid*2)*16 + srow; int _sl = sps ^ ((_row>>1)&3); \
    gl_lds16(_src + (size_t)(_r0+_row)*K + _kt + _sl*8, _lb + (wid*2)*512); } \
  { int _row = (wid*2+1)*16 + srow; int _sl = sps ^ ((_row>>1)&3); \
    gl_lds16(_src + (size_t)(_r0+_row)*K + _kt + _sl*8, _lb + (wid*2+1)*512); } \
} while(0)

#define NOPS ((void)0)
#define VM6 asm volatile("s_waitcnt vmcnt(6)" ::: "memory")
#define VM0 asm volatile("s_waitcnt vmcnt(0)" ::: "memory")

#define PH(BUF, KH, MIH, DOB, STGS, VMW) do { \
  _Pragma("unroll") \
  for (int _m = 0; _m < 4; ++_m) { \
    int _row = wr*128 + ((MIH)*4+_m)*16 + fr; \
    af[_m] = *(const short8*)(lds_ + ((BUF)*2+(KH))*8192 + _row*32 + ((slot ^ ((_row>>1)&3))<<3)); \
  } \
  if (DOB) { \
    _Pragma("unroll") \
    for (int _n = 0; _n < 4; ++_n) { \
      int _row = wc*64 + _n*16 + fr; \
      bf_[_n] = *(const short8*)(lds_ + 32768 + ((BUF)*2+(KH))*8192 + _row*32 + ((slot ^ ((_row>>1)&3))<<3)); \
    } \
  } \
  STGS; VMW; \
  __builtin_amdgcn_s_barrier(); \
  asm volatile("s_waitcnt lgkmcnt(0)" ::: "memory"); \
  __builtin_amdgcn_sched_barrier(0); \
  __builtin_amdgcn_s_setprio(1); \
  _Pragma("unroll") \
  for (int _m = 0; _m < 4; ++_m) \
    _Pragma("unroll") \
    for (int _n = 0; _n < 4; ++_n) \
      acc[(MIH)*4+_m][_n] = mfma16(af[_m], bf_[_n], acc[(MIH)*4+_m][_n]); \
  __builtin_amdgcn_s_setprio(0); \
  __builtin_amdgcn_s_barrier(); \
} while(0)

template<int CB16>
__global__ __launch_bounds__(512, 2) void gemm256_k(const short* __restrict__ A,
                                                    const short* __restrict__ Bt,
                                                    void* __restrict__ Cout,
                                                    int Nstride, int K, int ntn) {
  __shared__ short lds_[65536];  // 128 KiB
  const int tid = threadIdx.x, wid = tid >> 6, lane = tid & 63;
  // XCD-bijective chunk + GM=16 m-supertile decode
  const int nwg = gridDim.x, orig = blockIdx.x;
  const int swz = (orig & 7) * (nwg >> 3) + (orig >> 3);
  const int per_group = ntn << 4;
  const int group = swz / per_group;
  const int rem = swz - group * per_group;
  const int m0 = (group * 16 + (rem & 15)) * 256;
  const int n0 = (rem >> 4) * 256;
  const int wr = wid >> 2, wc = wid & 3;
  const int fr = lane & 15, slot = lane >> 4;
  const int srow = lane >> 2, sps = lane & 3;

  f32x4 acc[8][4] = {};
  short8 af[4], bf_[4];
  const int NT = K >> 6;

  STG(1, 0, 0, 0); STG(0, 0, 0, 0); STG(1, 0, 1, 0); STG(0, 0, 1, 0);
  asm volatile("s_waitcnt vmcnt(4)" ::: "memory");
  STG(1, 1, 0, 1); STG(0, 1, 0, 1); STG(1, 1, 1, 1);
  asm volatile("s_waitcnt vmcnt(6)" ::: "memory");
  __builtin_amdgcn_s_barrier();

  for (int i = 0; i < (NT >> 1) - 1; ++i) {
    const int t = 2 * i;
    PH(0, 0, 0, 1, STG(0, 1, 1, t + 1), NOPS);
    PH(0, 0, 1, 0, STG(1, 0, 0, t + 2), NOPS);
    PH(0, 1, 0, 1, STG(0, 0, 0, t + 2), NOPS);
    PH(0, 1, 1, 0, STG(1, 0, 1, t + 2), VM6);
    PH(1, 0, 0, 1, STG(0, 0, 1, t + 2), NOPS);
    PH(1, 0, 1, 0, STG(1, 1, 0, t + 3), NOPS);
    PH(1, 1, 0, 1, STG(0, 1, 0, t + 3), NOPS);
    PH(1, 1, 1, 0, STG(1, 1, 1, t + 3), VM6);
  }
  // epilogue: stage the missing A buf1 kh1 <- NT-1 at ph1; drain all at ph4.
  PH(0, 0, 0, 1, STG(0, 1, 1, NT - 1), NOPS);
  PH(0, 0, 1, 0, NOPS, NOPS);
  PH(0, 1, 0, 1, NOPS, NOPS);
  PH(0, 1, 1, 0, NOPS, VM0);
  PH(1, 0, 0, 1, NOPS, NOPS);
  PH(1, 0, 1, 0, NOPS, NOPS);
  PH(1, 1, 0, 1, NOPS, NOPS);
  PH(1, 1, 1, 0, NOPS, NOPS);

  const int er = (lane >> 4) * 4, ec = lane & 15;
  if (CB16) {
    short* C = (short*)Cout;
#pragma unroll
    for (int mi = 0; mi < 8; ++mi)
#pragma unroll
      for (int j = 0; j < 4; ++j) {
        size_t base = (size_t)(m0 + wr * 128 + mi * 16 + er + j) * Nstride + n0 + wc * 64 + ec;
#pragma unroll
        for (int ni = 0; ni < 4; ++ni) C[base + ni * 16] = f2bf(acc[mi][ni][j]);
      }
  } else {
    float* C = (float*)Cout;
#pragma unroll
    for (int mi = 0; mi < 8; ++mi)
#pragma unroll
      for (int j = 0; j < 4; ++j) {
        size_t base = (size_t)(m0 + wr * 128 + mi * 16 + er + j) * Nstride + n0 + wc * 64 + ec;
#pragma unroll
        for (int ni = 0; ni < 4; ++ni) C[base + ni * 16] = acc[mi][ni][j];
      }
  }
}

// ---------------------------------------------------------------- conv + silu (sliding window, read-once)
__global__ __launch_bounds__(256) void conv_silu_k(const short* __restrict__ projb,
                                                   const float* __restrict__ convw,
                                                   const float* __restrict__ convb,
                                                   short* __restrict__ hbc) {
  const int c = blockIdx.x * 256 + threadIdx.x;
  const int s0 = blockIdx.y * 256;
  const int b = blockIdx.z;
  const size_t rb = (size_t)b * S_LEN;
  const float* wp = convw + (size_t)c * 4;
  const float w0 = wp[0], w1 = wp[1], w2 = wp[2], w3 = wp[3];
  const float bias = convb[c];
  const short* pcol = projb + INTER + c;
  float x1 = 0.f, x2 = 0.f, x3 = 0.f;  // s-1, s-2, s-3
  if (s0 > 0) {
    x3 = bf2f(pcol[(rb + s0 - 3) * PROJP]);
    x2 = bf2f(pcol[(rb + s0 - 2) * PROJP]);
    x1 = bf2f(pcol[(rb + s0 - 1) * PROJP]);
  }
  for (int s = s0; s < s0 + 256; ++s) {
    float v = bf2f(pcol[(rb + s) * PROJP]);
    float acc = bias + w0 * x3 + w1 * x2 + w2 * x1 + w3 * v;
    float o = acc * sigmoidf_(acc);
    hbc[(rb + s) * CONVD + c] = f2bf(o);
    x3 = x2; x2 = x1; x1 = v;
  }
}

// ---------------------------------------------------------------- dt softplus + per-chunk cumsum (fused)
__global__ __launch_bounds__(128) void acum_k(const short* __restrict__ projb,
                                              const float* __restrict__ dt_bias,
                                              const float* __restrict__ A_log,
                                              float* __restrict__ dtT,
                                              float* __restrict__ acum) {
  const int l = threadIdx.x;
  const int z = blockIdx.x, h = blockIdx.y, b = blockIdx.z;
  const float A = -__expf(A_log[h]);
  __shared__ float sv[128];
  const int r = b * S_LEN + z * 128 + l;
  float xv = bf2f(projb[(size_t)r * PROJP + INTER + CONVD + h]) + dt_bias[h];
  float sp = (xv > 20.f) ? xv : log1pf(__expf(xv));
  sp = fminf(fmaxf(sp, 0.f), 100.f);
  const size_t base = ((size_t)(b * NH + h)) * S_LEN + z * 128;
  dtT[base + l] = sp;
  sv[l] = sp * A;
  __syncthreads();
  for (int off = 1; off < 128; off <<= 1) {
    float t = (l >= off) ? sv[l - off] : 0.f;
    __syncthreads();
    sv[l] += t;
    __syncthreads();
  }
  acum[base + l] = sv[l];
}

// ---------------------------------------------------------------- states per (b,z,g): operand-swapped
// st[p][n] = sum_s xdt_dec[s][p] * B[s][n], decay folded into sxdt (dv = dt*exp(acL-ac)).
// sBT [n][l] bf16 built once from global (conflict-free u16 writes); writes states [p][n] fp32.
__global__ __launch_bounds__(512) void states_k(const short* __restrict__ hbc,
                                                const float* __restrict__ dtT,
                                                const float* __restrict__ acum,
                                                float* __restrict__ states) {
  __shared__ short sBT[128 * 128];  // [n][l]
  __shared__ short sxdt[64 * 128];  // [p][s], decayed
  const int tid = threadIdx.x, wid = tid >> 6, lane = tid & 63;
  const int g = blockIdx.x, z = blockIdx.y, b = blockIdx.z;
  const size_t srow0 = (size_t)(b * S_LEN + z * 128);
  const short* hrow = hbc + srow0 * CONVD;

  {  // sBT build (once): thread (l = tid&127, n0 = (tid>>7)*32)
    const int l = tid & 127, n0b = (tid >> 7) * 32;
    const short* src = hrow + (size_t)l * CONVD + INTER + g * NS + n0b;
    short8 v0 = *(const short8*)(src);
    short8 v1 = *(const short8*)(src + 8);
    short8 v2 = *(const short8*)(src + 16);
    short8 v3 = *(const short8*)(src + 24);
#pragma unroll
    for (int j = 0; j < 8; ++j) {
      sBT[(n0b + j) * 128 + l] = v0[j];
      sBT[(n0b + 8 + j) * 128 + l] = v1[j];
      sBT[(n0b + 16 + j) * 128 + l] = v2[j];
      sBT[(n0b + 24 + j) * 128 + l] = v3[j];
    }
  }

  const int fr = lane & 15, fk8 = (lane >> 4) * 8;
  const int er = (lane >> 4) * 4, ec = lane & 15;
  const int pband = (wid & 3) * 16, nhalf = (wid >> 2) * 64;
  const int s2 = tid & 63, p0w = (tid >> 6) * 8;
  unsigned int* sx32 = (unsigned int*)sxdt;

  for (int hh = 0; hh < 16; ++hh) {
    const int h = g * 16 + hh;
    const float* ac_g = acum + ((size_t)(b * NH + h)) * S_LEN + z * 128;
    const float* dts = dtT + ((size_t)(b * NH + h)) * S_LEN + z * 128;
    __syncthreads();  // prior head's sxdt reads done (hh=0: sBT build done)
    {
      const float acL = ac_g[127];
      float dv0 = dts[2 * s2] * __expf(acL - ac_g[2 * s2]);
      float dv1 = dts[2 * s2 + 1] * __expf(acL - ac_g[2 * s2 + 1]);
      const short* rsrc = hrow + (size_t)(2 * s2) * CONVD + (size_t)h * PD + p0w;
      short8 r0 = *(const short8*)(rsrc);
      short8 r1 = *(const short8*)(rsrc + CONVD);
#pragma unroll
      for (int j = 0; j < 8; ++j) {
        unsigned int lo = (unsigned short)f2bf(bf2f(r0[j]) * dv0);
        unsigned int hi = (unsigned short)f2bf(bf2f(r1[j]) * dv1);
        sx32[(p0w + j) * 64 + s2] = lo | (hi << 16);
      }
    }
    __syncthreads();
    f32x4 st[4] = {};
#pragma unroll
    for (int kk = 0; kk < 4; ++kk) {
      short8 a = *(const short8*)(sxdt + (pband + fr) * 128 + kk * 32 + fk8);
#pragma unroll
      for (int ni = 0; ni < 4; ++ni) {
        short8 bb = *(const short8*)(sBT + (nhalf + ni * 16 + fr) * 128 + kk * 32 + fk8);
        st[ni] = mfma16(a, bb, st[ni]);
      }
    }
    float* stp = states + (((size_t)(b * NC + z)) * NH + h) * (size_t)(NS * PD);
#pragma unroll
    for (int ni = 0; ni < 4; ++ni)
#pragma unroll
      for (int j = 0; j < 4; ++j)
        stp[(pband + er + j) * NS + nhalf + ni * 16 + ec] = st[ni][j];
  }
}

// ---------------------------------------------------------------- inter-chunk scan
// reads fp32 states [p][n]; writes prev (pre-update E) as bf16 [p][n] COALESCED,
// in-place into the first half of each slab (reads precede writes per chunk).
__global__ __launch_bounds__(256) void scan_k(float* __restrict__ states,
                                              const float* __restrict__ acum) {
  const int h = blockIdx.x, b = blockIdx.y;
  const int tid = threadIdx.x;
  float* stp = states + ((size_t)(b * NC * NH) + h) * (size_t)(NS * PD);
  const size_t cst = (size_t)NH * NS * PD;
  const float* ac = acum + ((size_t)(b * NH + h)) * S_LEN;
  float E[32];
#pragma unroll
  for (int i = 0; i < 32; ++i) E[i] = 0.f;
  const int n = tid & 127, pg = tid >> 7;
  for (int zz = 0; zz < NC; ++zz) {
    float* sz = stp + (size_t)zz * cst;
    short* pvb = (short*)sz;
    float tmp[32];
#pragma unroll
    for (int i = 0; i < 32; ++i) tmp[i] = sz[i * 256 + tid];
    __syncthreads();
    float dec = __expf(ac[zz * 128 + 127]);
#pragma unroll
    for (int i = 0; i < 32; ++i) {
      int p = i * 2 + pg;
      pvb[p * 128 + n] = f2bf(E[i]);   // prev entering chunk zz, bf16 [p][n]
      E[i] = dec * E[i] + tmp[i];
    }
    __syncthreads();
  }
}

// ---------------------------------------------------------------- fused Y + gate + group-RMS-norm per (b,z,g)
__global__ __launch_bounds__(512) void yfull_k(const short* __restrict__ hbc,
                                               const short* __restrict__ projb,
                                               const float* __restrict__ dtT,
                                               const float* __restrict__ acum,
                                               const float* __restrict__ states,
                                               const float* __restrict__ Dv,
                                               const float* __restrict__ norm_w,
                                               float* __restrict__ Yg,
                                               short* __restrict__ normed) {
  __shared__ short lds[50176];  // sC 16384 | sB 16384 (overlaid sxdt 8192 + sprev 8192) | sP 8x2176
  __shared__ float sac[128];
  __shared__ float sScale[128];
  __shared__ float sNW[1024];
  short* sC = lds;
  short* sB = lds + 16384;
  short* sxdt = lds + 16384;
  short* sprev = lds + 16384 + 8192;
  const int tid = threadIdx.x, wid = tid >> 6, lane = tid & 63;
  short* sPw = lds + 32768 + wid * 2176;  // per-wave 16x136 P band (136: 4-way not 8-way)
  const int g = blockIdx.x, z = blockIdx.y, b = blockIdx.z;
  const size_t srow0 = (size_t)(b * S_LEN + z * 128);
  const short* hrow = hbc + srow0 * CONVD;

  {
    const int n0_ = (lane & 15) * 8;
#pragma unroll
    for (int it = 0; it < 4; ++it) {
      int s = it * 32 + wid * 4 + (lane >> 4);
      gl_lds16(hrow + (size_t)s * CONVD + INTER + GN + g * NS + n0_, sC + (it * 32 + wid * 4) * 128);
      gl_lds16(hrow + (size_t)s * CONVD + INTER + g * NS + n0_, sB + (it * 32 + wid * 4) * 128);
    }
  }
  for (int i = tid; i < 1024; i += 512) sNW[i] = norm_w[g * 1024 + i];
  __syncthreads();  // drains gl_lds vmcnt; sNW visible

  const int fr = lane & 15, fk8 = (lane >> 4) * 8;
  const int er = (lane >> 4) * 4, ec = lane & 15;
  const int lrow = wid * 16;
  const int s2 = tid & 63, p0w = (tid >> 6) * 8;
  unsigned int* sx32 = (unsigned int*)sxdt;

  f32x4 sc[8] = {};
#pragma unroll
  for (int kk = 0; kk < 4; ++kk) {
    short8 a = *(const short8*)(sC + (lrow + fr) * 128 + kk * 32 + fk8);
#pragma unroll
    for (int si = 0; si < 8; ++si) {
      short8 bv = *(const short8*)(sB + (si * 16 + fr) * 128 + kk * 32 + fk8);
      sc[si] = mfma16(a, bv, sc[si]);
    }
  }

  float rssq[4] = {0.f, 0.f, 0.f, 0.f};

  for (int hh = 0; hh < 16; ++hh) {
    const int h = g * 16 + hh;
    const float* ac = acum + ((size_t)(b * NH + h)) * S_LEN + z * 128;
    const float* dts = dtT + ((size_t)(b * NH + h)) * S_LEN + z * 128;
    const short* pvb = (const short*)(states + (((size_t)(b * NC + z)) * NH + h) * (size_t)(NS * PD));
    __syncthreads();  // prior head reads done; hh=0: scores reads of sB done
    if (tid < 128) sac[tid] = ac[tid];
    {
      float dv0 = dts[2 * s2], dv1 = dts[2 * s2 + 1];
      const short* rsrc = hrow + (size_t)(2 * s2) * CONVD + (size_t)h * PD + p0w;
      short8 r0 = *(const short8*)(rsrc);
      short8 r1 = *(const short8*)(rsrc + CONVD);
#pragma unroll
      for (int j = 0; j < 8; ++j) {
        unsigned int lo = (unsigned short)f2bf(bf2f(r0[j]) * dv0);
        unsigned int hi = (unsigned short)f2bf(bf2f(r1[j]) * dv1);
        sx32[(p0w + j) * 64 + s2] = lo | (hi << 16);
      }
    }
    // stage prev (bf16 [p][n], 8192 shorts) via gl_lds: wave w rows p=w*8..w*8+7
    gl_lds16(pvb + wid * 1024 + lane * 8, sprev + wid * 1024);
    gl_lds16(pvb + wid * 1024 + 512 + lane * 8, sprev + wid * 1024 + 512);
    __syncthreads();  // drains lgkm + vmcnt

    {
      float acS[8];
#pragma unroll
      for (int si = 0; si < 8; ++si) acS[si] = sac[si * 16 + ec];
#pragma unroll
      for (int j = 0; j < 4; ++j) {
        int lloc = er + j;
        float acl = sac[lrow + lloc];
#pragma unroll
        for (int si = 0; si < 8; ++si) {
          int s = si * 16 + ec;
          float v = (s <= lrow + lloc) ? sc[si][j] * __expf(acl - acS[si]) : 0.f;
          sPw[lloc * 136 + s] = f2bf(v);
        }
      }
    }
    f32x4 yd[4] = {}, yo[4] = {};
#pragma unroll
    for (int kk = 0; kk < 4; ++kk) {
      short8 ap = *(const short8*)(sPw + fr * 136 + kk * 32 + fk8);
      short8 acf = *(const short8*)(sC + (lrow + fr) * 128 + kk * 32 + fk8);
#pragma unroll
      for (int ni = 0; ni < 4; ++ni) {
        short8 bv = *(const short8*)(sxdt + (ni * 16 + fr) * 128 + kk * 32 + fk8);
        yd[ni] = mfma16(ap, bv, yd[ni]);
        short8 bp = *(const short8*)(sprev + (ni * 16 + fr) * 128 + kk * 32 + fk8);
        yo[ni] = mfma16(acf, bp, yo[ni]);
      }
    }
    const float Dh = Dv[h];
#pragma unroll
    for (int j = 0; j < 4; ++j) {
      int l = lrow + er + j;
      float e_ac = __expf(sac[l]);
#pragma unroll
      for (int ni = 0; ni < 4; ++ni) {
        int p = ni * 16 + ec;
        float hs = bf2f(hrow[(size_t)l * CONVD + (size_t)h * PD + p]);
        float y = yd[ni][j] + yo[ni][j] * e_ac + hs * Dh;
        float gate = bf2f(projb[(srow0 + l) * (size_t)PROJP + (size_t)h * PD + p]);
        float gg = y * gate * sigmoidf_(gate);
        Yg[(srow0 + l) * (size_t)INTER + (size_t)h * PD + p] = gg;
        rssq[j] += gg * gg;
      }
    }
  }

#pragma unroll
  for (int j = 0; j < 4; ++j) {
#pragma unroll
    for (int m = 1; m <= 8; m <<= 1) rssq[j] += __shfl_xor(rssq[j], m, 64);
  }
  if (ec == 0) {
#pragma unroll
    for (int j = 0; j < 4; ++j) sScale[lrow + er + j] = rsqrtf(rssq[j] * (1.f / 1024.f) + 1e-5f);
  }
  __syncthreads();  // also makes all Yg writes visible (vmcnt drained)

  for (int e = tid * 8; e < 128 * 1024; e += 4096) {
    int row = e >> 10, ch = e & 1023;
    const float* gp = Yg + (srow0 + row) * (size_t)INTER + g * 1024 + ch;
    float4 g0 = *(const float4*)(gp);
    float4 g1 = *(const float4*)(gp + 4);
    float scl = sScale[row];
    short8 o;
    o[0] = f2bf(g0.x * scl * sNW[ch + 0]); o[1] = f2bf(g0.y * scl * sNW[ch + 1]);
    o[2] = f2bf(g0.z * scl * sNW[ch + 2]); o[3] = f2bf(g0.w * scl * sNW[ch + 3]);
    o[4] = f2bf(g1.x * scl * sNW[ch + 4]); o[5] = f2bf(g1.y * scl * sNW[ch + 5]);
    o[6] = f2bf(g1.z * scl * sNW[ch + 6]); o[7] = f2bf(g1.w * scl * sNW[ch + 7]);
    *(short8*)(normed + (srow0 + row) * (size_t)INTER + g * 1024 + ch) = o;
  }
}

// ----------------------------------------------------------------
extern "C" void kernel_launch(void* const* d_in, const int* in_sizes, int n_in,
                              void* d_out, int out_size, void* d_ws, size_t ws_size,
                              hipStream_t stream) {
  const float* x     = (const float*)d_in[0];
  const float* w1    = (const float*)d_in[1];
  const float* convw = (const float*)d_in[2];
  const float* convb = (const float*)d_in[3];
  const float* dtb   = (const float*)d_in[4];
  const float* alog  = (const float*)d_in[5];
  const float* Dv    = (const float*)d_in[6];
  const float* nw    = (const float*)d_in[7];
  const float* w2    = (const float*)d_in[8];
  float* out = (float*)d_out;

  char* ws = (char*)d_ws;
  size_t off = 0;
  float* dtT = (float*)(ws + off);  off += (size_t)BB * NH * S_LEN * 4;
  float* acum = (float*)(ws + off); off += (size_t)BB * NH * S_LEN * 4;
  short* xb = (short*)(ws + off);   off += (size_t)BS * HID_DIM * 2;
  char* w1region = ws + off;        off += (size_t)PROJP * HID_DIM * 2;
  short* w1b = (short*)w1region;
  short* normed = (short*)w1region;                              // reuse after gemm1
  short* w2b = (short*)(w1region + (size_t)BS * INTER * 2);      // reuse after gemm1
  short* projb = (short*)(ws + off); off += (size_t)BS * PROJP * 2;
  short* hbc = (short*)(ws + off);   off += (size_t)BS * CONVD * 2;
  float* Y = (float*)(ws + off);     off += (size_t)BS * INTER * 4;
  float* states = (float*)(ws + off); off += (size_t)BB * NC * NH * NS * PD * 4;

  const size_t nx = (size_t)BS * HID_DIM;
  const size_t nw1 = (size_t)PROJ * HID_DIM;
  const size_t nw2 = (size_t)HID_DIM * INTER;

  cvt_f32_bf16_k<<<dim3(nx / 2048), 256, 0, stream>>>(x, xb, nx);
  cvt_f32_bf16_k<<<dim3(nw1 / 2048), 256, 0, stream>>>(w1, w1b, nw1);

  // gemm1: [4096 x 18560(pad 18688)] = xb[4096x4096] * w1b^T ; 16 x 73 tiles
  gemm256_k<1><<<dim3(16 * 73), 512, 0, stream>>>(xb, w1b, projb, PROJP, HID_DIM, 73);

  // w1b dead now; stage w2 into its region
  cvt_f32_bf16_k<<<dim3(nw2 / 2048), 256, 0, stream>>>(w2, w2b, nw2);

  conv_silu_k<<<dim3(CONVD / 256, S_LEN / 256, BB), 256, 0, stream>>>(projb, convw, convb, hbc);
  acum_k<<<dim3(NC, NH, BB), 128, 0, stream>>>(projb, dtb, alog, dtT, acum);

  states_k<<<dim3(NG, NC, BB), 512, 0, stream>>>(hbc, dtT, acum, states);
  scan_k<<<dim3(NH, BB), 256, 0, stream>>>(states, acum);
  yfull_k<<<dim3(NG, NC, BB), 512, 0, stream>>>(hbc, projb, dtT, acum, states, Dv, nw, Y, normed);

  // gemm2: [4096 x 4096] = normed[4096x8192] * w2b^T ; 16 x 16 tiles
  gemm256_k<0><<<dim3(16 * 16), 512, 0, stream>>>(normed, w2b, out, HID_DIM, INTER, 16);
}

// Round 8
// 1249.756 us; speedup vs baseline: 1.6743x; 1.0290x over previous
//
#include <hip/hip_runtime.h>
#include <hip/hip_bf16.h>
#include <cstdint>
#include <cstddef>

#define DEVI __device__ __forceinline__

#define BB 2
#define S_LEN 2048
#define HID_DIM 4096
#define NH 128
#define PD 64
#define NS 128
#define NG 8
#define INTER 8192
#define CONVD 10240
#define PROJ 18560
#define PROJP 18688   // padded to 73*256 for 256-wide GEMM tiles
#define NC 16
#define BS 4096
#define GN 1024   // NG*NS

using short8 = __attribute__((ext_vector_type(8))) short;
using short4v = __attribute__((ext_vector_type(4))) short;
using f32x4  = __attribute__((ext_vector_type(4))) float;
using bf16x8 = __attribute__((ext_vector_type(8))) __bf16;

DEVI float bf2f(short u) {
  union { unsigned int i; float f; } v;
  v.i = ((unsigned int)(unsigned short)u) << 16;
  return v.f;
}
DEVI short f2bf(float f) {
  union { float ff; unsigned int i; } v; v.ff = f;
  unsigned int x = v.i;
  return (short)((x + 0x7fffu + ((x >> 16) & 1u)) >> 16);
}
DEVI f32x4 mfma16(short8 a, short8 b, f32x4 c) {
  return __builtin_amdgcn_mfma_f32_16x16x32_bf16(
      __builtin_bit_cast(bf16x8, a), __builtin_bit_cast(bf16x8, b), c, 0, 0, 0);
}
DEVI void gl_lds16(const short* g, short* l) {
  __builtin_amdgcn_global_load_lds(
      (const __attribute__((address_space(1))) void*)g,
      (__attribute__((address_space(3))) void*)l, 16, 0, 0);
}
DEVI float sigmoidf_(float x) { return 1.f / (1.f + __expf(-x)); }

// ---------------------------------------------------------------- converts
__global__ __launch_bounds__(256) void cvt_f32_bf16_k(const float* __restrict__ in,
                                                      short* __restrict__ out, size_t n) {
  size_t i = ((size_t)blockIdx.x * 256 + threadIdx.x) * 8;
  if (i + 8 > n) return;
  float4 a = *(const float4*)(in + i);
  float4 b = *(const float4*)(in + i + 4);
  short8 o;
  o[0] = f2bf(a.x); o[1] = f2bf(a.y); o[2] = f2bf(a.z); o[3] = f2bf(a.w);
  o[4] = f2bf(b.x); o[5] = f2bf(b.y); o[6] = f2bf(b.z); o[7] = f2bf(b.w);
  *(short8*)(out + i) = o;
}

// ---------------------------------------------------------------- 256x256 8-phase GEMM, reg-dbuf frags
// Staging/VM ledger as round-4. NEW: fragment double-buffer — phase p prefetches
// p+1's LDS fragments during p's MFMA; lgkmcnt(0)+sched_barrier after MFMA.
// Prefetch safety (all verified): read(p+1) completes by end of p (lgkm0);
// earliest overwrite of that region is a STG >= 1 phase later; every prefetch
// source region is VM-guaranteed (ph1's A11 by ph4's VM6; epilogue by ph4 VM0).

#define STG(ISB, BUF, KH, TILE) do { \
  const short* _src = (ISB) ? Bt : A; \
  const int _r0 = (ISB) ? n0 : m0; \
  short* _lb = lds_ + ((ISB) ? 32768 : 0) + ((BUF)*2+(KH))*8192; \
  const int _kt = (TILE)*64 + (KH)*32; \
  { int _row = (wid*2)*16 + srow; int _sl = sps ^ ((_row>>1)&3); \
    gl_lds16(_src + (size_t)(_r0+_row)*K + _kt + _sl*8, _lb + (wid*2)*512); } \
  { int _row = (wid*2+1)*16 + srow; int _sl = sps ^ ((_row>>1)&3); \
    gl_lds16(_src + (size_t)(_r0+_row)*K + _kt + _sl*8, _lb + (wid*2+1)*512); } \
} while(0)

#define NOPS ((void)0)
#define VM6 asm volatile("s_waitcnt vmcnt(6)" ::: "memory")
#define VM0 asm volatile("s_waitcnt vmcnt(0)" ::: "memory")

#define LDAF(DST, BUF, KH, MIH) do { \
  _Pragma("unroll") \
  for (int _m = 0; _m < 4; ++_m) { \
    int _row = wr*128 + ((MIH)*4+_m)*16 + fr; \
    DST[_m] = *(const short8*)(lds_ + ((BUF)*2+(KH))*8192 + _row*32 + ((slot ^ ((_row>>1)&3))<<3)); \
  } \
} while(0)

#define LDBF(DST, BUF, KH) do { \
  _Pragma("unroll") \
  for (int _n = 0; _n < 4; ++_n) { \
    int _row = wc*64 + _n*16 + fr; \
    DST[_n] = *(const short8*)(lds_ + 32768 + ((BUF)*2+(KH))*8192 + _row*32 + ((slot ^ ((_row>>1)&3))<<3)); \
  } \
} while(0)

// phase: stage -> vm -> barrier -> prefetch(p+1 frags) -> MFMA(cur frags) -> lgkm0 -> barrier
#define PH2(CAF, CBF, MIH, PFEN, PFAF, PFBF, PFB, PFKH, PFMIH, PFDOB, STGS, VMW) do { \
  STGS; VMW; \
  __builtin_amdgcn_s_barrier(); \
  if (PFEN) { LDAF(PFAF, PFB, PFKH, PFMIH); if (PFDOB) LDBF(PFBF, PFB, PFKH); } \
  __builtin_amdgcn_s_setprio(1); \
  _Pragma("unroll") \
  for (int _m = 0; _m < 4; ++_m) \
    _Pragma("unroll") \
    for (int _n = 0; _n < 4; ++_n) \
      acc[(MIH)*4+_m][_n] = mfma16(CAF[_m], CBF[_n], acc[(MIH)*4+_m][_n]); \
  __builtin_amdgcn_s_setprio(0); \
  asm volatile("s_waitcnt lgkmcnt(0)" ::: "memory"); \
  __builtin_amdgcn_sched_barrier(0); \
  __builtin_amdgcn_s_barrier(); \
} while(0)

template<int CB16>
__global__ __launch_bounds__(512, 2) void gemm256_k(const short* __restrict__ A,
                                                    const short* __restrict__ Bt,
                                                    void* __restrict__ Cout,
                                                    int Nstride, int K, int ntn) {
  __shared__ short lds_[65536];  // 128 KiB
  const int tid = threadIdx.x, wid = tid >> 6, lane = tid & 63;
  // XCD-bijective chunk + GM=8 m-supertile decode
  const int nwg = gridDim.x, orig = blockIdx.x;
  const int swz = (orig & 7) * (nwg >> 3) + (orig >> 3);
  const int per_group = ntn << 3;
  const int group = swz / per_group;
  const int rem = swz - group * per_group;
  const int m0 = (group * 8 + (rem & 7)) * 256;
  const int n0 = (rem >> 3) * 256;
  const int wr = wid >> 2, wc = wid & 3;
  const int fr = lane & 15, slot = lane >> 4;
  const int srow = lane >> 2, sps = lane & 3;

  f32x4 acc[8][4] = {};
  short8 af_a[4], af_b[4], bf_a[4], bf_b[4];
  const int NT = K >> 6;

  // prologue staging: tile0 (4 halves) + tile1 (3 halves)
  STG(1, 0, 0, 0); STG(0, 0, 0, 0); STG(1, 0, 1, 0); STG(0, 0, 1, 0);
  asm volatile("s_waitcnt vmcnt(4)" ::: "memory");
  STG(1, 1, 0, 1); STG(0, 1, 0, 1); STG(1, 1, 1, 1);
  asm volatile("s_waitcnt vmcnt(6)" ::: "memory");
  __builtin_amdgcn_s_barrier();
  // preload ph1 fragments
  LDAF(af_a, 0, 0, 0); LDBF(bf_a, 0, 0);
  asm volatile("s_waitcnt lgkmcnt(0)" ::: "memory");
  __builtin_amdgcn_sched_barrier(0);

  for (int i = 0; i < (NT >> 1) - 1; ++i) {
    const int t = 2 * i;
    PH2(af_a, bf_a, 0, 1, af_b, bf_a, 0, 0, 1, 0, STG(0, 1, 1, t + 1), NOPS);  // ph1
    PH2(af_b, bf_a, 1, 1, af_a, bf_b, 0, 1, 0, 1, STG(1, 0, 0, t + 2), NOPS);  // ph2
    PH2(af_a, bf_b, 0, 1, af_b, bf_a, 0, 1, 1, 0, STG(0, 0, 0, t + 2), NOPS);  // ph3
    PH2(af_b, bf_b, 1, 1, af_a, bf_a, 1, 0, 0, 1, STG(1, 0, 1, t + 2), VM6);   // ph4
    PH2(af_a, bf_a, 0, 1, af_b, bf_b, 1, 0, 1, 0, STG(0, 0, 1, t + 2), NOPS);  // ph5
    PH2(af_b, bf_a, 1, 1, af_a, bf_b, 1, 1, 0, 1, STG(1, 1, 0, t + 3), NOPS);  // ph6
    PH2(af_a, bf_b, 0, 1, af_b, bf_a, 1, 1, 1, 0, STG(0, 1, 0, t + 3), NOPS);  // ph7
    PH2(af_b, bf_b, 1, 1, af_a, bf_a, 0, 0, 0, 1, STG(1, 1, 1, t + 3), VM6);   // ph8
  }
  // epilogue (tiles NT-2 buf0, NT-1 buf1); ph1 stages A11<-NT-1; VM0 at ph4
  PH2(af_a, bf_a, 0, 1, af_b, bf_a, 0, 0, 1, 0, STG(0, 1, 1, NT - 1), NOPS);
  PH2(af_b, bf_a, 1, 1, af_a, bf_b, 0, 1, 0, 1, NOPS, NOPS);
  PH2(af_a, bf_b, 0, 1, af_b, bf_a, 0, 1, 1, 0, NOPS, NOPS);
  PH2(af_b, bf_b, 1, 1, af_a, bf_a, 1, 0, 0, 1, NOPS, VM0);
  PH2(af_a, bf_a, 0, 1, af_b, bf_b, 1, 0, 1, 0, NOPS, NOPS);
  PH2(af_b, bf_a, 1, 1, af_a, bf_b, 1, 1, 0, 1, NOPS, NOPS);
  PH2(af_a, bf_b, 0, 1, af_b, bf_a, 1, 1, 1, 0, NOPS, NOPS);
  PH2(af_b, bf_b, 1, 0, af_a, bf_a, 0, 0, 0, 0, NOPS, NOPS);

  const int er = (lane >> 4) * 4, ec = lane & 15;
  if (CB16) {
    short* C = (short*)Cout;
#pragma unroll
    for (int mi = 0; mi < 8; ++mi)
#pragma unroll
      for (int j = 0; j < 4; ++j) {
        size_t base = (size_t)(m0 + wr * 128 + mi * 16 + er + j) * Nstride + n0 + wc * 64 + ec;
#pragma unroll
        for (int ni = 0; ni < 4; ++ni) C[base + ni * 16] = f2bf(acc[mi][ni][j]);
      }
  } else {
    float* C = (float*)Cout;
#pragma unroll
    for (int mi = 0; mi < 8; ++mi)
#pragma unroll
      for (int j = 0; j < 4; ++j) {
        size_t base = (size_t)(m0 + wr * 128 + mi * 16 + er + j) * Nstride + n0 + wc * 64 + ec;
#pragma unroll
        for (int ni = 0; ni < 4; ++ni) C[base + ni * 16] = acc[mi][ni][j];
      }
  }
}

// ---------------------------------------------------------------- conv + silu (sliding window, read-once)
__global__ __launch_bounds__(256) void conv_silu_k(const short* __restrict__ projb,
                                                   const float* __restrict__ convw,
                                                   const float* __restrict__ convb,
                                                   short* __restrict__ hbc) {
  const int c = blockIdx.x * 256 + threadIdx.x;
  const int s0 = blockIdx.y * 256;
  const int b = blockIdx.z;
  const size_t rb = (size_t)b * S_LEN;
  const float* wp = convw + (size_t)c * 4;
  const float w0 = wp[0], w1 = wp[1], w2 = wp[2], w3 = wp[3];
  const float bias = convb[c];
  const short* pcol = projb + INTER + c;
  float x1 = 0.f, x2 = 0.f, x3 = 0.f;  // s-1, s-2, s-3
  if (s0 > 0) {
    x3 = bf2f(pcol[(rb + s0 - 3) * PROJP]);
    x2 = bf2f(pcol[(rb + s0 - 2) * PROJP]);
    x1 = bf2f(pcol[(rb + s0 - 1) * PROJP]);
  }
  for (int s = s0; s < s0 + 256; ++s) {
    float v = bf2f(pcol[(rb + s) * PROJP]);
    float acc = bias + w0 * x3 + w1 * x2 + w2 * x1 + w3 * v;
    float o = acc * sigmoidf_(acc);
    hbc[(rb + s) * CONVD + c] = f2bf(o);
    x3 = x2; x2 = x1; x1 = v;
  }
}

// ---------------------------------------------------------------- dt softplus + per-chunk cumsum (fused)
__global__ __launch_bounds__(128) void acum_k(const short* __restrict__ projb,
                                              const float* __restrict__ dt_bias,
                                              const float* __restrict__ A_log,
                                              float* __restrict__ dtT,
                                              float* __restrict__ acum) {
  const int l = threadIdx.x;
  const int z = blockIdx.x, h = blockIdx.y, b = blockIdx.z;
  const float A = -__expf(A_log[h]);
  __shared__ float sv[128];
  const int r = b * S_LEN + z * 128 + l;
  float xv = bf2f(projb[(size_t)r * PROJP + INTER + CONVD + h]) + dt_bias[h];
  float sp = (xv > 20.f) ? xv : log1pf(__expf(xv));
  sp = fminf(fmaxf(sp, 0.f), 100.f);
  const size_t base = ((size_t)(b * NH + h)) * S_LEN + z * 128;
  dtT[base + l] = sp;
  sv[l] = sp * A;
  __syncthreads();
  for (int off = 1; off < 128; off <<= 1) {
    float t = (l >= off) ? sv[l - off] : 0.f;
    __syncthreads();
    sv[l] += t;
    __syncthreads();
  }
  acum[base + l] = sv[l];
}

// ---------------------------------------------------------------- states per (b,z,g): operand-swapped
__global__ __launch_bounds__(512) void states_k(const short* __restrict__ hbc,
                                                const float* __restrict__ dtT,
                                                const float* __restrict__ acum,
                                                float* __restrict__ states) {
  __shared__ short sBT[128 * 128];  // [n][l]
  __shared__ short sxdt[64 * 128];  // [p][s], decayed
  const int tid = threadIdx.x, wid = tid >> 6, lane = tid & 63;
  const int g = blockIdx.x, z = blockIdx.y, b = blockIdx.z;
  const size_t srow0 = (size_t)(b * S_LEN + z * 128);
  const short* hrow = hbc + srow0 * CONVD;

  {  // sBT build (once): thread (l = tid&127, n0 = (tid>>7)*32)
    const int l = tid & 127, n0b = (tid >> 7) * 32;
    const short* src = hrow + (size_t)l * CONVD + INTER + g * NS + n0b;
    short8 v0 = *(const short8*)(src);
    short8 v1 = *(const short8*)(src + 8);
    short8 v2 = *(const short8*)(src + 16);
    short8 v3 = *(const short8*)(src + 24);
#pragma unroll
    for (int j = 0; j < 8; ++j) {
      sBT[(n0b + j) * 128 + l] = v0[j];
      sBT[(n0b + 8 + j) * 128 + l] = v1[j];
      sBT[(n0b + 16 + j) * 128 + l] = v2[j];
      sBT[(n0b + 24 + j) * 128 + l] = v3[j];
    }
  }

  const int fr = lane & 15, fk8 = (lane >> 4) * 8;
  const int er = (lane >> 4) * 4, ec = lane & 15;
  const int pband = (wid & 3) * 16, nhalf = (wid >> 2) * 64;
  const int s2 = tid & 63, p0w = (tid >> 6) * 8;
  unsigned int* sx32 = (unsigned int*)sxdt;

  for (int hh = 0; hh < 16; ++hh) {
    const int h = g * 16 + hh;
    const float* ac_g = acum + ((size_t)(b * NH + h)) * S_LEN + z * 128;
    const float* dts = dtT + ((size_t)(b * NH + h)) * S_LEN + z * 128;
    __syncthreads();  // prior head's sxdt reads done (hh=0: sBT build done)
    {
      const float acL = ac_g[127];
      float dv0 = dts[2 * s2] * __expf(acL - ac_g[2 * s2]);
      float dv1 = dts[2 * s2 + 1] * __expf(acL - ac_g[2 * s2 + 1]);
      const short* rsrc = hrow + (size_t)(2 * s2) * CONVD + (size_t)h * PD + p0w;
      short8 r0 = *(const short8*)(rsrc);
      short8 r1 = *(const short8*)(rsrc + CONVD);
#pragma unroll
      for (int j = 0; j < 8; ++j) {
        unsigned int lo = (unsigned short)f2bf(bf2f(r0[j]) * dv0);
        unsigned int hi = (unsigned short)f2bf(bf2f(r1[j]) * dv1);
        sx32[(p0w + j) * 64 + s2] = lo | (hi << 16);
      }
    }
    __syncthreads();
    f32x4 st[4] = {};
#pragma unroll
    for (int kk = 0; kk < 4; ++kk) {
      short8 a = *(const short8*)(sxdt + (pband + fr) * 128 + kk * 32 + fk8);
#pragma unroll
      for (int ni = 0; ni < 4; ++ni) {
        short8 bb = *(const short8*)(sBT + (nhalf + ni * 16 + fr) * 128 + kk * 32 + fk8);
        st[ni] = mfma16(a, bb, st[ni]);
      }
    }
    float* stp = states + (((size_t)(b * NC + z)) * NH + h) * (size_t)(NS * PD);
#pragma unroll
    for (int ni = 0; ni < 4; ++ni)
#pragma unroll
      for (int j = 0; j < 4; ++j)
        stp[(pband + er + j) * NS + nhalf + ni * 16 + ec] = st[ni][j];
  }
}

// ---------------------------------------------------------------- inter-chunk scan
__global__ __launch_bounds__(256) void scan_k(float* __restrict__ states,
                                              const float* __restrict__ acum) {
  const int h = blockIdx.x, b = blockIdx.y;
  const int tid = threadIdx.x;
  float* stp = states + ((size_t)(b * NC * NH) + h) * (size_t)(NS * PD);
  const size_t cst = (size_t)NH * NS * PD;
  const float* ac = acum + ((size_t)(b * NH + h)) * S_LEN;
  float E[32];
#pragma unroll
  for (int i = 0; i < 32; ++i) E[i] = 0.f;
  const int n = tid & 127, pg = tid >> 7;
  for (int zz = 0; zz < NC; ++zz) {
    float* sz = stp + (size_t)zz * cst;
    short* pvb = (short*)sz;
    float tmp[32];
#pragma unroll
    for (int i = 0; i < 32; ++i) tmp[i] = sz[i * 256 + tid];
    __syncthreads();
    float dec = __expf(ac[zz * 128 + 127]);
#pragma unroll
    for (int i = 0; i < 32; ++i) {
      int p = i * 2 + pg;
      pvb[p * 128 + n] = f2bf(E[i]);   // prev entering chunk zz, bf16 [p][n]
      E[i] = dec * E[i] + tmp[i];
    }
    __syncthreads();
  }
}

// ---------------------------------------------------------------- fused Y + gate + group-RMS-norm per (b,z,g)
// gg written bf16 directly into `normed`; epilogue rescales in place (no fp32 Yg).
__global__ __launch_bounds__(512) void yfull_k(const short* __restrict__ hbc,
                                               const short* __restrict__ projb,
                                               const float* __restrict__ dtT,
                                               const float* __restrict__ acum,
                                               const float* __restrict__ states,
                                               const float* __restrict__ Dv,
                                               const float* __restrict__ norm_w,
                                               short* __restrict__ normed) {
  __shared__ short lds[50176];  // sC 16384 | sB 16384 (overlaid sxdt 8192 + sprev 8192) | sP 8x2176
  __shared__ float sac[128];
  __shared__ float sScale[128];
  __shared__ float sNW[1024];
  short* sC = lds;
  short* sB = lds + 16384;
  short* sxdt = lds + 16384;
  short* sprev = lds + 16384 + 8192;
  const int tid = threadIdx.x, wid = tid >> 6, lane = tid & 63;
  short* sPw = lds + 32768 + wid * 2176;  // per-wave 16x136 P band
  const int g = blockIdx.x, z = blockIdx.y, b = blockIdx.z;
  const size_t srow0 = (size_t)(b * S_LEN + z * 128);
  const short* hrow = hbc + srow0 * CONVD;

  {
    const int n0_ = (lane & 15) * 8;
#pragma unroll
    for (int it = 0; it < 4; ++it) {
      int s = it * 32 + wid * 4 + (lane >> 4);
      gl_lds16(hrow + (size_t)s * CONVD + INTER + GN + g * NS + n0_, sC + (it * 32 + wid * 4) * 128);
      gl_lds16(hrow + (size_t)s * CONVD + INTER + g * NS + n0_, sB + (it * 32 + wid * 4) * 128);
    }
  }
  for (int i = tid; i < 1024; i += 512) sNW[i] = norm_w[g * 1024 + i];
  __syncthreads();  // drains gl_lds vmcnt; sNW visible

  const int fr = lane & 15, fk8 = (lane >> 4) * 8;
  const int er = (lane >> 4) * 4, ec = lane & 15;
  const int lrow = wid * 16;
  const int s2 = tid & 63, p0w = (tid >> 6) * 8;
  unsigned int* sx32 = (unsigned int*)sxdt;

  f32x4 sc[8] = {};
#pragma unroll
  for (int kk = 0; kk < 4; ++kk) {
    short8 a = *(const short8*)(sC + (lrow + fr) * 128 + kk * 32 + fk8);
#pragma unroll
    for (int si = 0; si < 8; ++si) {
      short8 bv = *(const short8*)(sB + (si * 16 + fr) * 128 + kk * 32 + fk8);
      sc[si] = mfma16(a, bv, sc[si]);
    }
  }

  float rssq[4] = {0.f, 0.f, 0.f, 0.f};

  for (int hh = 0; hh < 16; ++hh) {
    const int h = g * 16 + hh;
    const float* ac = acum + ((size_t)(b * NH + h)) * S_LEN + z * 128;
    const float* dts = dtT + ((size_t)(b * NH + h)) * S_LEN + z * 128;
    const short* pvb = (const short*)(states + (((size_t)(b * NC + z)) * NH + h) * (size_t)(NS * PD));
    __syncthreads();  // prior head reads done; hh=0: scores reads of sB done
    if (tid < 128) sac[tid] = ac[tid];
    {
      float dv0 = dts[2 * s2], dv1 = dts[2 * s2 + 1];
      const short* rsrc = hrow + (size_t)(2 * s2) * CONVD + (size_t)h * PD + p0w;
      short8 r0 = *(const short8*)(rsrc);
      short8 r1 = *(const short8*)(rsrc + CONVD);
#pragma unroll
      for (int j = 0; j < 8; ++j) {
        unsigned int lo = (unsigned short)f2bf(bf2f(r0[j]) * dv0);
        unsigned int hi = (unsigned short)f2bf(bf2f(r1[j]) * dv1);
        sx32[(p0w + j) * 64 + s2] = lo | (hi << 16);
      }
    }
    // stage prev (bf16 [p][n], 8192 shorts) via gl_lds: wave w rows p=w*8..w*8+7
    gl_lds16(pvb + wid * 1024 + lane * 8, sprev + wid * 1024);
    gl_lds16(pvb + wid * 1024 + 512 + lane * 8, sprev + wid * 1024 + 512);
    __syncthreads();  // drains lgkm + vmcnt

    {
      float acS[8];
#pragma unroll
      for (int si = 0; si < 8; ++si) acS[si] = sac[si * 16 + ec];
#pragma unroll
      for (int j = 0; j < 4; ++j) {
        int lloc = er + j;
        float acl = sac[lrow + lloc];
#pragma unroll
        for (int si = 0; si < 8; ++si) {
          int s = si * 16 + ec;
          float v = (s <= lrow + lloc) ? sc[si][j] * __expf(acl - acS[si]) : 0.f;
          sPw[lloc * 136 + s] = f2bf(v);
        }
      }
    }
    f32x4 yd[4] = {}, yo[4] = {};
#pragma unroll
    for (int kk = 0; kk < 4; ++kk) {
      short8 ap = *(const short8*)(sPw + fr * 136 + kk * 32 + fk8);
      short8 acf = *(const short8*)(sC + (lrow + fr) * 128 + kk * 32 + fk8);
#pragma unroll
      for (int ni = 0; ni < 4; ++ni) {
        short8 bv = *(const short8*)(sxdt + (ni * 16 + fr) * 128 + kk * 32 + fk8);
        yd[ni] = mfma16(ap, bv, yd[ni]);
        short8 bp = *(const short8*)(sprev + (ni * 16 + fr) * 128 + kk * 32 + fk8);
        yo[ni] = mfma16(acf, bp, yo[ni]);
      }
    }
    const float Dh = Dv[h];
#pragma unroll
    for (int j = 0; j < 4; ++j) {
      int l = lrow + er + j;
      float e_ac = __expf(sac[l]);
#pragma unroll
      for (int ni = 0; ni < 4; ++ni) {
        int p = ni * 16 + ec;
        float hs = bf2f(hrow[(size_t)l * CONVD + (size_t)h * PD + p]);
        float y = yd[ni][j] + yo[ni][j] * e_ac + hs * Dh;
        float gate = bf2f(projb[(srow0 + l) * (size_t)PROJP + (size_t)h * PD + p]);
        float gg = y * gate * sigmoidf_(gate);
        normed[(srow0 + l) * (size_t)INTER + (size_t)h * PD + p] = f2bf(gg);
        rssq[j] += gg * gg;
      }
    }
  }

#pragma unroll
  for (int j = 0; j < 4; ++j) {
#pragma unroll
    for (int m = 1; m <= 8; m <<= 1) rssq[j] += __shfl_xor(rssq[j], m, 64);
  }
  if (ec == 0) {
#pragma unroll
    for (int j = 0; j < 4; ++j) sScale[lrow + er + j] = rsqrtf(rssq[j] * (1.f / 1024.f) + 1e-5f);
  }
  __syncthreads();  // drains vmcnt -> all gg writes visible in L2 (same XCD)

  // in-place rescale of the block's 128x1024 bf16 slab
  for (int e = tid * 8; e < 128 * 1024; e += 4096) {
    int row = e >> 10, ch = e & 1023;
    short* gp = normed + (srow0 + row) * (size_t)INTER + g * 1024 + ch;
    short8 gv = *(const short8*)(gp);
    float scl = sScale[row];
    short8 o;
#pragma unroll
    for (int q = 0; q < 8; ++q) o[q] = f2bf(bf2f(gv[q]) * scl * sNW[ch + q]);
    *(short8*)(gp) = o;
  }
}

// ----------------------------------------------------------------
extern "C" void kernel_launch(void* const* d_in, const int* in_sizes, int n_in,
                              void* d_out, int out_size, void* d_ws, size_t ws_size,
                              hipStream_t stream) {
  const float* x     = (const float*)d_in[0];
  const float* w1    = (const float*)d_in[1];
  const float* convw = (const float*)d_in[2];
  const float* convb = (const float*)d_in[3];
  const float* dtb   = (const float*)d_in[4];
  const float* alog  = (const float*)d_in[5];
  const float* Dv    = (const float*)d_in[6];
  const float* nw    = (const float*)d_in[7];
  const float* w2    = (const float*)d_in[8];
  float* out = (float*)d_out;

  char* ws = (char*)d_ws;
  size_t off = 0;
  float* dtT = (float*)(ws + off);  off += (size_t)BB * NH * S_LEN * 4;
  float* acum = (float*)(ws + off); off += (size_t)BB * NH * S_LEN * 4;
  short* xb = (short*)(ws + off);   off += (size_t)BS * HID_DIM * 2;
  char* w1region = ws + off;        off += (size_t)PROJP * HID_DIM * 2;
  short* w1b = (short*)w1region;
  short* normed = (short*)w1region;                              // reuse after gemm1
  short* w2b = (short*)(w1region + (size_t)BS * INTER * 2);      // reuse after gemm1
  short* projb = (short*)(ws + off); off += (size_t)BS * PROJP * 2;
  short* hbc = (short*)(ws + off);   off += (size_t)BS * CONVD * 2;
  float* states = (float*)(ws + off); off += (size_t)BB * NC * NH * NS * PD * 4;

  const size_t nx = (size_t)BS * HID_DIM;
  const size_t nw1 = (size_t)PROJ * HID_DIM;
  const size_t nw2 = (size_t)HID_DIM * INTER;

  cvt_f32_bf16_k<<<dim3(nx / 2048), 256, 0, stream>>>(x, xb, nx);
  cvt_f32_bf16_k<<<dim3(nw1 / 2048), 256, 0, stream>>>(w1, w1b, nw1);

  // gemm1: [4096 x 18560(pad 18688)] = xb[4096x4096] * w1b^T ; 16 x 73 tiles
  gemm256_k<1><<<dim3(16 * 73), 512, 0, stream>>>(xb, w1b, projb, PROJP, HID_DIM, 73);

  // w1b dead now; stage w2 into its region
  cvt_f32_bf16_k<<<dim3(nw2 / 2048), 256, 0, stream>>>(w2, w2b, nw2);

  conv_silu_k<<<dim3(CONVD / 256, S_LEN / 256, BB), 256, 0, stream>>>(projb, convw, convb, hbc);
  acum_k<<<dim3(NC, NH, BB), 128, 0, stream>>>(projb, dtb, alog, dtT, acum);

  states_k<<<dim3(NG, NC, BB), 512, 0, stream>>>(hbc, dtT, acum, states);
  scan_k<<<dim3(NH, BB), 256, 0, stream>>>(states, acum);
  yfull_k<<<dim3(NG, NC, BB), 512, 0, stream>>>(hbc, projb, dtT, acum, states, Dv, nw, normed);

  // gemm2: [4096 x 4096] = normed[4096x8192] * w2b^T ; 16 x 16 tiles
  gemm256_k<0><<<dim3(16 * 16), 512, 0, stream>>>(normed, w2b, out, HID_DIM, INTER, 16);
}

// Round 9
// 1182.839 us; speedup vs baseline: 1.7690x; 1.0566x over previous
//
#include <hip/hip_runtime.h>
#include <hip/hip_bf16.h>
#include <cstdint>
#include <cstddef>

#define DEVI __device__ __forceinline__

#define BB 2
#define S_LEN 2048
#define HID_DIM 4096
#define NH 128
#define PD 64
#define NS 128
#define NG 8
#define INTER 8192
#define CONVD 10240
#define PROJ 18560
#define PROJP 18688   // padded to 73*256 for 256-wide GEMM tiles
#define NC 16
#define BS 4096
#define GN 1024   // NG*NS

using short8 = __attribute__((ext_vector_type(8))) short;
using short4v = __attribute__((ext_vector_type(4))) short;
using f32x4  = __attribute__((ext_vector_type(4))) float;
using bf16x8 = __attribute__((ext_vector_type(8))) __bf16;

DEVI float bf2f(short u) {
  union { unsigned int i; float f; } v;
  v.i = ((unsigned int)(unsigned short)u) << 16;
  return v.f;
}
DEVI short f2bf(float f) {
  union { float ff; unsigned int i; } v; v.ff = f;
  unsigned int x = v.i;
  return (short)((x + 0x7fffu + ((x >> 16) & 1u)) >> 16);
}
DEVI f32x4 mfma16(short8 a, short8 b, f32x4 c) {
  return __builtin_amdgcn_mfma_f32_16x16x32_bf16(
      __builtin_bit_cast(bf16x8, a), __builtin_bit_cast(bf16x8, b), c, 0, 0, 0);
}
DEVI void gl_lds16(const short* g, short* l) {
  __builtin_amdgcn_global_load_lds(
      (const __attribute__((address_space(1))) void*)g,
      (__attribute__((address_space(3))) void*)l, 16, 0, 0);
}
DEVI float sigmoidf_(float x) { return 1.f / (1.f + __expf(-x)); }

// ---------------------------------------------------------------- converts
__global__ __launch_bounds__(256) void cvt_f32_bf16_k(const float* __restrict__ in,
                                                      short* __restrict__ out, size_t n) {
  size_t i = ((size_t)blockIdx.x * 256 + threadIdx.x) * 8;
  if (i + 8 > n) return;
  float4 a = *(const float4*)(in + i);
  float4 b = *(const float4*)(in + i + 4);
  short8 o;
  o[0] = f2bf(a.x); o[1] = f2bf(a.y); o[2] = f2bf(a.z); o[3] = f2bf(a.w);
  o[4] = f2bf(b.x); o[5] = f2bf(b.y); o[6] = f2bf(b.z); o[7] = f2bf(b.w);
  *(short8*)(out + i) = o;
}

// ---------------------------------------------------------------- 256x256 8-phase GEMM (validated r8)
#define STG(ISB, BUF, KH, TILE) do { \
  const short* _src = (ISB) ? Bt : A; \
  const int _r0 = (ISB) ? n0 : m0; \
  short* _lb = lds_ + ((ISB) ? 32768 : 0) + ((BUF)*2+(KH))*8192; \
  const int _kt = (TILE)*64 + (KH)*32; \
  { int _row = (wid*2)*16 + srow; int _sl = sps ^ ((_row>>1)&3); \
    gl_lds16(_src + (size_t)(_r0+_row)*K + _kt + _sl*8, _lb + (wid*2)*512); } \
  { int _row = (wid*2+1)*16 + srow; int _sl = sps ^ ((_row>>1)&3); \
    gl_lds16(_src + (size_t)(_r0+_row)*K + _kt + _sl*8, _lb + (wid*2+1)*512); } \
} while(0)

#define NOPS ((void)0)
#define VM6 asm volatile("s_waitcnt vmcnt(6)" ::: "memory")
#define VM0 asm volatile("s_waitcnt vmcnt(0)" ::: "memory")

#define LDAF(DST, BUF, KH, MIH) do { \
  _Pragma("unroll") \
  for (int _m = 0; _m < 4; ++_m) { \
    int _row = wr*128 + ((MIH)*4+_m)*16 + fr; \
    DST[_m] = *(const short8*)(lds_ + ((BUF)*2+(KH))*8192 + _row*32 + ((slot ^ ((_row>>1)&3))<<3)); \
  } \
} while(0)

#define LDBF(DST, BUF, KH) do { \
  _Pragma("unroll") \
  for (int _n = 0; _n < 4; ++_n) { \
    int _row = wc*64 + _n*16 + fr; \
    DST[_n] = *(const short8*)(lds_ + 32768 + ((BUF)*2+(KH))*8192 + _row*32 + ((slot ^ ((_row>>1)&3))<<3)); \
  } \
} while(0)

#define PH2(CAF, CBF, MIH, PFEN, PFAF, PFBF, PFB, PFKH, PFMIH, PFDOB, STGS, VMW) do { \
  STGS; VMW; \
  __builtin_amdgcn_s_barrier(); \
  if (PFEN) { LDAF(PFAF, PFB, PFKH, PFMIH); if (PFDOB) LDBF(PFBF, PFB, PFKH); } \
  __builtin_amdgcn_s_setprio(1); \
  _Pragma("unroll") \
  for (int _m = 0; _m < 4; ++_m) \
    _Pragma("unroll") \
    for (int _n = 0; _n < 4; ++_n) \
      acc[(MIH)*4+_m][_n] = mfma16(CAF[_m], CBF[_n], acc[(MIH)*4+_m][_n]); \
  __builtin_amdgcn_s_setprio(0); \
  asm volatile("s_waitcnt lgkmcnt(0)" ::: "memory"); \
  __builtin_amdgcn_sched_barrier(0); \
  __builtin_amdgcn_s_barrier(); \
} while(0)

template<int CB16>
__global__ __launch_bounds__(512, 2) void gemm256_k(const short* __restrict__ A,
                                                    const short* __restrict__ Bt,
                                                    void* __restrict__ Cout,
                                                    int Nstride, int K, int ntn) {
  __shared__ short lds_[65536];  // 128 KiB
  const int tid = threadIdx.x, wid = tid >> 6, lane = tid & 63;
  const int nwg = gridDim.x, orig = blockIdx.x;
  const int swz = (orig & 7) * (nwg >> 3) + (orig >> 3);
  const int per_group = ntn << 3;
  const int group = swz / per_group;
  const int rem = swz - group * per_group;
  const int m0 = (group * 8 + (rem & 7)) * 256;
  const int n0 = (rem >> 3) * 256;
  const int wr = wid >> 2, wc = wid & 3;
  const int fr = lane & 15, slot = lane >> 4;
  const int srow = lane >> 2, sps = lane & 3;

  f32x4 acc[8][4] = {};
  short8 af_a[4], af_b[4], bf_a[4], bf_b[4];
  const int NT = K >> 6;

  STG(1, 0, 0, 0); STG(0, 0, 0, 0); STG(1, 0, 1, 0); STG(0, 0, 1, 0);
  asm volatile("s_waitcnt vmcnt(4)" ::: "memory");
  STG(1, 1, 0, 1); STG(0, 1, 0, 1); STG(1, 1, 1, 1);
  asm volatile("s_waitcnt vmcnt(6)" ::: "memory");
  __builtin_amdgcn_s_barrier();
  LDAF(af_a, 0, 0, 0); LDBF(bf_a, 0, 0);
  asm volatile("s_waitcnt lgkmcnt(0)" ::: "memory");
  __builtin_amdgcn_sched_barrier(0);

  for (int i = 0; i < (NT >> 1) - 1; ++i) {
    const int t = 2 * i;
    PH2(af_a, bf_a, 0, 1, af_b, bf_a, 0, 0, 1, 0, STG(0, 1, 1, t + 1), NOPS);
    PH2(af_b, bf_a, 1, 1, af_a, bf_b, 0, 1, 0, 1, STG(1, 0, 0, t + 2), NOPS);
    PH2(af_a, bf_b, 0, 1, af_b, bf_a, 0, 1, 1, 0, STG(0, 0, 0, t + 2), NOPS);
    PH2(af_b, bf_b, 1, 1, af_a, bf_a, 1, 0, 0, 1, STG(1, 0, 1, t + 2), VM6);
    PH2(af_a, bf_a, 0, 1, af_b, bf_b, 1, 0, 1, 0, STG(0, 0, 1, t + 2), NOPS);
    PH2(af_b, bf_a, 1, 1, af_a, bf_b, 1, 1, 0, 1, STG(1, 1, 0, t + 3), NOPS);
    PH2(af_a, bf_b, 0, 1, af_b, bf_a, 1, 1, 1, 0, STG(0, 1, 0, t + 3), NOPS);
    PH2(af_b, bf_b, 1, 1, af_a, bf_a, 0, 0, 0, 1, STG(1, 1, 1, t + 3), VM6);
  }
  PH2(af_a, bf_a, 0, 1, af_b, bf_a, 0, 0, 1, 0, STG(0, 1, 1, NT - 1), NOPS);
  PH2(af_b, bf_a, 1, 1, af_a, bf_b, 0, 1, 0, 1, NOPS, NOPS);
  PH2(af_a, bf_b, 0, 1, af_b, bf_a, 0, 1, 1, 0, NOPS, NOPS);
  PH2(af_b, bf_b, 1, 1, af_a, bf_a, 1, 0, 0, 1, NOPS, VM0);
  PH2(af_a, bf_a, 0, 1, af_b, bf_b, 1, 0, 1, 0, NOPS, NOPS);
  PH2(af_b, bf_a, 1, 1, af_a, bf_b, 1, 1, 0, 1, NOPS, NOPS);
  PH2(af_a, bf_b, 0, 1, af_b, bf_a, 1, 1, 1, 0, NOPS, NOPS);
  PH2(af_b, bf_b, 1, 0, af_a, bf_a, 0, 0, 0, 0, NOPS, NOPS);

  const int er = (lane >> 4) * 4, ec = lane & 15;
  if (CB16) {
    short* C = (short*)Cout;
#pragma unroll
    for (int mi = 0; mi < 8; ++mi)
#pragma unroll
      for (int j = 0; j < 4; ++j) {
        size_t base = (size_t)(m0 + wr * 128 + mi * 16 + er + j) * Nstride + n0 + wc * 64 + ec;
#pragma unroll
        for (int ni = 0; ni < 4; ++ni) C[base + ni * 16] = f2bf(acc[mi][ni][j]);
      }
  } else {
    float* C = (float*)Cout;
#pragma unroll
    for (int mi = 0; mi < 8; ++mi)
#pragma unroll
      for (int j = 0; j < 4; ++j) {
        size_t base = (size_t)(m0 + wr * 128 + mi * 16 + er + j) * Nstride + n0 + wc * 64 + ec;
#pragma unroll
        for (int ni = 0; ni < 4; ++ni) C[base + ni * 16] = acc[mi][ni][j];
      }
  }
}

// ---------------------------------------------------------------- conv + silu (sliding window, read-once)
__global__ __launch_bounds__(256) void conv_silu_k(const short* __restrict__ projb,
                                                   const float* __restrict__ convw,
                                                   const float* __restrict__ convb,
                                                   short* __restrict__ hbc) {
  const int c = blockIdx.x * 256 + threadIdx.x;
  const int s0 = blockIdx.y * 256;
  const int b = blockIdx.z;
  const size_t rb = (size_t)b * S_LEN;
  const float* wp = convw + (size_t)c * 4;
  const float w0 = wp[0], w1 = wp[1], w2 = wp[2], w3 = wp[3];
  const float bias = convb[c];
  const short* pcol = projb + INTER + c;
  float x1 = 0.f, x2 = 0.f, x3 = 0.f;
  if (s0 > 0) {
    x3 = bf2f(pcol[(rb + s0 - 3) * PROJP]);
    x2 = bf2f(pcol[(rb + s0 - 2) * PROJP]);
    x1 = bf2f(pcol[(rb + s0 - 1) * PROJP]);
  }
  for (int s = s0; s < s0 + 256; ++s) {
    float v = bf2f(pcol[(rb + s) * PROJP]);
    float acc = bias + w0 * x3 + w1 * x2 + w2 * x1 + w3 * v;
    float o = acc * sigmoidf_(acc);
    hbc[(rb + s) * CONVD + c] = f2bf(o);
    x3 = x2; x2 = x1; x1 = v;
  }
}

// ---------------------------------------------------------------- dt softplus + per-chunk cumsum (fused)
__global__ __launch_bounds__(128) void acum_k(const short* __restrict__ projb,
                                              const float* __restrict__ dt_bias,
                                              const float* __restrict__ A_log,
                                              float* __restrict__ dtT,
                                              float* __restrict__ acum) {
  const int l = threadIdx.x;
  const int z = blockIdx.x, h = blockIdx.y, b = blockIdx.z;
  const float A = -__expf(A_log[h]);
  __shared__ float sv[128];
  const int r = b * S_LEN + z * 128 + l;
  float xv = bf2f(projb[(size_t)r * PROJP + INTER + CONVD + h]) + dt_bias[h];
  float sp = (xv > 20.f) ? xv : log1pf(__expf(xv));
  sp = fminf(fmaxf(sp, 0.f), 100.f);
  const size_t base = ((size_t)(b * NH + h)) * S_LEN + z * 128;
  dtT[base + l] = sp;
  sv[l] = sp * A;
  __syncthreads();
  for (int off = 1; off < 128; off <<= 1) {
    float t = (l >= off) ? sv[l - off] : 0.f;
    __syncthreads();
    sv[l] += t;
    __syncthreads();
  }
  acum[base + l] = sv[l];
}

// ---------------------------------------------------------------- states per (b,z,g)
// padded LDS (stride 136 -> conflict-free fragment reads), double-buffered sxdt,
// reg-prefetch of head h+1 during head h's MFMA; ONE barrier per head.
__global__ __launch_bounds__(512) void states_k(const short* __restrict__ hbc,
                                                const float* __restrict__ dtT,
                                                const float* __restrict__ acum,
                                                float* __restrict__ states) {
  __shared__ short sBT[128 * 136];       // [n][l]
  __shared__ short sxdt2[2][64 * 136];   // [p][s] decayed, double buffer
  const int tid = threadIdx.x, wid = tid >> 6, lane = tid & 63;
  const int g = blockIdx.x, z = blockIdx.y, b = blockIdx.z;
  const size_t srow0 = (size_t)(b * S_LEN + z * 128);
  const short* hrow = hbc + srow0 * CONVD;

  {  // sBT build
    const int l = tid & 127, n0b = (tid >> 7) * 32;
    const short* src = hrow + (size_t)l * CONVD + INTER + g * NS + n0b;
    short8 v0 = *(const short8*)(src);
    short8 v1 = *(const short8*)(src + 8);
    short8 v2 = *(const short8*)(src + 16);
    short8 v3 = *(const short8*)(src + 24);
#pragma unroll
    for (int j = 0; j < 8; ++j) {
      sBT[(n0b + j) * 136 + l] = v0[j];
      sBT[(n0b + 8 + j) * 136 + l] = v1[j];
      sBT[(n0b + 16 + j) * 136 + l] = v2[j];
      sBT[(n0b + 24 + j) * 136 + l] = v3[j];
    }
  }

  const int fr = lane & 15, fk8 = (lane >> 4) * 8;
  const int er = (lane >> 4) * 4, ec = lane & 15;
  const int pband = (wid & 3) * 16, nhalf = (wid >> 2) * 64;
  const int s2 = tid & 63, p0w = (tid >> 6) * 8;

  float cdv0, cdv1; short8 cr0, cr1;
  {  // head 0 load
    const int h = g * 16;
    const float* acg = acum + ((size_t)(b * NH + h)) * S_LEN + z * 128;
    const float* dts = dtT + ((size_t)(b * NH + h)) * S_LEN + z * 128;
    const float acL = acg[127];
    cdv0 = dts[2 * s2] * __expf(acL - acg[2 * s2]);
    cdv1 = dts[2 * s2 + 1] * __expf(acL - acg[2 * s2 + 1]);
    const short* rsrc = hrow + (size_t)(2 * s2) * CONVD + (size_t)h * PD + p0w;
    cr0 = *(const short8*)(rsrc);
    cr1 = *(const short8*)(rsrc + CONVD);
  }
  {
    unsigned int* x32 = (unsigned int*)sxdt2[0];
#pragma unroll
    for (int j = 0; j < 8; ++j) {
      unsigned int lo = (unsigned short)f2bf(bf2f(cr0[j]) * cdv0);
      unsigned int hi = (unsigned short)f2bf(bf2f(cr1[j]) * cdv1);
      x32[(p0w + j) * 68 + s2] = lo | (hi << 16);
    }
  }
  __syncthreads();

  for (int hh = 0; hh < 16; ++hh) {
    const int h = g * 16 + hh;
    float ndv0 = 0.f, ndv1 = 0.f; short8 nr0, nr1;
    if (hh < 15) {  // prefetch next head (latency hides under MFMA)
      const int h2 = h + 1;
      const float* acg = acum + ((size_t)(b * NH + h2)) * S_LEN + z * 128;
      const float* dts = dtT + ((size_t)(b * NH + h2)) * S_LEN + z * 128;
      const float acL = acg[127];
      ndv0 = dts[2 * s2] * __expf(acL - acg[2 * s2]);
      ndv1 = dts[2 * s2 + 1] * __expf(acL - acg[2 * s2 + 1]);
      const short* rsrc = hrow + (size_t)(2 * s2) * CONVD + (size_t)h2 * PD + p0w;
      nr0 = *(const short8*)(rsrc);
      nr1 = *(const short8*)(rsrc + CONVD);
    }
    const short* sx = sxdt2[hh & 1];
    f32x4 st[4] = {};
#pragma unroll
    for (int kk = 0; kk < 4; ++kk) {
      short8 a = *(const short8*)(sx + (pband + fr) * 136 + kk * 32 + fk8);
#pragma unroll
      for (int ni = 0; ni < 4; ++ni) {
        short8 bb = *(const short8*)(sBT + (nhalf + ni * 16 + fr) * 136 + kk * 32 + fk8);
        st[ni] = mfma16(a, bb, st[ni]);
      }
    }
    float* stp = states + (((size_t)(b * NC + z)) * NH + h) * (size_t)(NS * PD);
#pragma unroll
    for (int ni = 0; ni < 4; ++ni)
#pragma unroll
      for (int j = 0; j < 4; ++j)
        stp[(pband + er + j) * NS + nhalf + ni * 16 + ec] = st[ni][j];
    if (hh < 15) {
      unsigned int* x32 = (unsigned int*)sxdt2[(hh + 1) & 1];
#pragma unroll
      for (int j = 0; j < 8; ++j) {
        unsigned int lo = (unsigned short)f2bf(bf2f(nr0[j]) * ndv0);
        unsigned int hi = (unsigned short)f2bf(bf2f(nr1[j]) * ndv1);
        x32[(p0w + j) * 68 + s2] = lo | (hi << 16);
      }
    }
    __syncthreads();
  }
}

// ---------------------------------------------------------------- inter-chunk scan
__global__ __launch_bounds__(256) void scan_k(float* __restrict__ states,
                                              const float* __restrict__ acum) {
  const int h = blockIdx.x, b = blockIdx.y;
  const int tid = threadIdx.x;
  float* stp = states + ((size_t)(b * NC * NH) + h) * (size_t)(NS * PD);
  const size_t cst = (size_t)NH * NS * PD;
  const float* ac = acum + ((size_t)(b * NH + h)) * S_LEN;
  float E[32];
#pragma unroll
  for (int i = 0; i < 32; ++i) E[i] = 0.f;
  const int n = tid & 127, pg = tid >> 7;
  for (int zz = 0; zz < NC; ++zz) {
    float* sz = stp + (size_t)zz * cst;
    short* pvb = (short*)sz;
    float tmp[32];
#pragma unroll
    for (int i = 0; i < 32; ++i) tmp[i] = sz[i * 256 + tid];
    __syncthreads();
    float dec = __expf(ac[zz * 128 + 127]);
#pragma unroll
    for (int i = 0; i < 32; ++i) {
      int p = i * 2 + pg;
      pvb[p * 128 + n] = f2bf(E[i]);   // prev entering chunk zz, bf16 [p][n]
      E[i] = dec * E[i] + tmp[i];
    }
    __syncthreads();
  }
}

// ---------------------------------------------------------------- fused Y + gate + group-RMS-norm per (b,z,g)
// XOR-swizzled sC/sB (gl_lds pre-swizzled source, swizzled reads; slot ^= row&7);
// reg-staged double-buffered sxdt/sprev (buf1 overlays sB after scores);
// ac/dts in registers; ONE barrier per head.
#define RDSW(BUF, ROWBASE, KK) \
  (*(const short8*)((BUF) + ((ROWBASE) + fr) * 128 + ((((KK) * 4 + slot4) ^ sw7) << 3)))

#define WRX(DST, D0, D1, R0, R1) do { \
  unsigned int* _x = (unsigned int*)(DST); \
  _Pragma("unroll") \
  for (int _j = 0; _j < 8; ++_j) { \
    unsigned int _lo = (unsigned short)f2bf(bf2f(R0[_j]) * (D0)); \
    unsigned int _hi = (unsigned short)f2bf(bf2f(R1[_j]) * (D1)); \
    _x[(p0w + _j) * 64 + ((((s2 >> 2) ^ _j) << 2) | (s2 & 3))] = _lo | (_hi << 16); \
  } \
} while (0)

#define WRP(DST, P0, P1) do { \
  int _p = tid >> 3; int _s0 = (tid & 7) * 2; int _m = _p & 7; \
  *(short8*)((DST) + _p * 128 + ((_s0 ^ _m) << 3)) = P0; \
  *(short8*)((DST) + _p * 128 + (((_s0 + 1) ^ _m) << 3)) = P1; \
} while (0)

#define LOADH_Y(H, DT0, DT1, ACS, ACL, R0, R1, P0, P1) do { \
  const float* _ac = acum + ((size_t)(b * NH + (H))) * S_LEN + z * 128; \
  const float* _dts = dtT + ((size_t)(b * NH + (H))) * S_LEN + z * 128; \
  DT0 = _dts[2 * s2]; DT1 = _dts[2 * s2 + 1]; \
  _Pragma("unroll") \
  for (int _si = 0; _si < 8; ++_si) ACS[_si] = _ac[_si * 16 + ec]; \
  _Pragma("unroll") \
  for (int _j = 0; _j < 4; ++_j) ACL[_j] = _ac[lrow + er + _j]; \
  const short* _rs = hrow + (size_t)(2 * s2) * CONVD + (size_t)(H) * PD + p0w; \
  R0 = *(const short8*)(_rs); R1 = *(const short8*)(_rs + CONVD); \
  const short* _pv = (const short*)(states + (((size_t)(b * NC + z)) * NH + (H)) * (size_t)(NS * PD)); \
  P0 = *(const short8*)(_pv + tid * 16); P1 = *(const short8*)(_pv + tid * 16 + 8); \
} while (0)

__global__ __launch_bounds__(512) void yfull_k(const short* __restrict__ hbc,
                                               const short* __restrict__ projb,
                                               const float* __restrict__ dtT,
                                               const float* __restrict__ acum,
                                               const float* __restrict__ states,
                                               const float* __restrict__ Dv,
                                               const float* __restrict__ norm_w,
                                               short* __restrict__ normed) {
  __shared__ short lds[66560];  // sC 16384 | sB 16384 (->sx1+sp1) | sx0 8192 | sp0 8192 | sP 8*2176
  __shared__ float sScale[128];
  __shared__ float sNW[1024];
  short* sC = lds;
  short* sB = lds + 16384;
  short* sx0 = lds + 32768;
  short* sp0 = lds + 40960;
  const int tid = threadIdx.x, wid = tid >> 6, lane = tid & 63;
  short* sPw = lds + 49152 + wid * 2176;
  const int g = blockIdx.x, z = blockIdx.y, b = blockIdx.z;
  const size_t srow0 = (size_t)(b * S_LEN + z * 128);
  const short* hrow = hbc + srow0 * CONVD;

  {  // gl_lds staging with pre-swizzled source (slot_g = slot ^ (row&7))
    const int slot_g = (lane & 15) ^ (((wid & 1) << 2) | (lane >> 4));
    const int n0_ = slot_g * 8;
#pragma unroll
    for (int it = 0; it < 4; ++it) {
      int s = it * 32 + wid * 4 + (lane >> 4);
      gl_lds16(hrow + (size_t)s * CONVD + INTER + GN + g * NS + n0_, sC + (it * 32 + wid * 4) * 128);
      gl_lds16(hrow + (size_t)s * CONVD + INTER + g * NS + n0_, sB + (it * 32 + wid * 4) * 128);
    }
  }
  for (int i = tid; i < 1024; i += 512) sNW[i] = norm_w[g * 1024 + i];
  __syncthreads();  // sC/sB staged

  const int fr = lane & 15, fk8 = (lane >> 4) * 8;
  const int slot4 = lane >> 4, sw7 = lane & 7;
  const int er = (lane >> 4) * 4, ec = lane & 15;
  const int lrow = wid * 16;
  const int s2 = tid & 63, p0w = (tid >> 6) * 8;

  // prefetch head 0 (latency hides under scores)
  float cdt0, cdt1, cacS[8], cacl[4];
  short8 cr0, cr1, cp0, cp1;
  LOADH_Y(g * 16, cdt0, cdt1, cacS, cacl, cr0, cr1, cp0, cp1);

  // scores C·B^T once (fp32 regs)
  f32x4 sc[8] = {};
#pragma unroll
  for (int kk = 0; kk < 4; ++kk) {
    short8 a = RDSW(sC, lrow, kk);
#pragma unroll
    for (int si = 0; si < 8; ++si) {
      short8 bv = RDSW(sB, si * 16, kk);
      sc[si] = mfma16(a, bv, sc[si]);
    }
  }
  WRX(sx0, cdt0, cdt1, cr0, cr1);
  WRP(sp0, cp0, cp1);
  __syncthreads();  // all waves past scores (sB free) + buf0 visible

  float rssq[4] = {0.f, 0.f, 0.f, 0.f};

  for (int hh = 0; hh < 16; ++hh) {
    const int h = g * 16 + hh;
    float ndt0 = 0.f, ndt1 = 0.f, nacS[8], nacl[4];
    short8 nr0, nr1, np0, np1;
    if (hh < 15) LOADH_Y(h + 1, ndt0, ndt1, nacS, nacl, nr0, nr1, np0, np1);

    short* sx = (hh & 1) ? sB : sx0;
    short* sp = (hh & 1) ? (sB + 8192) : sp0;

    // mask raw scores -> P (bf16) in this wave's private band
#pragma unroll
    for (int j = 0; j < 4; ++j) {
      int lloc = er + j;
      float acl = cacl[j];
#pragma unroll
      for (int si = 0; si < 8; ++si) {
        int sI = si * 16 + ec;
        float v = (sI <= lrow + lloc) ? sc[si][j] * __expf(acl - cacS[si]) : 0.f;
        sPw[lloc * 136 + sI] = f2bf(v);
      }
    }
    f32x4 yd[4] = {}, yo[4] = {};
#pragma unroll
    for (int kk = 0; kk < 4; ++kk) {
      short8 ap = *(const short8*)(sPw + fr * 136 + kk * 32 + fk8);
      short8 acf = RDSW(sC, lrow, kk);
#pragma unroll
      for (int ni = 0; ni < 4; ++ni) {
        short8 bv = RDSW(sx, ni * 16, kk);
        yd[ni] = mfma16(ap, bv, yd[ni]);
        short8 bp = RDSW(sp, ni * 16, kk);
        yo[ni] = mfma16(acf, bp, yo[ni]);
      }
    }
    const float Dh = Dv[h];
#pragma unroll
    for (int j = 0; j < 4; ++j) {
      int l = lrow + er + j;
      float e_ac = __expf(cacl[j]);
#pragma unroll
      for (int ni = 0; ni < 4; ++ni) {
        int p = ni * 16 + ec;
        float hs = bf2f(hrow[(size_t)l * CONVD + (size_t)h * PD + p]);
        float y = yd[ni][j] + yo[ni][j] * e_ac + hs * Dh;
        float gate = bf2f(projb[(srow0 + l) * (size_t)PROJP + (size_t)h * PD + p]);
        float gg = y * gate * sigmoidf_(gate);
        normed[(srow0 + l) * (size_t)INTER + (size_t)h * PD + p] = f2bf(gg);
        rssq[j] += gg * gg;
      }
    }
    if (hh < 15) {
      short* nx = (hh & 1) ? sx0 : sB;
      short* npv = (hh & 1) ? sp0 : (sB + 8192);
      WRX(nx, ndt0, ndt1, nr0, nr1);
      WRP(npv, np0, np1);
      cdt0 = ndt0; cdt1 = ndt1; cr0 = nr0; cr1 = nr1; cp0 = np0; cp1 = np1;
#pragma unroll
      for (int si = 0; si < 8; ++si) cacS[si] = nacS[si];
#pragma unroll
      for (int j = 0; j < 4; ++j) cacl[j] = nacl[j];
    }
    __syncthreads();
  }

#pragma unroll
  for (int j = 0; j < 4; ++j) {
#pragma unroll
    for (int m = 1; m <= 8; m <<= 1) rssq[j] += __shfl_xor(rssq[j], m, 64);
  }
  if (ec == 0) {
#pragma unroll
    for (int j = 0; j < 4; ++j) sScale[lrow + er + j] = rsqrtf(rssq[j] * (1.f / 1024.f) + 1e-5f);
  }
  __syncthreads();  // drains vmcnt -> all gg writes visible

  // in-place rescale of the block's 128x1024 bf16 slab
  for (int e = tid * 8; e < 128 * 1024; e += 4096) {
    int row = e >> 10, ch = e & 1023;
    short* gp = normed + (srow0 + row) * (size_t)INTER + g * 1024 + ch;
    short8 gv = *(const short8*)(gp);
    float scl = sScale[row];
    short8 o;
#pragma unroll
    for (int q = 0; q < 8; ++q) o[q] = f2bf(bf2f(gv[q]) * scl * sNW[ch + q]);
    *(short8*)(gp) = o;
  }
}

// ----------------------------------------------------------------
extern "C" void kernel_launch(void* const* d_in, const int* in_sizes, int n_in,
                              void* d_out, int out_size, void* d_ws, size_t ws_size,
                              hipStream_t stream) {
  const float* x     = (const float*)d_in[0];
  const float* w1    = (const float*)d_in[1];
  const float* convw = (const float*)d_in[2];
  const float* convb = (const float*)d_in[3];
  const float* dtb   = (const float*)d_in[4];
  const float* alog  = (const float*)d_in[5];
  const float* Dv    = (const float*)d_in[6];
  const float* nw    = (const float*)d_in[7];
  const float* w2    = (const float*)d_in[8];
  float* out = (float*)d_out;

  char* ws = (char*)d_ws;
  size_t off = 0;
  float* dtT = (float*)(ws + off);  off += (size_t)BB * NH * S_LEN * 4;
  float* acum = (float*)(ws + off); off += (size_t)BB * NH * S_LEN * 4;
  short* xb = (short*)(ws + off);   off += (size_t)BS * HID_DIM * 2;
  char* w1region = ws + off;        off += (size_t)PROJP * HID_DIM * 2;
  short* w1b = (short*)w1region;
  short* normed = (short*)w1region;                              // reuse after gemm1
  short* w2b = (short*)(w1region + (size_t)BS * INTER * 2);      // reuse after gemm1
  short* projb = (short*)(ws + off); off += (size_t)BS * PROJP * 2;
  short* hbc = (short*)(ws + off);   off += (size_t)BS * CONVD * 2;
  float* states = (float*)(ws + off); off += (size_t)BB * NC * NH * NS * PD * 4;

  const size_t nx = (size_t)BS * HID_DIM;
  const size_t nw1 = (size_t)PROJ * HID_DIM;
  const size_t nw2 = (size_t)HID_DIM * INTER;

  cvt_f32_bf16_k<<<dim3(nx / 2048), 256, 0, stream>>>(x, xb, nx);
  cvt_f32_bf16_k<<<dim3(nw1 / 2048), 256, 0, stream>>>(w1, w1b, nw1);

  // gemm1: [4096 x 18560(pad 18688)] = xb[4096x4096] * w1b^T ; 16 x 73 tiles
  gemm256_k<1><<<dim3(16 * 73), 512, 0, stream>>>(xb, w1b, projb, PROJP, HID_DIM, 73);

  // w1b dead now; stage w2 into its region
  cvt_f32_bf16_k<<<dim3(nw2 / 2048), 256, 0, stream>>>(w2, w2b, nw2);

  conv_silu_k<<<dim3(CONVD / 256, S_LEN / 256, BB), 256, 0, stream>>>(projb, convw, convb, hbc);
  acum_k<<<dim3(NC, NH, BB), 128, 0, stream>>>(projb, dtb, alog, dtT, acum);

  states_k<<<dim3(NG, NC, BB), 512, 0, stream>>>(hbc, dtT, acum, states);
  scan_k<<<dim3(NH, BB), 256, 0, stream>>>(states, acum);
  yfull_k<<<dim3(NG, NC, BB), 512, 0, stream>>>(hbc, projb, dtT, acum, states, Dv, nw, normed);

  // gemm2: [4096 x 4096] = normed[4096x8192] * w2b^T ; 16 x 16 tiles
  gemm256_k<0><<<dim3(16 * 16), 512, 0, stream>>>(normed, w2b, out, HID_DIM, INTER, 16);
}

// Round 10
// 1171.929 us; speedup vs baseline: 1.7855x; 1.0093x over previous
//
#include <hip/hip_runtime.h>
#include <hip/hip_bf16.h>
#include <cstdint>
#include <cstddef>

#define DEVI __device__ __forceinline__

#define BB 2
#define S_LEN 2048
#define HID_DIM 4096
#define NH 128
#define PD 64
#define NS 128
#define NG 8
#define INTER 8192
#define CONVD 10240
#define PROJ 18560
#define PROJP 18688   // padded to 73*256 for 256-wide GEMM tiles
#define NC 16
#define BS 4096
#define GN 1024   // NG*NS

using short8 = __attribute__((ext_vector_type(8))) short;
using short4v = __attribute__((ext_vector_type(4))) short;
using f32x4  = __attribute__((ext_vector_type(4))) float;
using bf16x8 = __attribute__((ext_vector_type(8))) __bf16;

DEVI float bf2f(short u) {
  union { unsigned int i; float f; } v;
  v.i = ((unsigned int)(unsigned short)u) << 16;
  return v.f;
}
DEVI short f2bf(float f) {
  union { float ff; unsigned int i; } v; v.ff = f;
  unsigned int x = v.i;
  return (short)((x + 0x7fffu + ((x >> 16) & 1u)) >> 16);
}
DEVI f32x4 mfma16(short8 a, short8 b, f32x4 c) {
  return __builtin_amdgcn_mfma_f32_16x16x32_bf16(
      __builtin_bit_cast(bf16x8, a), __builtin_bit_cast(bf16x8, b), c, 0, 0, 0);
}
DEVI void gl_lds16(const short* g, short* l) {
  __builtin_amdgcn_global_load_lds(
      (const __attribute__((address_space(1))) void*)g,
      (__attribute__((address_space(3))) void*)l, 16, 0, 0);
}
DEVI float sigmoidf_(float x) { return 1.f / (1.f + __expf(-x)); }

// ---------------------------------------------------------------- converts
__global__ __launch_bounds__(256) void cvt_f32_bf16_k(const float* __restrict__ in,
                                                      short* __restrict__ out, size_t n) {
  size_t i = ((size_t)blockIdx.x * 256 + threadIdx.x) * 8;
  if (i + 8 > n) return;
  float4 a = *(const float4*)(in + i);
  float4 b = *(const float4*)(in + i + 4);
  short8 o;
  o[0] = f2bf(a.x); o[1] = f2bf(a.y); o[2] = f2bf(a.z); o[3] = f2bf(a.w);
  o[4] = f2bf(b.x); o[5] = f2bf(b.y); o[6] = f2bf(b.z); o[7] = f2bf(b.w);
  *(short8*)(out + i) = o;
}

// ---------------------------------------------------------------- 256x256 GEMM, merged-iter schedule
// K-tile-granular dbuf: iter computes tile t (buf cb), stages t+1 (buf nb).
// 2 barriers + 1 vmcnt per K-tile. Ledger:
//   STG(nb,kh0); VM4; bar1;  -- VM4 drains prev iter's 8 gl_lds (12 outstanding -> 4 own)
//   read cb MIH0 (A kh0+kh1, B kh0+kh1); 32 MFMA;
//   STG(nb,kh1);             -- writes nb only; reads are cb; no hazard
//   read cb MIH1 (A); 32 MFMA (B frags reused);
//   lgkm0; bar2;             -- cb reads retired before next iter's STG overwrites cb
// Final iter: VM0 at bar1, no staging.

#define STG(ISB, BUF, KH, TILE) do { \
  const short* _src = (ISB) ? Bt : A; \
  const int _r0 = (ISB) ? n0 : m0; \
  short* _lb = lds_ + ((ISB) ? 32768 : 0) + ((BUF)*2+(KH))*8192; \
  const int _kt = (TILE)*64 + (KH)*32; \
  { int _row = (wid*2)*16 + srow; int _sl = sps ^ ((_row>>1)&3); \
    gl_lds16(_src + (size_t)(_r0+_row)*K + _kt + _sl*8, _lb + (wid*2)*512); } \
  { int _row = (wid*2+1)*16 + srow; int _sl = sps ^ ((_row>>1)&3); \
    gl_lds16(_src + (size_t)(_r0+_row)*K + _kt + _sl*8, _lb + (wid*2+1)*512); } \
} while(0)

#define VM4 asm volatile("s_waitcnt vmcnt(4)" ::: "memory")
#define VM0 asm volatile("s_waitcnt vmcnt(0)" ::: "memory")

#define LDAF(DST, BUF, KH, MIH) do { \
  _Pragma("unroll") \
  for (int _m = 0; _m < 4; ++_m) { \
    int _row = wr*128 + ((MIH)*4+_m)*16 + fr; \
    DST[_m] = *(const short8*)(lds_ + ((BUF)*2+(KH))*8192 + _row*32 + ((slot ^ ((_row>>1)&3))<<3)); \
  } \
} while(0)

#define LDBF(DST, BUF, KH) do { \
  _Pragma("unroll") \
  for (int _n = 0; _n < 4; ++_n) { \
    int _row = wc*64 + _n*16 + fr; \
    DST[_n] = *(const short8*)(lds_ + 32768 + ((BUF)*2+(KH))*8192 + _row*32 + ((slot ^ ((_row>>1)&3))<<3)); \
  } \
} while(0)

#define MFMA16X(MIH, AF, BF) do { \
  _Pragma("unroll") \
  for (int _m = 0; _m < 4; ++_m) \
    _Pragma("unroll") \
    for (int _n = 0; _n < 4; ++_n) \
      acc[(MIH)*4+_m][_n] = mfma16(AF[_m], BF[_n], acc[(MIH)*4+_m][_n]); \
} while(0)

#define ITER(CB, NB, TNEXT, DOSTG, VMW) do { \
  if (DOSTG) { STG(0, NB, 0, TNEXT); STG(1, NB, 0, TNEXT); } \
  VMW; \
  __builtin_amdgcn_s_barrier(); \
  LDAF(af0, CB, 0, 0); LDAF(af1, CB, 1, 0); \
  LDBF(bf0, CB, 0); LDBF(bf1, CB, 1); \
  __builtin_amdgcn_s_setprio(1); \
  MFMA16X(0, af0, bf0); \
  MFMA16X(0, af1, bf1); \
  __builtin_amdgcn_s_setprio(0); \
  if (DOSTG) { STG(0, NB, 1, TNEXT); STG(1, NB, 1, TNEXT); } \
  LDAF(af0, CB, 0, 1); LDAF(af1, CB, 1, 1); \
  __builtin_amdgcn_s_setprio(1); \
  MFMA16X(1, af0, bf0); \
  MFMA16X(1, af1, bf1); \
  __builtin_amdgcn_s_setprio(0); \
  asm volatile("s_waitcnt lgkmcnt(0)" ::: "memory"); \
  __builtin_amdgcn_s_barrier(); \
} while(0)

template<int CB16>
__global__ __launch_bounds__(512, 2) void gemm256_k(const short* __restrict__ A,
                                                    const short* __restrict__ Bt,
                                                    void* __restrict__ Cout,
                                                    int Nstride, int K, int ntn) {
  __shared__ short lds_[65536];  // 128 KiB
  const int tid = threadIdx.x, wid = tid >> 6, lane = tid & 63;
  // XCD-bijective chunk + GM=8 m-supertile decode
  const int nwg = gridDim.x, orig = blockIdx.x;
  const int swz = (orig & 7) * (nwg >> 3) + (orig >> 3);
  const int per_group = ntn << 3;
  const int group = swz / per_group;
  const int rem = swz - group * per_group;
  const int m0 = (group * 8 + (rem & 7)) * 256;
  const int n0 = (rem >> 3) * 256;
  const int wr = wid >> 2, wc = wid & 3;
  const int fr = lane & 15, slot = lane >> 4;
  const int srow = lane >> 2, sps = lane & 3;

  f32x4 acc[8][4] = {};
  short8 af0[4], af1[4], bf0[4], bf1[4];
  const int NT = K >> 6;  // even for K=4096/8192

  // prologue: stage tile 0 into buf0 (8 gl_lds ops)
  STG(0, 0, 0, 0); STG(1, 0, 0, 0); STG(0, 0, 1, 0); STG(1, 0, 1, 0);

  for (int ii = 0; ii < (NT >> 1) - 1; ++ii) {
    const int t = 2 * ii;
    ITER(0, 1, t + 1, 1, VM4);
    ITER(1, 0, t + 2, 1, VM4);
  }
  ITER(0, 1, NT - 1, 1, VM4);
  ITER(1, 0, 0, 0, VM0);

  const int er = (lane >> 4) * 4, ec = lane & 15;
  if (CB16) {
    short* C = (short*)Cout;
#pragma unroll
    for (int mi = 0; mi < 8; ++mi)
#pragma unroll
      for (int j = 0; j < 4; ++j) {
        size_t base = (size_t)(m0 + wr * 128 + mi * 16 + er + j) * Nstride + n0 + wc * 64 + ec;
#pragma unroll
        for (int ni = 0; ni < 4; ++ni) C[base + ni * 16] = f2bf(acc[mi][ni][j]);
      }
  } else {
    float* C = (float*)Cout;
#pragma unroll
    for (int mi = 0; mi < 8; ++mi)
#pragma unroll
      for (int j = 0; j < 4; ++j) {
        size_t base = (size_t)(m0 + wr * 128 + mi * 16 + er + j) * Nstride + n0 + wc * 64 + ec;
#pragma unroll
        for (int ni = 0; ni < 4; ++ni) C[base + ni * 16] = acc[mi][ni][j];
      }
  }
}

// ---------------------------------------------------------------- conv + silu (sliding window, read-once)
__global__ __launch_bounds__(256) void conv_silu_k(const short* __restrict__ projb,
                                                   const float* __restrict__ convw,
                                                   const float* __restrict__ convb,
                                                   short* __restrict__ hbc) {
  const int c = blockIdx.x * 256 + threadIdx.x;
  const int s0 = blockIdx.y * 256;
  const int b = blockIdx.z;
  const size_t rb = (size_t)b * S_LEN;
  const float* wp = convw + (size_t)c * 4;
  const float w0 = wp[0], w1 = wp[1], w2 = wp[2], w3 = wp[3];
  const float bias = convb[c];
  const short* pcol = projb + INTER + c;
  float x1 = 0.f, x2 = 0.f, x3 = 0.f;
  if (s0 > 0) {
    x3 = bf2f(pcol[(rb + s0 - 3) * PROJP]);
    x2 = bf2f(pcol[(rb + s0 - 2) * PROJP]);
    x1 = bf2f(pcol[(rb + s0 - 1) * PROJP]);
  }
  for (int s = s0; s < s0 + 256; ++s) {
    float v = bf2f(pcol[(rb + s) * PROJP]);
    float acc = bias + w0 * x3 + w1 * x2 + w2 * x1 + w3 * v;
    float o = acc * sigmoidf_(acc);
    hbc[(rb + s) * CONVD + c] = f2bf(o);
    x3 = x2; x2 = x1; x1 = v;
  }
}

// ---------------------------------------------------------------- dt softplus + per-chunk cumsum (fused)
__global__ __launch_bounds__(128) void acum_k(const short* __restrict__ projb,
                                              const float* __restrict__ dt_bias,
                                              const float* __restrict__ A_log,
                                              float* __restrict__ dtT,
                                              float* __restrict__ acum) {
  const int l = threadIdx.x;
  const int z = blockIdx.x, h = blockIdx.y, b = blockIdx.z;
  const float A = -__expf(A_log[h]);
  __shared__ float sv[128];
  const int r = b * S_LEN + z * 128 + l;
  float xv = bf2f(projb[(size_t)r * PROJP + INTER + CONVD + h]) + dt_bias[h];
  float sp = (xv > 20.f) ? xv : log1pf(__expf(xv));
  sp = fminf(fmaxf(sp, 0.f), 100.f);
  const size_t base = ((size_t)(b * NH + h)) * S_LEN + z * 128;
  dtT[base + l] = sp;
  sv[l] = sp * A;
  __syncthreads();
  for (int off = 1; off < 128; off <<= 1) {
    float t = (l >= off) ? sv[l - off] : 0.f;
    __syncthreads();
    sv[l] += t;
    __syncthreads();
  }
  acum[base + l] = sv[l];
}

// ---------------------------------------------------------------- states per (b,z,g)
__global__ __launch_bounds__(512) void states_k(const short* __restrict__ hbc,
                                                const float* __restrict__ dtT,
                                                const float* __restrict__ acum,
                                                float* __restrict__ states) {
  __shared__ short sBT[128 * 136];       // [n][l]
  __shared__ short sxdt2[2][64 * 136];   // [p][s] decayed, double buffer
  const int tid = threadIdx.x, wid = tid >> 6, lane = tid & 63;
  const int g = blockIdx.x, z = blockIdx.y, b = blockIdx.z;
  const size_t srow0 = (size_t)(b * S_LEN + z * 128);
  const short* hrow = hbc + srow0 * CONVD;

  {  // sBT build
    const int l = tid & 127, n0b = (tid >> 7) * 32;
    const short* src = hrow + (size_t)l * CONVD + INTER + g * NS + n0b;
    short8 v0 = *(const short8*)(src);
    short8 v1 = *(const short8*)(src + 8);
    short8 v2 = *(const short8*)(src + 16);
    short8 v3 = *(const short8*)(src + 24);
#pragma unroll
    for (int j = 0; j < 8; ++j) {
      sBT[(n0b + j) * 136 + l] = v0[j];
      sBT[(n0b + 8 + j) * 136 + l] = v1[j];
      sBT[(n0b + 16 + j) * 136 + l] = v2[j];
      sBT[(n0b + 24 + j) * 136 + l] = v3[j];
    }
  }

  const int fr = lane & 15, fk8 = (lane >> 4) * 8;
  const int er = (lane >> 4) * 4, ec = lane & 15;
  const int pband = (wid & 3) * 16, nhalf = (wid >> 2) * 64;
  const int s2 = tid & 63, p0w = (tid >> 6) * 8;

  float cdv0, cdv1; short8 cr0, cr1;
  {  // head 0 load
    const int h = g * 16;
    const float* acg = acum + ((size_t)(b * NH + h)) * S_LEN + z * 128;
    const float* dts = dtT + ((size_t)(b * NH + h)) * S_LEN + z * 128;
    const float acL = acg[127];
    cdv0 = dts[2 * s2] * __expf(acL - acg[2 * s2]);
    cdv1 = dts[2 * s2 + 1] * __expf(acL - acg[2 * s2 + 1]);
    const short* rsrc = hrow + (size_t)(2 * s2) * CONVD + (size_t)h * PD + p0w;
    cr0 = *(const short8*)(rsrc);
    cr1 = *(const short8*)(rsrc + CONVD);
  }
  {
    unsigned int* x32 = (unsigned int*)sxdt2[0];
#pragma unroll
    for (int j = 0; j < 8; ++j) {
      unsigned int lo = (unsigned short)f2bf(bf2f(cr0[j]) * cdv0);
      unsigned int hi = (unsigned short)f2bf(bf2f(cr1[j]) * cdv1);
      x32[(p0w + j) * 68 + s2] = lo | (hi << 16);
    }
  }
  __syncthreads();

  for (int hh = 0; hh < 16; ++hh) {
    const int h = g * 16 + hh;
    float ndv0 = 0.f, ndv1 = 0.f; short8 nr0, nr1;
    if (hh < 15) {
      const int h2 = h + 1;
      const float* acg = acum + ((size_t)(b * NH + h2)) * S_LEN + z * 128;
      const float* dts = dtT + ((size_t)(b * NH + h2)) * S_LEN + z * 128;
      const float acL = acg[127];
      ndv0 = dts[2 * s2] * __expf(acL - acg[2 * s2]);
      ndv1 = dts[2 * s2 + 1] * __expf(acL - acg[2 * s2 + 1]);
      const short* rsrc = hrow + (size_t)(2 * s2) * CONVD + (size_t)h2 * PD + p0w;
      nr0 = *(const short8*)(rsrc);
      nr1 = *(const short8*)(rsrc + CONVD);
    }
    const short* sx = sxdt2[hh & 1];
    f32x4 st[4] = {};
#pragma unroll
    for (int kk = 0; kk < 4; ++kk) {
      short8 a = *(const short8*)(sx + (pband + fr) * 136 + kk * 32 + fk8);
#pragma unroll
      for (int ni = 0; ni < 4; ++ni) {
        short8 bb = *(const short8*)(sBT + (nhalf + ni * 16 + fr) * 136 + kk * 32 + fk8);
        st[ni] = mfma16(a, bb, st[ni]);
      }
    }
    float* stp = states + (((size_t)(b * NC + z)) * NH + h) * (size_t)(NS * PD);
#pragma unroll
    for (int ni = 0; ni < 4; ++ni)
#pragma unroll
      for (int j = 0; j < 4; ++j)
        stp[(pband + er + j) * NS + nhalf + ni * 16 + ec] = st[ni][j];
    if (hh < 15) {
      unsigned int* x32 = (unsigned int*)sxdt2[(hh + 1) & 1];
#pragma unroll
      for (int j = 0; j < 8; ++j) {
        unsigned int lo = (unsigned short)f2bf(bf2f(nr0[j]) * ndv0);
        unsigned int hi = (unsigned short)f2bf(bf2f(nr1[j]) * ndv1);
        x32[(p0w + j) * 68 + s2] = lo | (hi << 16);
      }
    }
    __syncthreads();
  }
}

// ---------------------------------------------------------------- inter-chunk scan
__global__ __launch_bounds__(256) void scan_k(float* __restrict__ states,
                                              const float* __restrict__ acum) {
  const int h = blockIdx.x, b = blockIdx.y;
  const int tid = threadIdx.x;
  float* stp = states + ((size_t)(b * NC * NH) + h) * (size_t)(NS * PD);
  const size_t cst = (size_t)NH * NS * PD;
  const float* ac = acum + ((size_t)(b * NH + h)) * S_LEN;
  float E[32];
#pragma unroll
  for (int i = 0; i < 32; ++i) E[i] = 0.f;
  const int n = tid & 127, pg = tid >> 7;
  for (int zz = 0; zz < NC; ++zz) {
    float* sz = stp + (size_t)zz * cst;
    short* pvb = (short*)sz;
    float tmp[32];
#pragma unroll
    for (int i = 0; i < 32; ++i) tmp[i] = sz[i * 256 + tid];
    __syncthreads();
    float dec = __expf(ac[zz * 128 + 127]);
#pragma unroll
    for (int i = 0; i < 32; ++i) {
      int p = i * 2 + pg;
      pvb[p * 128 + n] = f2bf(E[i]);   // prev entering chunk zz, bf16 [p][n]
      E[i] = dec * E[i] + tmp[i];
    }
    __syncthreads();
  }
}

// ---------------------------------------------------------------- fused Y + gate + group-RMS-norm per (b,z,g)
#define RDSW(BUF, ROWBASE, KK) \
  (*(const short8*)((BUF) + ((ROWBASE) + fr) * 128 + ((((KK) * 4 + slot4) ^ sw7) << 3)))

#define WRX(DST, D0, D1, R0, R1) do { \
  unsigned int* _x = (unsigned int*)(DST); \
  _Pragma("unroll") \
  for (int _j = 0; _j < 8; ++_j) { \
    unsigned int _lo = (unsigned short)f2bf(bf2f(R0[_j]) * (D0)); \
    unsigned int _hi = (unsigned short)f2bf(bf2f(R1[_j]) * (D1)); \
    _x[(p0w + _j) * 64 + ((((s2 >> 2) ^ _j) << 2) | (s2 & 3))] = _lo | (_hi << 16); \
  } \
} while (0)

#define WRP(DST, P0, P1) do { \
  int _p = tid >> 3; int _s0 = (tid & 7) * 2; int _m = _p & 7; \
  *(short8*)((DST) + _p * 128 + ((_s0 ^ _m) << 3)) = P0; \
  *(short8*)((DST) + _p * 128 + (((_s0 + 1) ^ _m) << 3)) = P1; \
} while (0)

#define LOADH_Y(H, DT0, DT1, ACS, ACL, R0, R1, P0, P1) do { \
  const float* _ac = acum + ((size_t)(b * NH + (H))) * S_LEN + z * 128; \
  const float* _dts = dtT + ((size_t)(b * NH + (H))) * S_LEN + z * 128; \
  DT0 = _dts[2 * s2]; DT1 = _dts[2 * s2 + 1]; \
  _Pragma("unroll") \
  for (int _si = 0; _si < 8; ++_si) ACS[_si] = _ac[_si * 16 + ec]; \
  _Pragma("unroll") \
  for (int _j = 0; _j < 4; ++_j) ACL[_j] = _ac[lrow + er + _j]; \
  const short* _rs = hrow + (size_t)(2 * s2) * CONVD + (size_t)(H) * PD + p0w; \
  R0 = *(const short8*)(_rs); R1 = *(const short8*)(_rs + CONVD); \
  const short* _pv = (const short*)(states + (((size_t)(b * NC + z)) * NH + (H)) * (size_t)(NS * PD)); \
  P0 = *(const short8*)(_pv + tid * 16); P1 = *(const short8*)(_pv + tid * 16 + 8); \
} while (0)

__global__ __launch_bounds__(512) void yfull_k(const short* __restrict__ hbc,
                                               const short* __restrict__ projb,
                                               const float* __restrict__ dtT,
                                               const float* __restrict__ acum,
                                               const float* __restrict__ states,
                                               const float* __restrict__ Dv,
                                               const float* __restrict__ norm_w,
                                               short* __restrict__ normed) {
  __shared__ short lds[66560];  // sC 16384 | sB 16384 (->sx1+sp1) | sx0 8192 | sp0 8192 | sP 8*2176
  __shared__ float sScale[128];
  __shared__ float sNW[1024];
  short* sC = lds;
  short* sB = lds + 16384;
  short* sx0 = lds + 32768;
  short* sp0 = lds + 40960;
  const int tid = threadIdx.x, wid = tid >> 6, lane = tid & 63;
  short* sPw = lds + 49152 + wid * 2176;
  const int g = blockIdx.x, z = blockIdx.y, b = blockIdx.z;
  const size_t srow0 = (size_t)(b * S_LEN + z * 128);
  const short* hrow = hbc + srow0 * CONVD;

  {  // gl_lds staging with pre-swizzled source (slot_g = slot ^ (row&7))
    const int slot_g = (lane & 15) ^ (((wid & 1) << 2) | (lane >> 4));
    const int n0_ = slot_g * 8;
#pragma unroll
    for (int it = 0; it < 4; ++it) {
      int s = it * 32 + wid * 4 + (lane >> 4);
      gl_lds16(hrow + (size_t)s * CONVD + INTER + GN + g * NS + n0_, sC + (it * 32 + wid * 4) * 128);
      gl_lds16(hrow + (size_t)s * CONVD + INTER + g * NS + n0_, sB + (it * 32 + wid * 4) * 128);
    }
  }
  for (int i = tid; i < 1024; i += 512) sNW[i] = norm_w[g * 1024 + i];
  __syncthreads();  // sC/sB staged

  const int fr = lane & 15, fk8 = (lane >> 4) * 8;
  const int slot4 = lane >> 4, sw7 = lane & 7;
  const int er = (lane >> 4) * 4, ec = lane & 15;
  const int lrow = wid * 16;
  const int s2 = tid & 63, p0w = (tid >> 6) * 8;

  // prefetch head 0 (latency hides under scores)
  float cdt0, cdt1, cacS[8], cacl[4];
  short8 cr0, cr1, cp0, cp1;
  LOADH_Y(g * 16, cdt0, cdt1, cacS, cacl, cr0, cr1, cp0, cp1);

  // scores C·B^T once (fp32 regs)
  f32x4 sc[8] = {};
#pragma unroll
  for (int kk = 0; kk < 4; ++kk) {
    short8 a = RDSW(sC, lrow, kk);
#pragma unroll
    for (int si = 0; si < 8; ++si) {
      short8 bv = RDSW(sB, si * 16, kk);
      sc[si] = mfma16(a, bv, sc[si]);
    }
  }
  WRX(sx0, cdt0, cdt1, cr0, cr1);
  WRP(sp0, cp0, cp1);
  __syncthreads();  // all waves past scores (sB free) + buf0 visible

  float rssq[4] = {0.f, 0.f, 0.f, 0.f};

  for (int hh = 0; hh < 16; ++hh) {
    const int h = g * 16 + hh;
    float ndt0 = 0.f, ndt1 = 0.f, nacS[8], nacl[4];
    short8 nr0, nr1, np0, np1;
    if (hh < 15) LOADH_Y(h + 1, ndt0, ndt1, nacS, nacl, nr0, nr1, np0, np1);

    short* sx = (hh & 1) ? sB : sx0;
    short* sp = (hh & 1) ? (sB + 8192) : sp0;

    // mask raw scores -> P (bf16) in this wave's private band
#pragma unroll
    for (int j = 0; j < 4; ++j) {
      int lloc = er + j;
      float acl = cacl[j];
#pragma unroll
      for (int si = 0; si < 8; ++si) {
        int sI = si * 16 + ec;
        float v = (sI <= lrow + lloc) ? sc[si][j] * __expf(acl - cacS[si]) : 0.f;
        sPw[lloc * 136 + sI] = f2bf(v);
      }
    }
    f32x4 yd[4] = {}, yo[4] = {};
#pragma unroll
    for (int kk = 0; kk < 4; ++kk) {
      short8 ap = *(const short8*)(sPw + fr * 136 + kk * 32 + fk8);
      short8 acf = RDSW(sC, lrow, kk);
#pragma unroll
      for (int ni = 0; ni < 4; ++ni) {
        short8 bv = RDSW(sx, ni * 16, kk);
        yd[ni] = mfma16(ap, bv, yd[ni]);
        short8 bp = RDSW(sp, ni * 16, kk);
        yo[ni] = mfma16(acf, bp, yo[ni]);
      }
    }
    const float Dh = Dv[h];
#pragma unroll
    for (int j = 0; j < 4; ++j) {
      int l = lrow + er + j;
      float e_ac = __expf(cacl[j]);
#pragma unroll
      for (int ni = 0; ni < 4; ++ni) {
        int p = ni * 16 + ec;
        float hs = bf2f(hrow[(size_t)l * CONVD + (size_t)h * PD + p]);
        float y = yd[ni][j] + yo[ni][j] * e_ac + hs * Dh;
        float gate = bf2f(projb[(srow0 + l) * (size_t)PROJP + (size_t)h * PD + p]);
        float gg = y * gate * sigmoidf_(gate);
        normed[(srow0 + l) * (size_t)INTER + (size_t)h * PD + p] = f2bf(gg);
        rssq[j] += gg * gg;
      }
    }
    if (hh < 15) {
      short* nx = (hh & 1) ? sx0 : sB;
      short* npv = (hh & 1) ? sp0 : (sB + 8192);
      WRX(nx, ndt0, ndt1, nr0, nr1);
      WRP(npv, np0, np1);
      cdt0 = ndt0; cdt1 = ndt1; cr0 = nr0; cr1 = nr1; cp0 = np0; cp1 = np1;
#pragma unroll
      for (int si = 0; si < 8; ++si) cacS[si] = nacS[si];
#pragma unroll
      for (int j = 0; j < 4; ++j) cacl[j] = nacl[j];
    }
    __syncthreads();
  }

#pragma unroll
  for (int j = 0; j < 4; ++j) {
#pragma unroll
    for (int m = 1; m <= 8; m <<= 1) rssq[j] += __shfl_xor(rssq[j], m, 64);
  }
  if (ec == 0) {
#pragma unroll
    for (int j = 0; j < 4; ++j) sScale[lrow + er + j] = rsqrtf(rssq[j] * (1.f / 1024.f) + 1e-5f);
  }
  __syncthreads();  // drains vmcnt -> all gg writes visible

  // in-place rescale of the block's 128x1024 bf16 slab
  for (int e = tid * 8; e < 128 * 1024; e += 4096) {
    int row = e >> 10, ch = e & 1023;
    short* gp = normed + (srow0 + row) * (size_t)INTER + g * 1024 + ch;
    short8 gv = *(const short8*)(gp);
    float scl = sScale[row];
    short8 o;
#pragma unroll
    for (int q = 0; q < 8; ++q) o[q] = f2bf(bf2f(gv[q]) * scl * sNW[ch + q]);
    *(short8*)(gp) = o;
  }
}

// ----------------------------------------------------------------
extern "C" void kernel_launch(void* const* d_in, const int* in_sizes, int n_in,
                              void* d_out, int out_size, void* d_ws, size_t ws_size,
                              hipStream_t stream) {
  const float* x     = (const float*)d_in[0];
  const float* w1    = (const float*)d_in[1];
  const float* convw = (const float*)d_in[2];
  const float* convb = (const float*)d_in[3];
  const float* dtb   = (const float*)d_in[4];
  const float* alog  = (const float*)d_in[5];
  const float* Dv    = (const float*)d_in[6];
  const float* nw    = (const float*)d_in[7];
  const float* w2    = (const float*)d_in[8];
  float* out = (float*)d_out;

  char* ws = (char*)d_ws;
  size_t off = 0;
  float* dtT = (float*)(ws + off);  off += (size_t)BB * NH * S_LEN * 4;
  float* acum = (float*)(ws + off); off += (size_t)BB * NH * S_LEN * 4;
  short* xb = (short*)(ws + off);   off += (size_t)BS * HID_DIM * 2;
  char* w1region = ws + off;        off += (size_t)PROJP * HID_DIM * 2;
  short* w1b = (short*)w1region;
  short* normed = (short*)w1region;                              // reuse after gemm1
  short* w2b = (short*)(w1region + (size_t)BS * INTER * 2);      // reuse after gemm1
  short* projb = (short*)(ws + off); off += (size_t)BS * PROJP * 2;
  short* hbc = (short*)(ws + off);   off += (size_t)BS * CONVD * 2;
  float* states = (float*)(ws + off); off += (size_t)BB * NC * NH * NS * PD * 4;

  const size_t nx = (size_t)BS * HID_DIM;
  const size_t nw1 = (size_t)PROJ * HID_DIM;
  const size_t nw2 = (size_t)HID_DIM * INTER;

  cvt_f32_bf16_k<<<dim3(nx / 2048), 256, 0, stream>>>(x, xb, nx);
  cvt_f32_bf16_k<<<dim3(nw1 / 2048), 256, 0, stream>>>(w1, w1b, nw1);

  // gemm1: [4096 x 18560(pad 18688)] = xb[4096x4096] * w1b^T ; 16 x 73 tiles
  gemm256_k<1><<<dim3(16 * 73), 512, 0, stream>>>(xb, w1b, projb, PROJP, HID_DIM, 73);

  // w1b dead now; stage w2 into its region
  cvt_f32_bf16_k<<<dim3(nw2 / 2048), 256, 0, stream>>>(w2, w2b, nw2);

  conv_silu_k<<<dim3(CONVD / 256, S_LEN / 256, BB), 256, 0, stream>>>(projb, convw, convb, hbc);
  acum_k<<<dim3(NC, NH, BB), 128, 0, stream>>>(projb, dtb, alog, dtT, acum);

  states_k<<<dim3(NG, NC, BB), 512, 0, stream>>>(hbc, dtT, acum, states);
  scan_k<<<dim3(NH, BB), 256, 0, stream>>>(states, acum);
  yfull_k<<<dim3(NG, NC, BB), 512, 0, stream>>>(hbc, projb, dtT, acum, states, Dv, nw, normed);

  // gemm2: [4096 x 4096] = normed[4096x8192] * w2b^T ; 16 x 16 tiles
  gemm256_k<0><<<dim3(16 * 16), 512, 0, stream>>>(normed, w2b, out, HID_DIM, INTER, 16);
}